// Round 10
// baseline (351.570 us; speedup 1.0000x reference)
//
#include <hip/hip_runtime.h>
#include <stdint.h>
#include <math.h>

#define B_    2
#define T_    2048
#define DIM_  2048
#define H_    16
#define DC_   512
#define DCQ_  1536
#define NROWS (B_*T_)   // 4096

typedef unsigned short u16;
typedef __attribute__((ext_vector_type(8))) __bf16 bf16x8;
typedef __attribute__((ext_vector_type(4))) float  f32x4;
typedef __attribute__((ext_vector_type(8))) unsigned short u16x8;
typedef __attribute__((ext_vector_type(4))) float  f4v;

__device__ __forceinline__ u16 f2bf(float f){
  unsigned u = __float_as_uint(f);
  u += 0x7FFFu + ((u >> 16) & 1u);   // RNE
  return (u16)(u >> 16);
}
__device__ __forceinline__ float bf2f(u16 h){ return __uint_as_float(((unsigned)h) << 16); }

__device__ __forceinline__ unsigned cvt_pk_bf16(float lo, float hi){
  unsigned r;
  asm("v_cvt_pk_bf16_f32 %0, %1, %2" : "=v"(r) : "v"(lo), "v"(hi));
  return r;
}

// async global->LDS, 16B per lane; LDS dest = wave-uniform base + lane*16.
__device__ __forceinline__ void gld_lds16(const void* g, void* l){
  auto gp = reinterpret_cast<__attribute__((address_space(1))) unsigned int*>(
      reinterpret_cast<uintptr_t>(g));
  auto lp = reinterpret_cast<__attribute__((address_space(3))) unsigned int*>(
      reinterpret_cast<uintptr_t>(l));
  __builtin_amdgcn_global_load_lds(gp, lp, 16, 0, 0);
}

__device__ __forceinline__ f32x4 mfma16(bf16x8 a, bf16x8 b, f32x4 c){
  return __builtin_amdgcn_mfma_f32_16x16x32_bf16(a, b, c, 0, 0, 0);
}

__device__ __forceinline__ void vmwait0(){ asm volatile("s_waitcnt vmcnt(0)" ::: "memory"); }
__device__ __forceinline__ void vmwait8(){ asm volatile("s_waitcnt vmcnt(8)" ::: "memory"); }
__device__ __forceinline__ void barr(){ asm volatile("s_barrier" ::: "memory"); }

// ---------------- dtype detect + ticket reset (8 XCD-partition tickets, stride 16)
__global__ void k_detect(const u16* cosr, int* flag, int* ticket){
  if (threadIdx.x == 0) *flag = (cosr[0] == (u16)0x3F80u) ? 1 : 0;
  if (threadIdx.x < 128) ticket[threadIdx.x] = 0;
}

// ---------------- merged x-convert + 8 weight transposes (one launch)
struct TDesc { const void* src; u16* dst; int srcStride, dstStride, cblk, nbx, blk0; };
struct TPack { TDesc d[8]; };
#define CONVBLK 8192

__global__ void k_prep(const void* __restrict__ xsrc, u16* __restrict__ x_bf,
                       TPack p, const int* flag){
  __shared__ u16 tile[64][72];
  const int bid = blockIdx.x;
  const int tid = threadIdx.x;
  const int f = *flag;
  if (bid < CONVBLK){
    int id = bid * 256 + tid;                 // n4 = 2097152 = 8192*256 exactly
    if (f){
      reinterpret_cast<uint2*>(x_bf)[id] = reinterpret_cast<const uint2*>(xsrc)[id];
    } else {
      f4v v = reinterpret_cast<const f4v*>(xsrc)[id];
      unsigned lo = (unsigned)f2bf(v.x) | ((unsigned)f2bf(v.y) << 16);
      unsigned hi = (unsigned)f2bf(v.z) | ((unsigned)f2bf(v.w) << 16);
      reinterpret_cast<uint2*>(x_bf)[id] = make_uint2(lo, hi);
    }
    return;
  }
  const int tb = bid - CONVBLK;
  int i = 0;
  #pragma unroll
  for (int k = 1; k < 8; ++k) if (tb >= p.d[k].blk0) i = k;
  const void* src = p.d[i].src;
  u16* dst = p.d[i].dst;
  const int srcStride = p.d[i].srcStride, dstStride = p.d[i].dstStride;
  const int rel = tb - p.d[i].blk0;
  const int bx = rel % p.d[i].nbx, by = rel / p.d[i].nbx;
  const int r0 = by << 6, c0 = bx * p.d[i].cblk;
  #pragma unroll
  for (int it = 0; it < 2; ++it){
    int task = (it << 8) + tid;
    int r = task >> 3, c8 = (task & 7) << 3;
    if (f){
      const u16* pp = (const u16*)src + (size_t)(r0 + r) * srcStride + c0 + c8;
      u16x8 v = *reinterpret_cast<const u16x8*>(pp);
      #pragma unroll
      for (int j = 0; j < 8; ++j) tile[r][c8 + j] = v[j];
    } else {
      const float* pp = (const float*)src + (size_t)(r0 + r) * srcStride + c0 + c8;
      f4v a = reinterpret_cast<const f4v*>(pp)[0];
      f4v b = reinterpret_cast<const f4v*>(pp)[1];
      tile[r][c8+0]=f2bf(a.x); tile[r][c8+1]=f2bf(a.y); tile[r][c8+2]=f2bf(a.z); tile[r][c8+3]=f2bf(a.w);
      tile[r][c8+4]=f2bf(b.x); tile[r][c8+5]=f2bf(b.y); tile[r][c8+6]=f2bf(b.z); tile[r][c8+7]=f2bf(b.w);
    }
  }
  __syncthreads();
  #pragma unroll
  for (int it = 0; it < 2; ++it){
    int task = (it << 8) + tid;
    int rr = task >> 3, cc8 = (task & 7) << 3;
    u16x8 v;
    #pragma unroll
    for (int j = 0; j < 8; ++j) v[j] = tile[cc8 + j][rr];
    *reinterpret_cast<u16x8*>(dst + (size_t)((bx << 6) + rr) * dstStride + r0 + cc8) = v;
  }
}

// ---------------- 256x256 8-phase GEMM, counted-vmcnt pipeline (2 groups by by-index).
// Optional bijective XCD-chunked swizzle (swz=1; nwg must be divisible by 8, gridDim.x==16).
// Row-XOR swizzle byte ^= ((row&7)<<4) via inverse-swizzled global sources.
#define MMQ(MH, NH, BFR) do{ \
  __builtin_amdgcn_s_setprio(1); \
  _Pragma("unroll") for (int ks = 0; ks < 2; ++ks) \
    _Pragma("unroll") for (int mi = 0; mi < 4; ++mi) \
      _Pragma("unroll") for (int ni = 0; ni < 2; ++ni) \
        acc[(MH)*4+mi][(NH)*2+ni] = mfma16(af[ks][mi], BFR[ks][ni], acc[(MH)*4+mi][(NH)*2+ni]); \
  __builtin_amdgcn_s_setprio(0); \
}while(0)

#define LDA(MH) do{ \
  _Pragma("unroll") for (int ks = 0; ks < 2; ++ks) \
    _Pragma("unroll") for (int mi = 0; mi < 4; ++mi){ \
      int row = (MH)*64 + mi*16 + l16; \
      int cb = ((ks << 6) + (g << 4)) ^ ((row & 7) << 4); \
      af[ks][mi] = *reinterpret_cast<const bf16x8*>(&lds[buf*32768 + wm*8192 + (((row << 7) + cb) >> 1)]); \
    } \
}while(0)

#define LDB(DST, NH) do{ \
  _Pragma("unroll") for (int ks = 0; ks < 2; ++ks) \
    _Pragma("unroll") for (int ni = 0; ni < 2; ++ni){ \
      int row = ((wn & 1) * 64) + (NH)*32 + ni*16 + l16; \
      int cb = ((ks << 6) + (g << 4)) ^ ((row & 7) << 4); \
      DST[ks][ni] = *reinterpret_cast<const bf16x8*>(&lds[buf*32768 + 16384 + (wn >> 1)*8192 + (((row << 7) + cb) >> 1)]); \
    } \
}while(0)

__global__ __launch_bounds__(512, 2) void k_gemm256(
    const u16* __restrict__ A0, int lda0, const u16* __restrict__ Bt0, int K0,
    u16* __restrict__ C0, int ldc0, float os0,
    const u16* __restrict__ A1, int lda1, const u16* __restrict__ Bt1, int K1,
    u16* __restrict__ C1, int ldc1, float os1,
    int ysplit, int swz, void* outp, const int* flag){
  __shared__ alignas(16) u16 lds[65536];   // 128 KB
  const int tid = threadIdx.x;
  const int wid = tid >> 6, lane = tid & 63;
  const int wm = wid >> 2, wn = wid & 3;
  const int l16 = lane & 15, g = lane >> 4;
  int lin = blockIdx.y * 16 + blockIdx.x;
  if (swz){
    const int q8 = (gridDim.x * gridDim.y) >> 3;
    lin = (lin & 7) * q8 + (lin >> 3);       // chunk per XCD (bijective: nwg%8==0)
  }
  int by = lin >> 4;
  const int m0 = (lin & 15) << 8;
  const u16 *A, *Bt; u16* C; int lda, K, ldc; float oscale;
  if (by < ysplit){ A = A0; lda = lda0; Bt = Bt0; K = K0; C = C0; ldc = ldc0; oscale = os0; }
  else { by -= ysplit; A = A1; lda = lda1; Bt = Bt1; K = K1; C = C1; ldc = ldc1; oscale = os1; }
  const int n0 = by << 8;
  const size_t Kz = (size_t)K;
  const int nkt = K >> 6;

  auto STAGE = [&](int kt, int bufn){
    const int kb = kt << 6;
    #pragma unroll
    for (int q = 0; q < 8; ++q){
      const int ht = q >> 1, ch = q & 1;
      const int Lb = ((ch * 8 + wid) << 10) + (lane << 4);   // byte within half-tile
      const int row = Lb >> 7;
      const int colb = (Lb & 127) ^ ((row & 7) << 4);        // inverse-swizzled source
      const u16* src;
      if (ht < 2) src = A  + (size_t)(m0 + ht * 128 + row) * lda + kb + (colb >> 1);
      else        src = Bt + (size_t)(n0 + (ht - 2) * 128 + row) * Kz + kb + (colb >> 1);
      gld_lds16(src, &lds[bufn * 32768 + ht * 8192 + ((ch * 8 + wid) << 9)]);
    }
  };

  f32x4 acc[8][4] = {};
  bf16x8 af[2][4], bf0[2][2], bf1[2][2];

  STAGE(0, 0);
  int buf = 0;

  for (int kt = 0; kt < nkt; ++kt){
    if (kt + 1 < nkt){ STAGE(kt + 1, buf ^ 1); vmwait8(); }   // wait only tile-kt's loads
    else vmwait0();
    barr();                                                    // buf resident for all waves
    // phase 0
    LDA(0);
    LDB(bf0, 0);
    barr();
    MMQ(0, 0, bf0);
    barr();
    // phase 1
    LDB(bf1, 1);
    barr();
    MMQ(0, 1, bf1);
    barr();
    // phase 2
    LDA(1);
    barr();
    MMQ(1, 0, bf0);
    barr();
    // phase 3
    MMQ(1, 1, bf1);
    barr();                                                    // reads done before next STAGE overwrites
    buf ^= 1;
  }

  const int r4 = g << 2;
  const int f = flag ? *flag : 1;
  #pragma unroll
  for (int mi8 = 0; mi8 < 8; ++mi8){
    int row = m0 + wm * 128 + mi8 * 16 + r4;
    #pragma unroll
    for (int ni4 = 0; ni4 < 4; ++ni4){
      int col = n0 + wn * 64 + ni4 * 16 + l16;
      #pragma unroll
      for (int j = 0; j < 4; ++j){
        float v = acc[mi8][ni4][j] * oscale;
        if (outp){
          if (f) ((u16*)outp)[(size_t)(row + j) * ldc + col] = f2bf(v);
          else   ((float*)outp)[(size_t)(row + j) * ldc + col] = v;
        } else {
          C[(size_t)(row + j) * ldc + col] = f2bf(v);
        }
      }
    }
  }
}

// ---------------- merged RoPE + vT build (one launch, 4096 blocks)
__global__ void k_ropevt(const u16* __restrict__ xc, const void* __restrict__ cosp,
                         const void* __restrict__ sinp, const int* flag,
                         u16* __restrict__ krope, u16* __restrict__ qrope,
                         const u16* __restrict__ kvP, u16* __restrict__ vT){
  __shared__ u16 tile[64][72];
  if (blockIdx.x < 2048){
    // RoPE from xc cols 2048..2175 (stride 2304); q-part pre-scaled by 1/sqrt(D)*log2e
    int id = blockIdx.x * 256 + threadIdx.x;   // exactly NROWS*128
    int row = id >> 7, c = id & 127;
    int t = row & (T_ - 1);
    int d = c & 63, i = d & 31;
    float cs, sn;
    if (*flag){ cs = bf2f(((const u16*)cosp)[t * 32 + i]); sn = bf2f(((const u16*)sinp)[t * 32 + i]); }
    else      { cs = ((const float*)cosp)[t * 32 + i];     sn = ((const float*)sinp)[t * 32 + i]; }
    int base = c & 64;
    float t1 = bf2f(xc[(size_t)row * 2304 + 2048 + base + i]);
    float t2 = bf2f(xc[(size_t)row * 2304 + 2048 + base + 32 + i]);
    float v = (d < 32) ? (t1 * cs - t2 * sn) : (t2 * cs + t1 * sn);
    if (c >= 64) v *= 0.12753139626374414f;
    ((c < 64) ? krope : qrope)[(size_t)row * 64 + d] = f2bf(v);
    return;
  }
  const int rel = blockIdx.x - 2048;
  const int t0 = (rel & 31) << 6, d0 = ((rel >> 5) & 1) << 6, bh = rel >> 6;
  const int b = bh >> 4, h = bh & 15;
  const int tid = threadIdx.x;
  #pragma unroll
  for (int i = 0; i < 2; ++i){
    int task = (i << 8) + tid;
    int r = task >> 3, c8 = (task & 7) << 3;
    const u16* p = kvP + (size_t)(b * T_ + t0 + r) * 3072 + 1024 + h * 128 + d0 + c8;
    u16x8 v = *reinterpret_cast<const u16x8*>(p);
    #pragma unroll
    for (int j = 0; j < 8; ++j) tile[r][c8 + j] = v[j];
  }
  __syncthreads();
  #pragma unroll
  for (int i = 0; i < 2; ++i){
    int task = (i << 8) + tid;
    int rr = task >> 3, cc8 = (task & 7) << 3;
    u16x8 v;
    #pragma unroll
    for (int j = 0; j < 8; ++j) v[j] = tile[cc8 + j][rr];
    *reinterpret_cast<u16x8*>(vT + ((size_t)bh * 128 + d0 + rr) * T_ + t0 + cc8) = v;
  }
}

// ---------------- causal flash attention, swapped-QK^T register softmax.
// Single 32KB LDS buffer -> 4 blocks/CU (4 waves/SIMD cross-block latency hiding).
// 1024 workers, per-XCD tickets (xcd = blockIdx.x & 7); balance-preserving item map:
// r=t>>5, c=t&31, qt = (r&1) ? c : 31-c  -> each CU's 4 items sum to 66 tile-units.
__global__ __launch_bounds__(256, 4) void k_attn(const u16* __restrict__ qP,
                                                 const u16* __restrict__ kvP,
                                                 const u16* __restrict__ vT,
                                                 const u16* __restrict__ krope,
                                                 const u16* __restrict__ qrope,
                                                 u16* __restrict__ aout,
                                                 int* __restrict__ ticket){
  __shared__ alignas(16) u16 smem[16384];   // 32 KB: K [64][128] @0, V [128][64] @8192
  const int tid = threadIdx.x, wid = tid >> 6, lane = tid & 63;
  const int l16 = lane & 15, g = lane >> 4;
  const int lk = g << 3, r4 = g << 2;
  const int sw8 = (l16 & 7) << 3;
  const int xcd = blockIdx.x & 7;

  while (true){
    if (tid == 0) *(int*)&smem[0] = atomicAdd(&ticket[xcd << 4], 1);
    __syncthreads();
    const int t = *(const int*)&smem[0];
    __syncthreads();
    if (t >= 128) break;
    const int rr_ = t >> 5, cc_ = t & 31;
    const int qt = (rr_ & 1) ? cc_ : (31 - cc_);   // paired heavy/light per CU slot
    const int bh = (xcd << 2) + rr_, b = bh >> 4, h = bh & 15;
    const int q0 = qt << 6;
    const size_t bT = (size_t)b * T_;
    const u16* kvPb = kvP + bT * 3072 + (h << 6);
    const u16* krb  = krope + bT * 64;
    const u16* vTb  = vT + (size_t)bh * 128 * T_;
    const int qlo = q0 + (wid << 4);
    const int nkv = qt + 1;

    auto STAGE = [&](int k0){
      #pragma unroll
      for (int r = 0; r < 8; ++r){
        int c = (r << 8) + tid;
        const u16* src;
        if (r < 4){
          int row = c >> 4, cc = c & 15;
          int ccx = (cc & 8) | ((cc & 7) ^ (row & 7));
          int col0 = ccx << 3;
          src = (col0 < 64) ? (kvPb + (size_t)(k0 + row) * 3072 + col0)
                            : (krb  + (size_t)(k0 + row) * 64 + (col0 - 64));
        } else {
          int cv = c - 1024;
          int row = cv >> 3, cc = cv & 7;
          int ccx = cc ^ (row & 7);
          src = vTb + (size_t)row * T_ + k0 + (ccx << 3);
        }
        gld_lds16(src, &smem[(size_t)((r << 8) + (wid << 6)) << 3]);
      }
    };

    bf16x8 qf[4];
    {
      size_t grow = bT + qlo + l16;
      #pragma unroll
      for (int ks = 0; ks < 4; ++ks){
        int d = (ks << 5) + lk;
        const u16* src = (ks < 2) ? (qP + grow * 1024 + (h << 6) + d)
                                  : (qrope + grow * 64 + (d - 64));
        qf[ks] = *reinterpret_cast<const bf16x8*>(src);
      }
    }
    f32x4 o[8] = {};
    float m = -3e38f, l = 0.f;

    for (int kv = 0; kv < nkv; ++kv){
      const int k0 = kv << 6;
      STAGE(k0);
      __syncthreads();                      // drains vmcnt -> tile resident
      f32x4 s[4] = {};
      #pragma unroll
      for (int ks = 0; ks < 4; ++ks){
        int colsw = ((ks << 5) + lk) ^ sw8;
        #pragma unroll
        for (int n = 0; n < 4; ++n){
          bf16x8 kf = *reinterpret_cast<const bf16x8*>(&smem[((n << 4) + l16) * 128 + colsw]);
          s[n] = mfma16(kf, qf[ks], s[n]);
        }
      }
      if (k0 == q0){
        const int tq = qlo + l16;
        #pragma unroll
        for (int n = 0; n < 4; ++n)
          #pragma unroll
          for (int j = 0; j < 4; ++j)
            s[n][j] = (k0 + (n << 4) + r4 + j <= tq) ? s[n][j] : -3e38f;
      }
      float mx;
      {
        float a0 = fmaxf(fmaxf(s[0][0], s[0][1]), fmaxf(s[0][2], s[0][3]));
        float a1 = fmaxf(fmaxf(s[1][0], s[1][1]), fmaxf(s[1][2], s[1][3]));
        float a2 = fmaxf(fmaxf(s[2][0], s[2][1]), fmaxf(s[2][2], s[2][3]));
        float a3 = fmaxf(fmaxf(s[3][0], s[3][1]), fmaxf(s[3][2], s[3][3]));
        mx = fmaxf(fmaxf(a0, a1), fmaxf(a2, a3));
        mx = fmaxf(mx, __shfl_xor(mx, 16));
        mx = fmaxf(mx, __shfl_xor(mx, 32));
      }
      if (__ballot(mx > m + 8.f)){
        float mnew = fmaxf(m, mx);
        float alpha = exp2f(m - mnew);
        m = mnew; l *= alpha;
        #pragma unroll
        for (int j = 0; j < 4; ++j){
          float av = __shfl(alpha, r4 + j);
          #pragma unroll
          for (int db = 0; db < 8; ++db) o[db][j] *= av;
        }
      }
      unsigned w[4][2];
      float rs = 0.f;
      #pragma unroll
      for (int n = 0; n < 4; ++n)
        #pragma unroll
        for (int jh = 0; jh < 2; ++jh){
          float p0 = exp2f(s[n][2*jh]     - m);
          float p1 = exp2f(s[n][2*jh + 1] - m);
          rs += p0 + p1;
          w[n][jh] = cvt_pk_bf16(p0, p1);
        }
      rs += __shfl_xor(rs, 16);
      rs += __shfl_xor(rs, 32);
      l += rs;
      const int srcA = l16 + ((g & 1) << 5);
      const int srcB = srcA + 16;
      const bool hi = (g >= 2);
      bf16x8 pa[2];
      #pragma unroll
      for (int ks2 = 0; ks2 < 2; ++ks2){
        unsigned a0 = __shfl((int)w[2*ks2][0],     srcA);
        unsigned b0 = __shfl((int)w[2*ks2 + 1][0], srcA);
        unsigned a1 = __shfl((int)w[2*ks2][1],     srcA);
        unsigned b1 = __shfl((int)w[2*ks2 + 1][1], srcA);
        unsigned a2 = __shfl((int)w[2*ks2][0],     srcB);
        unsigned b2 = __shfl((int)w[2*ks2 + 1][0], srcB);
        unsigned a3 = __shfl((int)w[2*ks2][1],     srcB);
        unsigned b3 = __shfl((int)w[2*ks2 + 1][1], srcB);
        union { unsigned u[4]; bf16x8 v; } pk;
        pk.u[0] = hi ? b0 : a0;
        pk.u[1] = hi ? b1 : a1;
        pk.u[2] = hi ? b2 : a2;
        pk.u[3] = hi ? b3 : a3;
        pa[ks2] = pk.v;
      }
      #pragma unroll
      for (int ks2 = 0; ks2 < 2; ++ks2){
        int colsw = ((ks2 << 5) + lk) ^ sw8;
        #pragma unroll
        for (int db = 0; db < 8; ++db){
          bf16x8 vb = *reinterpret_cast<const bf16x8*>(&smem[8192 + ((db << 4) + l16) * 64 + colsw]);
          o[db] = mfma16(pa[ks2], vb, o[db]);
        }
      }
      __syncthreads();                      // reads done before next STAGE overwrites
    }
    #pragma unroll
    for (int j = 0; j < 4; ++j){
      float lv = __shfl(l, r4 + j);
      float rinv = 1.f / lv;
      const int tq = qlo + r4 + j;
      u16* dst = aout + (bT + tq) * 2048 + (h << 7) + l16;
      #pragma unroll
      for (int db = 0; db < 8; ++db)
        dst[db << 4] = f2bf(o[db][j] * rinv);
    }
  }
}

extern "C" void kernel_launch(void* const* d_in, const int* in_sizes, int n_in,
                              void* d_out, int out_size, void* d_ws, size_t ws_size,
                              hipStream_t stream){
  const void* x       = d_in[0];
  const void* cosp    = d_in[1];
  const void* sinp    = d_in[2];
  const void* w_kv    = d_in[3];
  const void* w_kdec  = d_in[4];
  const void* w_vdec  = d_in[5];
  const void* w_qc    = d_in[6];
  const void* w_qdec  = d_in[7];
  const void* w_krope = d_in[8];
  const void* w_qrope = d_in[9];
  const void* w_o     = d_in[10];

  char* ws = (char*)d_ws;
  size_t off = 0;
  auto alloc = [&](size_t bytes){ void* p = ws + off; off += (bytes + 255) & ~(size_t)255; return p; };
  int* flag     = (int*)alloc(256);
  int* ticket   = (int*)alloc(1024);                         // 8 tickets, stride 16 ints
  u16* x_bf     = (u16*)alloc((size_t)NROWS * DIM_ * 2);
  u16* w_c1T    = (u16*)alloc((size_t)2304 * DIM_ * 2);      // [kvT(512); qcT(1536); kropeT(64); qropeT(64); pad(128)] x 2048
  u16* w_kvdT   = (u16*)alloc((size_t)3072 * DC_ * 2);       // [kdecPackedT(1024); vdecT(2048)] x 512
  u16* w_qdPT   = (u16*)alloc((size_t)1024 * DCQ_ * 2);      // packed qdecT (1024 x 1536)
  u16* w_oT     = (u16*)alloc((size_t)DIM_ * DIM_ * 2);
  u16* xc       = (u16*)alloc((size_t)NROWS * 2304 * 2);     // [c_kv(512) | c_q(1536) | ropes(128) | pad(128)]
  u16* qP       = (u16*)alloc((size_t)NROWS * 1024 * 2);     // packed q decode (pre-scaled)
  u16* kvP      = (u16*)alloc((size_t)NROWS * 3072 * 2);     // [kPacked(1024) | v(2048)]
  u16* krope    = (u16*)alloc((size_t)NROWS * 64 * 2);
  u16* qrope    = (u16*)alloc((size_t)NROWS * 64 * 2);       // pre-scaled
  u16* vT       = (u16*)alloc((size_t)32 * 128 * T_ * 2);    // [bh][d][t]
  u16* aout     = (u16*)alloc((size_t)NROWS * DIM_ * 2);
  (void)in_sizes; (void)n_in; (void)out_size; (void)ws_size;

  const float SC2 = 0.12753139626374414f;   // 1/sqrt(128) * log2(e)

  hipLaunchKernelGGL(k_detect, dim3(1), dim3(128), 0, stream, (const u16*)cosp, flag, ticket);

  // merged x-convert + weight transposes (8192 conv blocks + 2880 transpose blocks)
  TPack tp;
  tp.d[0] = { w_kv,    w_c1T,                        512,  2048, 64,  8,  0    };
  tp.d[1] = { w_qc,    w_c1T + (size_t)512 * 2048,   1536, 2048, 64,  24, 256  };
  tp.d[2] = { w_krope, w_c1T + (size_t)2048 * 2048,  64,   2048, 64,  1,  1024 };
  tp.d[3] = { w_qrope, w_c1T + (size_t)2112 * 2048,  64,   2048, 64,  1,  1056 };
  tp.d[4] = { w_kdec,  w_kvdT,                       2048, 512,  128, 16, 1088 };
  tp.d[5] = { w_vdec,  w_kvdT + (size_t)1024 * 512,  2048, 512,  64,  32, 1216 };
  tp.d[6] = { w_qdec,  w_qdPT,                       2048, 1536, 128, 16, 1472 };
  tp.d[7] = { w_o,     w_oT,                         2048, 2048, 64,  32, 1856 };
  hipLaunchKernelGGL(k_prep, dim3(CONVBLK + 2880), dim3(256), 0, stream, x, x_bf, tp, flag);

  // G13: xc = x @ [w_kv | w_qc | w_krope | w_qrope | pad]  (4096 x 2304, K=2048), XCD-chunked
  hipLaunchKernelGGL(k_gemm256, dim3(16, 9), dim3(512), 0, stream,
                     x_bf, DIM_, w_c1T, DIM_, xc, 2304, 1.0f,
                     x_bf, DIM_, w_c1T, DIM_, xc, 2304, 1.0f,
                     9, 1, (void*)nullptr, (const int*)nullptr);
  // G2 + G4 grouped (256 blocks, linear order: groups have unequal K -> keep round-robin)
  hipLaunchKernelGGL(k_gemm256, dim3(16, 16), dim3(512), 0, stream,
                     xc, 2304, w_kvdT, DC_, kvP, 3072, 1.0f,
                     xc + 512, 2304, w_qdPT, DCQ_, qP, 1024, SC2,
                     12, 0, (void*)nullptr, (const int*)nullptr);
  // merged RoPE + vT (2048 + 2048 blocks)
  hipLaunchKernelGGL(k_ropevt, dim3(4096), dim3(256), 0, stream,
                     xc, cosp, sinp, flag, krope, qrope, kvP, vT);
  // attention (1024 workers = 4 blocks/CU, XCD-partitioned tickets)
  hipLaunchKernelGGL(k_attn, dim3(1024), dim3(256), 0, stream,
                     qP, kvP, vT, krope, qrope, aout, ticket);
  // G5: out = aout @ w_o  (4096 x 2048, K=2048; writes d_out, dtype per flag), XCD-chunked
  hipLaunchKernelGGL(k_gemm256, dim3(16, 8), dim3(512), 0, stream,
                     aout, DIM_, w_oT, DIM_, (u16*)nullptr, DIM_, 1.0f,
                     aout, DIM_, w_oT, DIM_, (u16*)nullptr, DIM_, 1.0f,
                     8, 1, d_out, (const int*)flag);
}

// Round 11
// 338.902 us; speedup vs baseline: 1.0374x; 1.0374x over previous
//
#include <hip/hip_runtime.h>
#include <stdint.h>
#include <math.h>

#define B_    2
#define T_    2048
#define DIM_  2048
#define H_    16
#define DC_   512
#define DCQ_  1536
#define NROWS (B_*T_)   // 4096

typedef unsigned short u16;
typedef __attribute__((ext_vector_type(8))) __bf16 bf16x8;
typedef __attribute__((ext_vector_type(4))) float  f32x4;
typedef __attribute__((ext_vector_type(8))) unsigned short u16x8;
typedef __attribute__((ext_vector_type(4))) float  f4v;

__device__ __forceinline__ u16 f2bf(float f){
  unsigned u = __float_as_uint(f);
  u += 0x7FFFu + ((u >> 16) & 1u);   // RNE
  return (u16)(u >> 16);
}
__device__ __forceinline__ float bf2f(u16 h){ return __uint_as_float(((unsigned)h) << 16); }

__device__ __forceinline__ unsigned cvt_pk_bf16(float lo, float hi){
  unsigned r;
  asm("v_cvt_pk_bf16_f32 %0, %1, %2" : "=v"(r) : "v"(lo), "v"(hi));
  return r;
}

// async global->LDS, 16B per lane; LDS dest = wave-uniform base + lane*16.
__device__ __forceinline__ void gld_lds16(const void* g, void* l){
  auto gp = reinterpret_cast<__attribute__((address_space(1))) unsigned int*>(
      reinterpret_cast<uintptr_t>(g));
  auto lp = reinterpret_cast<__attribute__((address_space(3))) unsigned int*>(
      reinterpret_cast<uintptr_t>(l));
  __builtin_amdgcn_global_load_lds(gp, lp, 16, 0, 0);
}

__device__ __forceinline__ f32x4 mfma16(bf16x8 a, bf16x8 b, f32x4 c){
  return __builtin_amdgcn_mfma_f32_16x16x32_bf16(a, b, c, 0, 0, 0);
}

__device__ __forceinline__ void vmwait0(){ asm volatile("s_waitcnt vmcnt(0)" ::: "memory"); }
__device__ __forceinline__ void vmwait8(){ asm volatile("s_waitcnt vmcnt(8)" ::: "memory"); }
__device__ __forceinline__ void barr(){ asm volatile("s_barrier" ::: "memory"); }

// ---------------- dtype detect + ticket reset (8 XCD-partition tickets, stride 16)
__global__ void k_detect(const u16* cosr, int* flag, int* ticket){
  if (threadIdx.x == 0) *flag = (cosr[0] == (u16)0x3F80u) ? 1 : 0;
  if (threadIdx.x < 128) ticket[threadIdx.x] = 0;
}

// ---------------- merged x-convert + 8 weight transposes (one launch)
struct TDesc { const void* src; u16* dst; int srcStride, dstStride, cblk, nbx, blk0; };
struct TPack { TDesc d[8]; };
#define CONVBLK 8192

__global__ void k_prep(const void* __restrict__ xsrc, u16* __restrict__ x_bf,
                       TPack p, const int* flag){
  __shared__ u16 tile[64][72];
  const int bid = blockIdx.x;
  const int tid = threadIdx.x;
  const int f = *flag;
  if (bid < CONVBLK){
    int id = bid * 256 + tid;                 // n4 = 2097152 = 8192*256 exactly
    if (f){
      reinterpret_cast<uint2*>(x_bf)[id] = reinterpret_cast<const uint2*>(xsrc)[id];
    } else {
      f4v v = reinterpret_cast<const f4v*>(xsrc)[id];
      unsigned lo = (unsigned)f2bf(v.x) | ((unsigned)f2bf(v.y) << 16);
      unsigned hi = (unsigned)f2bf(v.z) | ((unsigned)f2bf(v.w) << 16);
      reinterpret_cast<uint2*>(x_bf)[id] = make_uint2(lo, hi);
    }
    return;
  }
  const int tb = bid - CONVBLK;
  int i = 0;
  #pragma unroll
  for (int k = 1; k < 8; ++k) if (tb >= p.d[k].blk0) i = k;
  const void* src = p.d[i].src;
  u16* dst = p.d[i].dst;
  const int srcStride = p.d[i].srcStride, dstStride = p.d[i].dstStride;
  const int rel = tb - p.d[i].blk0;
  const int bx = rel % p.d[i].nbx, by = rel / p.d[i].nbx;
  const int r0 = by << 6, c0 = bx * p.d[i].cblk;
  #pragma unroll
  for (int it = 0; it < 2; ++it){
    int task = (it << 8) + tid;
    int r = task >> 3, c8 = (task & 7) << 3;
    if (f){
      const u16* pp = (const u16*)src + (size_t)(r0 + r) * srcStride + c0 + c8;
      u16x8 v = *reinterpret_cast<const u16x8*>(pp);
      #pragma unroll
      for (int j = 0; j < 8; ++j) tile[r][c8 + j] = v[j];
    } else {
      const float* pp = (const float*)src + (size_t)(r0 + r) * srcStride + c0 + c8;
      f4v a = reinterpret_cast<const f4v*>(pp)[0];
      f4v b = reinterpret_cast<const f4v*>(pp)[1];
      tile[r][c8+0]=f2bf(a.x); tile[r][c8+1]=f2bf(a.y); tile[r][c8+2]=f2bf(a.z); tile[r][c8+3]=f2bf(a.w);
      tile[r][c8+4]=f2bf(b.x); tile[r][c8+5]=f2bf(b.y); tile[r][c8+6]=f2bf(b.z); tile[r][c8+7]=f2bf(b.w);
    }
  }
  __syncthreads();
  #pragma unroll
  for (int it = 0; it < 2; ++it){
    int task = (it << 8) + tid;
    int rr = task >> 3, cc8 = (task & 7) << 3;
    u16x8 v;
    #pragma unroll
    for (int j = 0; j < 8; ++j) v[j] = tile[cc8 + j][rr];
    *reinterpret_cast<u16x8*>(dst + (size_t)((bx << 6) + rr) * dstStride + r0 + cc8) = v;
  }
}

// ---------------- 256x256 8-phase GEMM, counted-vmcnt pipeline (2 groups by by-index).
// Optional bijective XCD-chunked swizzle (swz=1; nwg must be divisible by 8, gridDim.x==16).
// Row-XOR swizzle byte ^= ((row&7)<<4) via inverse-swizzled global sources.
#define MMQ(MH, NH, BFR) do{ \
  __builtin_amdgcn_s_setprio(1); \
  _Pragma("unroll") for (int ks = 0; ks < 2; ++ks) \
    _Pragma("unroll") for (int mi = 0; mi < 4; ++mi) \
      _Pragma("unroll") for (int ni = 0; ni < 2; ++ni) \
        acc[(MH)*4+mi][(NH)*2+ni] = mfma16(af[ks][mi], BFR[ks][ni], acc[(MH)*4+mi][(NH)*2+ni]); \
  __builtin_amdgcn_s_setprio(0); \
}while(0)

#define LDA(MH) do{ \
  _Pragma("unroll") for (int ks = 0; ks < 2; ++ks) \
    _Pragma("unroll") for (int mi = 0; mi < 4; ++mi){ \
      int row = (MH)*64 + mi*16 + l16; \
      int cb = ((ks << 6) + (g << 4)) ^ ((row & 7) << 4); \
      af[ks][mi] = *reinterpret_cast<const bf16x8*>(&lds[buf*32768 + wm*8192 + (((row << 7) + cb) >> 1)]); \
    } \
}while(0)

#define LDB(DST, NH) do{ \
  _Pragma("unroll") for (int ks = 0; ks < 2; ++ks) \
    _Pragma("unroll") for (int ni = 0; ni < 2; ++ni){ \
      int row = ((wn & 1) * 64) + (NH)*32 + ni*16 + l16; \
      int cb = ((ks << 6) + (g << 4)) ^ ((row & 7) << 4); \
      DST[ks][ni] = *reinterpret_cast<const bf16x8*>(&lds[buf*32768 + 16384 + (wn >> 1)*8192 + (((row << 7) + cb) >> 1)]); \
    } \
}while(0)

__global__ __launch_bounds__(512, 2) void k_gemm256(
    const u16* __restrict__ A0, int lda0, const u16* __restrict__ Bt0, int K0,
    u16* __restrict__ C0, int ldc0, float os0,
    const u16* __restrict__ A1, int lda1, const u16* __restrict__ Bt1, int K1,
    u16* __restrict__ C1, int ldc1, float os1,
    int ysplit, int swz, void* outp, const int* flag){
  __shared__ alignas(16) u16 lds[65536];   // 128 KB
  const int tid = threadIdx.x;
  const int wid = tid >> 6, lane = tid & 63;
  const int wm = wid >> 2, wn = wid & 3;
  const int l16 = lane & 15, g = lane >> 4;
  int lin = blockIdx.y * 16 + blockIdx.x;
  if (swz){
    const int q8 = (gridDim.x * gridDim.y) >> 3;
    lin = (lin & 7) * q8 + (lin >> 3);       // chunk per XCD (bijective: nwg%8==0)
  }
  int by = lin >> 4;
  const int m0 = (lin & 15) << 8;
  const u16 *A, *Bt; u16* C; int lda, K, ldc; float oscale;
  if (by < ysplit){ A = A0; lda = lda0; Bt = Bt0; K = K0; C = C0; ldc = ldc0; oscale = os0; }
  else { by -= ysplit; A = A1; lda = lda1; Bt = Bt1; K = K1; C = C1; ldc = ldc1; oscale = os1; }
  const int n0 = by << 8;
  const size_t Kz = (size_t)K;
  const int nkt = K >> 6;

  auto STAGE = [&](int kt, int bufn){
    const int kb = kt << 6;
    #pragma unroll
    for (int q = 0; q < 8; ++q){
      const int ht = q >> 1, ch = q & 1;
      const int Lb = ((ch * 8 + wid) << 10) + (lane << 4);   // byte within half-tile
      const int row = Lb >> 7;
      const int colb = (Lb & 127) ^ ((row & 7) << 4);        // inverse-swizzled source
      const u16* src;
      if (ht < 2) src = A  + (size_t)(m0 + ht * 128 + row) * lda + kb + (colb >> 1);
      else        src = Bt + (size_t)(n0 + (ht - 2) * 128 + row) * Kz + kb + (colb >> 1);
      gld_lds16(src, &lds[bufn * 32768 + ht * 8192 + ((ch * 8 + wid) << 9)]);
    }
  };

  f32x4 acc[8][4] = {};
  bf16x8 af[2][4], bf0[2][2], bf1[2][2];

  STAGE(0, 0);
  int buf = 0;

  for (int kt = 0; kt < nkt; ++kt){
    if (kt + 1 < nkt){ STAGE(kt + 1, buf ^ 1); vmwait8(); }   // wait only tile-kt's loads
    else vmwait0();
    barr();                                                    // buf resident for all waves
    // phase 0
    LDA(0);
    LDB(bf0, 0);
    barr();
    MMQ(0, 0, bf0);
    barr();
    // phase 1
    LDB(bf1, 1);
    barr();
    MMQ(0, 1, bf1);
    barr();
    // phase 2
    LDA(1);
    barr();
    MMQ(1, 0, bf0);
    barr();
    // phase 3
    MMQ(1, 1, bf1);
    barr();                                                    // reads done before next STAGE overwrites
    buf ^= 1;
  }

  const int r4 = g << 2;
  const int f = flag ? *flag : 1;
  #pragma unroll
  for (int mi8 = 0; mi8 < 8; ++mi8){
    int row = m0 + wm * 128 + mi8 * 16 + r4;
    #pragma unroll
    for (int ni4 = 0; ni4 < 4; ++ni4){
      int col = n0 + wn * 64 + ni4 * 16 + l16;
      #pragma unroll
      for (int j = 0; j < 4; ++j){
        float v = acc[mi8][ni4][j] * oscale;
        if (outp){
          if (f) ((u16*)outp)[(size_t)(row + j) * ldc + col] = f2bf(v);
          else   ((float*)outp)[(size_t)(row + j) * ldc + col] = v;
        } else {
          C[(size_t)(row + j) * ldc + col] = f2bf(v);
        }
      }
    }
  }
}

// ---------------- merged RoPE + vT build (one launch, 4096 blocks)
__global__ void k_ropevt(const u16* __restrict__ xc, const void* __restrict__ cosp,
                         const void* __restrict__ sinp, const int* flag,
                         u16* __restrict__ krope, u16* __restrict__ qrope,
                         const u16* __restrict__ kvP, u16* __restrict__ vT){
  __shared__ u16 tile[64][72];
  if (blockIdx.x < 2048){
    // RoPE from xc cols 2048..2175 (stride 2304); q-part pre-scaled by 1/sqrt(D)*log2e
    int id = blockIdx.x * 256 + threadIdx.x;   // exactly NROWS*128
    int row = id >> 7, c = id & 127;
    int t = row & (T_ - 1);
    int d = c & 63, i = d & 31;
    float cs, sn;
    if (*flag){ cs = bf2f(((const u16*)cosp)[t * 32 + i]); sn = bf2f(((const u16*)sinp)[t * 32 + i]); }
    else      { cs = ((const float*)cosp)[t * 32 + i];     sn = ((const float*)sinp)[t * 32 + i]; }
    int base = c & 64;
    float t1 = bf2f(xc[(size_t)row * 2304 + 2048 + base + i]);
    float t2 = bf2f(xc[(size_t)row * 2304 + 2048 + base + 32 + i]);
    float v = (d < 32) ? (t1 * cs - t2 * sn) : (t2 * cs + t1 * sn);
    if (c >= 64) v *= 0.12753139626374414f;
    ((c < 64) ? krope : qrope)[(size_t)row * 64 + d] = f2bf(v);
    return;
  }
  const int rel = blockIdx.x - 2048;
  const int t0 = (rel & 31) << 6, d0 = ((rel >> 5) & 1) << 6, bh = rel >> 6;
  const int b = bh >> 4, h = bh & 15;
  const int tid = threadIdx.x;
  #pragma unroll
  for (int i = 0; i < 2; ++i){
    int task = (i << 8) + tid;
    int r = task >> 3, c8 = (task & 7) << 3;
    const u16* p = kvP + (size_t)(b * T_ + t0 + r) * 3072 + 1024 + h * 128 + d0 + c8;
    u16x8 v = *reinterpret_cast<const u16x8*>(p);
    #pragma unroll
    for (int j = 0; j < 8; ++j) tile[r][c8 + j] = v[j];
  }
  __syncthreads();
  #pragma unroll
  for (int i = 0; i < 2; ++i){
    int task = (i << 8) + tid;
    int rr = task >> 3, cc8 = (task & 7) << 3;
    u16x8 v;
    #pragma unroll
    for (int j = 0; j < 8; ++j) v[j] = tile[cc8 + j][rr];
    *reinterpret_cast<u16x8*>(vT + ((size_t)bh * 128 + d0 + rr) * T_ + t0 + cc8) = v;
  }
}

// ---------------- causal flash attention, swapped-QK^T register softmax.
// Single 32KB LDS buffer; natural VGPR ~100 (<=128) + 32KB -> 4 blocks/CU.
// launch_bounds min-waves hint = 3 (cap ~170 VGPR, NO spill; (256,4) capped to 64 and spilled).
// 1024 workers, per-XCD tickets (xcd = blockIdx.x & 7); balance-preserving item map:
// r=t>>5, c=t&31, qt = (r&1) ? c : 31-c  -> each CU's 4 items sum to 66 tile-units.
__global__ __launch_bounds__(256, 3) void k_attn(const u16* __restrict__ qP,
                                                 const u16* __restrict__ kvP,
                                                 const u16* __restrict__ vT,
                                                 const u16* __restrict__ krope,
                                                 const u16* __restrict__ qrope,
                                                 u16* __restrict__ aout,
                                                 int* __restrict__ ticket){
  __shared__ alignas(16) u16 smem[16384];   // 32 KB: K [64][128] @0, V [128][64] @8192
  const int tid = threadIdx.x, wid = tid >> 6, lane = tid & 63;
  const int l16 = lane & 15, g = lane >> 4;
  const int lk = g << 3, r4 = g << 2;
  const int sw8 = (l16 & 7) << 3;
  const int xcd = blockIdx.x & 7;

  while (true){
    if (tid == 0) *(int*)&smem[0] = atomicAdd(&ticket[xcd << 4], 1);
    __syncthreads();
    const int t = *(const int*)&smem[0];
    __syncthreads();
    if (t >= 128) break;
    const int rr_ = t >> 5, cc_ = t & 31;
    const int qt = (rr_ & 1) ? cc_ : (31 - cc_);   // paired heavy/light per CU slot
    const int bh = (xcd << 2) + rr_, b = bh >> 4, h = bh & 15;
    const int q0 = qt << 6;
    const size_t bT = (size_t)b * T_;
    const u16* kvPb = kvP + bT * 3072 + (h << 6);
    const u16* krb  = krope + bT * 64;
    const u16* vTb  = vT + (size_t)bh * 128 * T_;
    const int qlo = q0 + (wid << 4);
    const int nkv = qt + 1;

    auto STAGE = [&](int k0){
      #pragma unroll
      for (int r = 0; r < 8; ++r){
        int c = (r << 8) + tid;
        const u16* src;
        if (r < 4){
          int row = c >> 4, cc = c & 15;
          int ccx = (cc & 8) | ((cc & 7) ^ (row & 7));
          int col0 = ccx << 3;
          src = (col0 < 64) ? (kvPb + (size_t)(k0 + row) * 3072 + col0)
                            : (krb  + (size_t)(k0 + row) * 64 + (col0 - 64));
        } else {
          int cv = c - 1024;
          int row = cv >> 3, cc = cv & 7;
          int ccx = cc ^ (row & 7);
          src = vTb + (size_t)row * T_ + k0 + (ccx << 3);
        }
        gld_lds16(src, &smem[(size_t)((r << 8) + (wid << 6)) << 3]);
      }
    };

    bf16x8 qf[4];
    {
      size_t grow = bT + qlo + l16;
      #pragma unroll
      for (int ks = 0; ks < 4; ++ks){
        int d = (ks << 5) + lk;
        const u16* src = (ks < 2) ? (qP + grow * 1024 + (h << 6) + d)
                                  : (qrope + grow * 64 + (d - 64));
        qf[ks] = *reinterpret_cast<const bf16x8*>(src);
      }
    }
    f32x4 o[8] = {};
    float m = -3e38f, l = 0.f;

    for (int kv = 0; kv < nkv; ++kv){
      const int k0 = kv << 6;
      STAGE(k0);
      __syncthreads();                      // drains vmcnt -> tile resident
      f32x4 s[4] = {};
      #pragma unroll
      for (int ks = 0; ks < 4; ++ks){
        int colsw = ((ks << 5) + lk) ^ sw8;
        #pragma unroll
        for (int n = 0; n < 4; ++n){
          bf16x8 kf = *reinterpret_cast<const bf16x8*>(&smem[((n << 4) + l16) * 128 + colsw]);
          s[n] = mfma16(kf, qf[ks], s[n]);
        }
      }
      if (k0 == q0){
        const int tq = qlo + l16;
        #pragma unroll
        for (int n = 0; n < 4; ++n)
          #pragma unroll
          for (int j = 0; j < 4; ++j)
            s[n][j] = (k0 + (n << 4) + r4 + j <= tq) ? s[n][j] : -3e38f;
      }
      float mx;
      {
        float a0 = fmaxf(fmaxf(s[0][0], s[0][1]), fmaxf(s[0][2], s[0][3]));
        float a1 = fmaxf(fmaxf(s[1][0], s[1][1]), fmaxf(s[1][2], s[1][3]));
        float a2 = fmaxf(fmaxf(s[2][0], s[2][1]), fmaxf(s[2][2], s[2][3]));
        float a3 = fmaxf(fmaxf(s[3][0], s[3][1]), fmaxf(s[3][2], s[3][3]));
        mx = fmaxf(fmaxf(a0, a1), fmaxf(a2, a3));
        mx = fmaxf(mx, __shfl_xor(mx, 16));
        mx = fmaxf(mx, __shfl_xor(mx, 32));
      }
      if (__ballot(mx > m + 8.f)){
        float mnew = fmaxf(m, mx);
        float alpha = exp2f(m - mnew);
        m = mnew; l *= alpha;
        #pragma unroll
        for (int j = 0; j < 4; ++j){
          float av = __shfl(alpha, r4 + j);
          #pragma unroll
          for (int db = 0; db < 8; ++db) o[db][j] *= av;
        }
      }
      unsigned w[4][2];
      float rs = 0.f;
      #pragma unroll
      for (int n = 0; n < 4; ++n)
        #pragma unroll
        for (int jh = 0; jh < 2; ++jh){
          float p0 = exp2f(s[n][2*jh]     - m);
          float p1 = exp2f(s[n][2*jh + 1] - m);
          rs += p0 + p1;
          w[n][jh] = cvt_pk_bf16(p0, p1);
        }
      rs += __shfl_xor(rs, 16);
      rs += __shfl_xor(rs, 32);
      l += rs;
      const int srcA = l16 + ((g & 1) << 5);
      const int srcB = srcA + 16;
      const bool hi = (g >= 2);
      bf16x8 pa[2];
      #pragma unroll
      for (int ks2 = 0; ks2 < 2; ++ks2){
        unsigned a0 = __shfl((int)w[2*ks2][0],     srcA);
        unsigned b0 = __shfl((int)w[2*ks2 + 1][0], srcA);
        unsigned a1 = __shfl((int)w[2*ks2][1],     srcA);
        unsigned b1 = __shfl((int)w[2*ks2 + 1][1], srcA);
        unsigned a2 = __shfl((int)w[2*ks2][0],     srcB);
        unsigned b2 = __shfl((int)w[2*ks2 + 1][0], srcB);
        unsigned a3 = __shfl((int)w[2*ks2][1],     srcB);
        unsigned b3 = __shfl((int)w[2*ks2 + 1][1], srcB);
        union { unsigned u[4]; bf16x8 v; } pk;
        pk.u[0] = hi ? b0 : a0;
        pk.u[1] = hi ? b1 : a1;
        pk.u[2] = hi ? b2 : a2;
        pk.u[3] = hi ? b3 : a3;
        pa[ks2] = pk.v;
      }
      #pragma unroll
      for (int ks2 = 0; ks2 < 2; ++ks2){
        int colsw = ((ks2 << 5) + lk) ^ sw8;
        #pragma unroll
        for (int db = 0; db < 8; ++db){
          bf16x8 vb = *reinterpret_cast<const bf16x8*>(&smem[8192 + ((db << 4) + l16) * 64 + colsw]);
          o[db] = mfma16(pa[ks2], vb, o[db]);
        }
      }
      __syncthreads();                      // reads done before next STAGE overwrites
    }
    #pragma unroll
    for (int j = 0; j < 4; ++j){
      float lv = __shfl(l, r4 + j);
      float rinv = 1.f / lv;
      const int tq = qlo + r4 + j;
      u16* dst = aout + (bT + tq) * 2048 + (h << 7) + l16;
      #pragma unroll
      for (int db = 0; db < 8; ++db)
        dst[db << 4] = f2bf(o[db][j] * rinv);
    }
  }
}

extern "C" void kernel_launch(void* const* d_in, const int* in_sizes, int n_in,
                              void* d_out, int out_size, void* d_ws, size_t ws_size,
                              hipStream_t stream){
  const void* x       = d_in[0];
  const void* cosp    = d_in[1];
  const void* sinp    = d_in[2];
  const void* w_kv    = d_in[3];
  const void* w_kdec  = d_in[4];
  const void* w_vdec  = d_in[5];
  const void* w_qc    = d_in[6];
  const void* w_qdec  = d_in[7];
  const void* w_krope = d_in[8];
  const void* w_qrope = d_in[9];
  const void* w_o     = d_in[10];

  char* ws = (char*)d_ws;
  size_t off = 0;
  auto alloc = [&](size_t bytes){ void* p = ws + off; off += (bytes + 255) & ~(size_t)255; return p; };
  int* flag     = (int*)alloc(256);
  int* ticket   = (int*)alloc(1024);                         // 8 tickets, stride 16 ints
  u16* x_bf     = (u16*)alloc((size_t)NROWS * DIM_ * 2);
  u16* w_c1T    = (u16*)alloc((size_t)2304 * DIM_ * 2);      // [kvT(512); qcT(1536); kropeT(64); qropeT(64); pad(128)] x 2048
  u16* w_kvdT   = (u16*)alloc((size_t)3072 * DC_ * 2);       // [kdecPackedT(1024); vdecT(2048)] x 512
  u16* w_qdPT   = (u16*)alloc((size_t)1024 * DCQ_ * 2);      // packed qdecT (1024 x 1536)
  u16* w_oT     = (u16*)alloc((size_t)DIM_ * DIM_ * 2);
  u16* xc       = (u16*)alloc((size_t)NROWS * 2304 * 2);     // [c_kv(512) | c_q(1536) | ropes(128) | pad(128)]
  u16* qP       = (u16*)alloc((size_t)NROWS * 1024 * 2);     // packed q decode (pre-scaled)
  u16* kvP      = (u16*)alloc((size_t)NROWS * 3072 * 2);     // [kPacked(1024) | v(2048)]
  u16* krope    = (u16*)alloc((size_t)NROWS * 64 * 2);
  u16* qrope    = (u16*)alloc((size_t)NROWS * 64 * 2);       // pre-scaled
  u16* vT       = (u16*)alloc((size_t)32 * 128 * T_ * 2);    // [bh][d][t]
  u16* aout     = (u16*)alloc((size_t)NROWS * DIM_ * 2);
  (void)in_sizes; (void)n_in; (void)out_size; (void)ws_size;

  const float SC2 = 0.12753139626374414f;   // 1/sqrt(128) * log2(e)

  hipLaunchKernelGGL(k_detect, dim3(1), dim3(128), 0, stream, (const u16*)cosp, flag, ticket);

  // merged x-convert + weight transposes (8192 conv blocks + 2880 transpose blocks)
  TPack tp;
  tp.d[0] = { w_kv,    w_c1T,                        512,  2048, 64,  8,  0    };
  tp.d[1] = { w_qc,    w_c1T + (size_t)512 * 2048,   1536, 2048, 64,  24, 256  };
  tp.d[2] = { w_krope, w_c1T + (size_t)2048 * 2048,  64,   2048, 64,  1,  1024 };
  tp.d[3] = { w_qrope, w_c1T + (size_t)2112 * 2048,  64,   2048, 64,  1,  1056 };
  tp.d[4] = { w_kdec,  w_kvdT,                       2048, 512,  128, 16, 1088 };
  tp.d[5] = { w_vdec,  w_kvdT + (size_t)1024 * 512,  2048, 512,  64,  32, 1216 };
  tp.d[6] = { w_qdec,  w_qdPT,                       2048, 1536, 128, 16, 1472 };
  tp.d[7] = { w_o,     w_oT,                         2048, 2048, 64,  32, 1856 };
  hipLaunchKernelGGL(k_prep, dim3(CONVBLK + 2880), dim3(256), 0, stream, x, x_bf, tp, flag);

  // G13: xc = x @ [w_kv | w_qc | w_krope | w_qrope | pad]  (4096 x 2304, K=2048), XCD-chunked
  hipLaunchKernelGGL(k_gemm256, dim3(16, 9), dim3(512), 0, stream,
                     x_bf, DIM_, w_c1T, DIM_, xc, 2304, 1.0f,
                     x_bf, DIM_, w_c1T, DIM_, xc, 2304, 1.0f,
                     9, 1, (void*)nullptr, (const int*)nullptr);
  // G2 + G4 grouped (256 blocks, linear order: groups have unequal K -> keep round-robin)
  hipLaunchKernelGGL(k_gemm256, dim3(16, 16), dim3(512), 0, stream,
                     xc, 2304, w_kvdT, DC_, kvP, 3072, 1.0f,
                     xc + 512, 2304, w_qdPT, DCQ_, qP, 1024, SC2,
                     12, 0, (void*)nullptr, (const int*)nullptr);
  // merged RoPE + vT (2048 + 2048 blocks)
  hipLaunchKernelGGL(k_ropevt, dim3(4096), dim3(256), 0, stream,
                     xc, cosp, sinp, flag, krope, qrope, kvP, vT);
  // attention (1024 workers -> 4 blocks/CU at ~100 VGPR + 32KB LDS, XCD-partitioned tickets)
  hipLaunchKernelGGL(k_attn, dim3(1024), dim3(256), 0, stream,
                     qP, kvP, vT, krope, qrope, aout, ticket);
  // G5: out = aout @ w_o  (4096 x 2048, K=2048; writes d_out, dtype per flag), XCD-chunked
  hipLaunchKernelGGL(k_gemm256, dim3(16, 8), dim3(512), 0, stream,
                     aout, DIM_, w_oT, DIM_, (u16*)nullptr, DIM_, 1.0f,
                     aout, DIM_, w_oT, DIM_, (u16*)nullptr, DIM_, 1.0f,
                     8, 1, d_out, (const int*)flag);
}

// Round 12
// 315.632 us; speedup vs baseline: 1.1139x; 1.0737x over previous
//
#include <hip/hip_runtime.h>
#include <stdint.h>
#include <math.h>

#define B_    2
#define T_    2048
#define DIM_  2048
#define H_    16
#define DC_   512
#define DCQ_  1536
#define NROWS (B_*T_)   // 4096

typedef unsigned short u16;
typedef __attribute__((ext_vector_type(8))) __bf16 bf16x8;
typedef __attribute__((ext_vector_type(4))) float  f32x4;
typedef __attribute__((ext_vector_type(8))) unsigned short u16x8;
typedef __attribute__((ext_vector_type(4))) float  f4v;

__device__ __forceinline__ u16 f2bf(float f){
  unsigned u = __float_as_uint(f);
  u += 0x7FFFu + ((u >> 16) & 1u);   // RNE
  return (u16)(u >> 16);
}
__device__ __forceinline__ float bf2f(u16 h){ return __uint_as_float(((unsigned)h) << 16); }

__device__ __forceinline__ unsigned cvt_pk_bf16(float lo, float hi){
  unsigned r;
  asm("v_cvt_pk_bf16_f32 %0, %1, %2" : "=v"(r) : "v"(lo), "v"(hi));
  return r;
}

// async global->LDS, 16B per lane; LDS dest = wave-uniform base + lane*16.
__device__ __forceinline__ void gld_lds16(const void* g, void* l){
  auto gp = reinterpret_cast<__attribute__((address_space(1))) unsigned int*>(
      reinterpret_cast<uintptr_t>(g));
  auto lp = reinterpret_cast<__attribute__((address_space(3))) unsigned int*>(
      reinterpret_cast<uintptr_t>(l));
  __builtin_amdgcn_global_load_lds(gp, lp, 16, 0, 0);
}

__device__ __forceinline__ f32x4 mfma16(bf16x8 a, bf16x8 b, f32x4 c){
  return __builtin_amdgcn_mfma_f32_16x16x32_bf16(a, b, c, 0, 0, 0);
}

__device__ __forceinline__ void vmwait0(){ asm volatile("s_waitcnt vmcnt(0)" ::: "memory"); }
__device__ __forceinline__ void vmwait8(){ asm volatile("s_waitcnt vmcnt(8)" ::: "memory"); }
__device__ __forceinline__ void barr(){ asm volatile("s_barrier" ::: "memory"); }

// ---------------- dtype detect + ticket reset (8 XCD-partition tickets, stride 16)
__global__ void k_detect(const u16* cosr, int* flag, int* ticket){
  if (threadIdx.x == 0) *flag = (cosr[0] == (u16)0x3F80u) ? 1 : 0;
  if (threadIdx.x < 128) ticket[threadIdx.x] = 0;
}

// ---------------- merged x-convert + 8 weight transposes (one launch)
struct TDesc { const void* src; u16* dst; int srcStride, dstStride, cblk, nbx, blk0; };
struct TPack { TDesc d[8]; };
#define CONVBLK 8192

__global__ void k_prep(const void* __restrict__ xsrc, u16* __restrict__ x_bf,
                       TPack p, const int* flag){
  __shared__ u16 tile[64][72];
  const int bid = blockIdx.x;
  const int tid = threadIdx.x;
  const int f = *flag;
  if (bid < CONVBLK){
    int id = bid * 256 + tid;                 // n4 = 2097152 = 8192*256 exactly
    if (f){
      reinterpret_cast<uint2*>(x_bf)[id] = reinterpret_cast<const uint2*>(xsrc)[id];
    } else {
      f4v v = reinterpret_cast<const f4v*>(xsrc)[id];
      unsigned lo = (unsigned)f2bf(v.x) | ((unsigned)f2bf(v.y) << 16);
      unsigned hi = (unsigned)f2bf(v.z) | ((unsigned)f2bf(v.w) << 16);
      reinterpret_cast<uint2*>(x_bf)[id] = make_uint2(lo, hi);
    }
    return;
  }
  const int tb = bid - CONVBLK;
  int i = 0;
  #pragma unroll
  for (int k = 1; k < 8; ++k) if (tb >= p.d[k].blk0) i = k;
  const void* src = p.d[i].src;
  u16* dst = p.d[i].dst;
  const int srcStride = p.d[i].srcStride, dstStride = p.d[i].dstStride;
  const int rel = tb - p.d[i].blk0;
  const int bx = rel % p.d[i].nbx, by = rel / p.d[i].nbx;
  const int r0 = by << 6, c0 = bx * p.d[i].cblk;
  #pragma unroll
  for (int it = 0; it < 2; ++it){
    int task = (it << 8) + tid;
    int r = task >> 3, c8 = (task & 7) << 3;
    if (f){
      const u16* pp = (const u16*)src + (size_t)(r0 + r) * srcStride + c0 + c8;
      u16x8 v = *reinterpret_cast<const u16x8*>(pp);
      #pragma unroll
      for (int j = 0; j < 8; ++j) tile[r][c8 + j] = v[j];
    } else {
      const float* pp = (const float*)src + (size_t)(r0 + r) * srcStride + c0 + c8;
      f4v a = reinterpret_cast<const f4v*>(pp)[0];
      f4v b = reinterpret_cast<const f4v*>(pp)[1];
      tile[r][c8+0]=f2bf(a.x); tile[r][c8+1]=f2bf(a.y); tile[r][c8+2]=f2bf(a.z); tile[r][c8+3]=f2bf(a.w);
      tile[r][c8+4]=f2bf(b.x); tile[r][c8+5]=f2bf(b.y); tile[r][c8+6]=f2bf(b.z); tile[r][c8+7]=f2bf(b.w);
    }
  }
  __syncthreads();
  #pragma unroll
  for (int it = 0; it < 2; ++it){
    int task = (it << 8) + tid;
    int rr = task >> 3, cc8 = (task & 7) << 3;
    u16x8 v;
    #pragma unroll
    for (int j = 0; j < 8; ++j) v[j] = tile[cc8 + j][rr];
    *reinterpret_cast<u16x8*>(dst + (size_t)((bx << 6) + rr) * dstStride + r0 + cc8) = v;
  }
}

// ---------------- 256x256 8-phase GEMM, counted-vmcnt pipeline (2 groups by by-index).
// Optional bijective XCD-chunked swizzle (swz=1; nwg must be divisible by 8, gridDim.x==16).
// Row-XOR swizzle byte ^= ((row&7)<<4) via inverse-swizzled global sources.
#define MMQ(MH, NH, BFR) do{ \
  __builtin_amdgcn_s_setprio(1); \
  _Pragma("unroll") for (int ks = 0; ks < 2; ++ks) \
    _Pragma("unroll") for (int mi = 0; mi < 4; ++mi) \
      _Pragma("unroll") for (int ni = 0; ni < 2; ++ni) \
        acc[(MH)*4+mi][(NH)*2+ni] = mfma16(af[ks][mi], BFR[ks][ni], acc[(MH)*4+mi][(NH)*2+ni]); \
  __builtin_amdgcn_s_setprio(0); \
}while(0)

#define LDA(MH) do{ \
  _Pragma("unroll") for (int ks = 0; ks < 2; ++ks) \
    _Pragma("unroll") for (int mi = 0; mi < 4; ++mi){ \
      int row = (MH)*64 + mi*16 + l16; \
      int cb = ((ks << 6) + (g << 4)) ^ ((row & 7) << 4); \
      af[ks][mi] = *reinterpret_cast<const bf16x8*>(&lds[buf*32768 + wm*8192 + (((row << 7) + cb) >> 1)]); \
    } \
}while(0)

#define LDB(DST, NH) do{ \
  _Pragma("unroll") for (int ks = 0; ks < 2; ++ks) \
    _Pragma("unroll") for (int ni = 0; ni < 2; ++ni){ \
      int row = ((wn & 1) * 64) + (NH)*32 + ni*16 + l16; \
      int cb = ((ks << 6) + (g << 4)) ^ ((row & 7) << 4); \
      DST[ks][ni] = *reinterpret_cast<const bf16x8*>(&lds[buf*32768 + 16384 + (wn >> 1)*8192 + (((row << 7) + cb) >> 1)]); \
    } \
}while(0)

__global__ __launch_bounds__(512, 2) void k_gemm256(
    const u16* __restrict__ A0, int lda0, const u16* __restrict__ Bt0, int K0,
    u16* __restrict__ C0, int ldc0, float os0,
    const u16* __restrict__ A1, int lda1, const u16* __restrict__ Bt1, int K1,
    u16* __restrict__ C1, int ldc1, float os1,
    int ysplit, int swz, void* outp, const int* flag){
  __shared__ alignas(16) u16 lds[65536];   // 128 KB
  const int tid = threadIdx.x;
  const int wid = tid >> 6, lane = tid & 63;
  const int wm = wid >> 2, wn = wid & 3;
  const int l16 = lane & 15, g = lane >> 4;
  int lin = blockIdx.y * 16 + blockIdx.x;
  if (swz){
    const int q8 = (gridDim.x * gridDim.y) >> 3;
    lin = (lin & 7) * q8 + (lin >> 3);       // chunk per XCD (bijective: nwg%8==0)
  }
  int by = lin >> 4;
  const int m0 = (lin & 15) << 8;
  const u16 *A, *Bt; u16* C; int lda, K, ldc; float oscale;
  if (by < ysplit){ A = A0; lda = lda0; Bt = Bt0; K = K0; C = C0; ldc = ldc0; oscale = os0; }
  else { by -= ysplit; A = A1; lda = lda1; Bt = Bt1; K = K1; C = C1; ldc = ldc1; oscale = os1; }
  const int n0 = by << 8;
  const size_t Kz = (size_t)K;
  const int nkt = K >> 6;

  auto STAGE = [&](int kt, int bufn){
    const int kb = kt << 6;
    #pragma unroll
    for (int q = 0; q < 8; ++q){
      const int ht = q >> 1, ch = q & 1;
      const int Lb = ((ch * 8 + wid) << 10) + (lane << 4);   // byte within half-tile
      const int row = Lb >> 7;
      const int colb = (Lb & 127) ^ ((row & 7) << 4);        // inverse-swizzled source
      const u16* src;
      if (ht < 2) src = A  + (size_t)(m0 + ht * 128 + row) * lda + kb + (colb >> 1);
      else        src = Bt + (size_t)(n0 + (ht - 2) * 128 + row) * Kz + kb + (colb >> 1);
      gld_lds16(src, &lds[bufn * 32768 + ht * 8192 + ((ch * 8 + wid) << 9)]);
    }
  };

  f32x4 acc[8][4] = {};
  bf16x8 af[2][4], bf0[2][2], bf1[2][2];

  STAGE(0, 0);
  int buf = 0;

  for (int kt = 0; kt < nkt; ++kt){
    if (kt + 1 < nkt){ STAGE(kt + 1, buf ^ 1); vmwait8(); }   // wait only tile-kt's loads
    else vmwait0();
    barr();                                                    // buf resident for all waves
    // phase 0
    LDA(0);
    LDB(bf0, 0);
    barr();
    MMQ(0, 0, bf0);
    barr();
    // phase 1
    LDB(bf1, 1);
    barr();
    MMQ(0, 1, bf1);
    barr();
    // phase 2
    LDA(1);
    barr();
    MMQ(1, 0, bf0);
    barr();
    // phase 3
    MMQ(1, 1, bf1);
    barr();                                                    // reads done before next STAGE overwrites
    buf ^= 1;
  }

  const int r4 = g << 2;
  const int f = flag ? *flag : 1;
  #pragma unroll
  for (int mi8 = 0; mi8 < 8; ++mi8){
    int row = m0 + wm * 128 + mi8 * 16 + r4;
    #pragma unroll
    for (int ni4 = 0; ni4 < 4; ++ni4){
      int col = n0 + wn * 64 + ni4 * 16 + l16;
      #pragma unroll
      for (int j = 0; j < 4; ++j){
        float v = acc[mi8][ni4][j] * oscale;
        if (outp){
          if (f) ((u16*)outp)[(size_t)(row + j) * ldc + col] = f2bf(v);
          else   ((float*)outp)[(size_t)(row + j) * ldc + col] = v;
        } else {
          C[(size_t)(row + j) * ldc + col] = f2bf(v);
        }
      }
    }
  }
}

// ---------------- merged RoPE + vT build (one launch, 4096 blocks)
__global__ void k_ropevt(const u16* __restrict__ xc, const void* __restrict__ cosp,
                         const void* __restrict__ sinp, const int* flag,
                         u16* __restrict__ krope, u16* __restrict__ qrope,
                         const u16* __restrict__ kvP, u16* __restrict__ vT){
  __shared__ u16 tile[64][72];
  if (blockIdx.x < 2048){
    // RoPE from xc cols 2048..2175 (stride 2304); q-part pre-scaled by 1/sqrt(D)*log2e
    int id = blockIdx.x * 256 + threadIdx.x;   // exactly NROWS*128
    int row = id >> 7, c = id & 127;
    int t = row & (T_ - 1);
    int d = c & 63, i = d & 31;
    float cs, sn;
    if (*flag){ cs = bf2f(((const u16*)cosp)[t * 32 + i]); sn = bf2f(((const u16*)sinp)[t * 32 + i]); }
    else      { cs = ((const float*)cosp)[t * 32 + i];     sn = ((const float*)sinp)[t * 32 + i]; }
    int base = c & 64;
    float t1 = bf2f(xc[(size_t)row * 2304 + 2048 + base + i]);
    float t2 = bf2f(xc[(size_t)row * 2304 + 2048 + base + 32 + i]);
    float v = (d < 32) ? (t1 * cs - t2 * sn) : (t2 * cs + t1 * sn);
    if (c >= 64) v *= 0.12753139626374414f;
    ((c < 64) ? krope : qrope)[(size_t)row * 64 + d] = f2bf(v);
    return;
  }
  const int rel = blockIdx.x - 2048;
  const int t0 = (rel & 31) << 6, d0 = ((rel >> 5) & 1) << 6, bh = rel >> 6;
  const int b = bh >> 4, h = bh & 15;
  const int tid = threadIdx.x;
  #pragma unroll
  for (int i = 0; i < 2; ++i){
    int task = (i << 8) + tid;
    int r = task >> 3, c8 = (task & 7) << 3;
    const u16* p = kvP + (size_t)(b * T_ + t0 + r) * 3072 + 1024 + h * 128 + d0 + c8;
    u16x8 v = *reinterpret_cast<const u16x8*>(p);
    #pragma unroll
    for (int j = 0; j < 8; ++j) tile[r][c8 + j] = v[j];
  }
  __syncthreads();
  #pragma unroll
  for (int i = 0; i < 2; ++i){
    int task = (i << 8) + tid;
    int rr = task >> 3, cc8 = (task & 7) << 3;
    u16x8 v;
    #pragma unroll
    for (int j = 0; j < 8; ++j) v[j] = tile[cc8 + j][rr];
    *reinterpret_cast<u16x8*>(vT + ((size_t)bh * 128 + d0 + rr) * T_ + t0 + cc8) = v;
  }
}

// ---------------- causal flash attention, swapped-QK^T register softmax.
// Single 32KB LDS buffer; launch_bounds (256,2): the ONLY no-spill config measured
// (rounds 6-9: VGPR=100, WRITE=16.4MB; (256,4)->64 VGPR spill; (256,3)->84 VGPR spill).
// Occupancy comes from resources: 100 VGPR + 32KB LDS -> 4-5 blocks/CU naturally.
// 1024 workers, per-XCD tickets; consecutive tickets alternate heavy/light:
// qt = (c&1) ? c>>1 : 31-(c>>1)  -> any 4-consecutive window sums ~62-66 tiles.
__global__ __launch_bounds__(256, 2) void k_attn(const u16* __restrict__ qP,
                                                 const u16* __restrict__ kvP,
                                                 const u16* __restrict__ vT,
                                                 const u16* __restrict__ krope,
                                                 const u16* __restrict__ qrope,
                                                 u16* __restrict__ aout,
                                                 int* __restrict__ ticket){
  __shared__ alignas(16) u16 smem[16384];   // 32 KB: K [64][128] @0, V [128][64] @8192
  const int tid = threadIdx.x, wid = tid >> 6, lane = tid & 63;
  const int l16 = lane & 15, g = lane >> 4;
  const int lk = g << 3, r4 = g << 2;
  const int sw8 = (l16 & 7) << 3;
  const int xcd = blockIdx.x & 7;

  while (true){
    if (tid == 0) *(int*)&smem[0] = atomicAdd(&ticket[xcd << 4], 1);
    __syncthreads();
    const int t = *(const int*)&smem[0];
    __syncthreads();
    if (t >= 128) break;
    const int rr_ = t >> 5, cc_ = t & 31;
    const int qt = (cc_ & 1) ? (cc_ >> 1) : (31 - (cc_ >> 1));   // heavy/light interleave
    const int bh = (xcd << 2) + rr_, b = bh >> 4, h = bh & 15;
    const int q0 = qt << 6;
    const size_t bT = (size_t)b * T_;
    const u16* kvPb = kvP + bT * 3072 + (h << 6);
    const u16* krb  = krope + bT * 64;
    const u16* vTb  = vT + (size_t)bh * 128 * T_;
    const int qlo = q0 + (wid << 4);
    const int nkv = qt + 1;

    auto STAGE = [&](int k0){
      #pragma unroll
      for (int r = 0; r < 8; ++r){
        int c = (r << 8) + tid;
        const u16* src;
        if (r < 4){
          int row = c >> 4, cc = c & 15;
          int ccx = (cc & 8) | ((cc & 7) ^ (row & 7));
          int col0 = ccx << 3;
          src = (col0 < 64) ? (kvPb + (size_t)(k0 + row) * 3072 + col0)
                            : (krb  + (size_t)(k0 + row) * 64 + (col0 - 64));
        } else {
          int cv = c - 1024;
          int row = cv >> 3, cc = cv & 7;
          int ccx = cc ^ (row & 7);
          src = vTb + (size_t)row * T_ + k0 + (ccx << 3);
        }
        gld_lds16(src, &smem[(size_t)((r << 8) + (wid << 6)) << 3]);
      }
    };

    bf16x8 qf[4];
    {
      size_t grow = bT + qlo + l16;
      #pragma unroll
      for (int ks = 0; ks < 4; ++ks){
        int d = (ks << 5) + lk;
        const u16* src = (ks < 2) ? (qP + grow * 1024 + (h << 6) + d)
                                  : (qrope + grow * 64 + (d - 64));
        qf[ks] = *reinterpret_cast<const bf16x8*>(src);
      }
    }
    f32x4 o[8] = {};
    float m = -3e38f, l = 0.f;

    for (int kv = 0; kv < nkv; ++kv){
      const int k0 = kv << 6;
      STAGE(k0);
      __syncthreads();                      // drains vmcnt -> tile resident
      f32x4 s[4] = {};
      #pragma unroll
      for (int ks = 0; ks < 4; ++ks){
        int colsw = ((ks << 5) + lk) ^ sw8;
        #pragma unroll
        for (int n = 0; n < 4; ++n){
          bf16x8 kf = *reinterpret_cast<const bf16x8*>(&smem[((n << 4) + l16) * 128 + colsw]);
          s[n] = mfma16(kf, qf[ks], s[n]);
        }
      }
      if (k0 == q0){
        const int tq = qlo + l16;
        #pragma unroll
        for (int n = 0; n < 4; ++n)
          #pragma unroll
          for (int j = 0; j < 4; ++j)
            s[n][j] = (k0 + (n << 4) + r4 + j <= tq) ? s[n][j] : -3e38f;
      }
      float mx;
      {
        float a0 = fmaxf(fmaxf(s[0][0], s[0][1]), fmaxf(s[0][2], s[0][3]));
        float a1 = fmaxf(fmaxf(s[1][0], s[1][1]), fmaxf(s[1][2], s[1][3]));
        float a2 = fmaxf(fmaxf(s[2][0], s[2][1]), fmaxf(s[2][2], s[2][3]));
        float a3 = fmaxf(fmaxf(s[3][0], s[3][1]), fmaxf(s[3][2], s[3][3]));
        mx = fmaxf(fmaxf(a0, a1), fmaxf(a2, a3));
        mx = fmaxf(mx, __shfl_xor(mx, 16));
        mx = fmaxf(mx, __shfl_xor(mx, 32));
      }
      if (__ballot(mx > m + 8.f)){
        float mnew = fmaxf(m, mx);
        float alpha = exp2f(m - mnew);
        m = mnew; l *= alpha;
        #pragma unroll
        for (int j = 0; j < 4; ++j){
          float av = __shfl(alpha, r4 + j);
          #pragma unroll
          for (int db = 0; db < 8; ++db) o[db][j] *= av;
        }
      }
      unsigned w[4][2];
      float rs = 0.f;
      #pragma unroll
      for (int n = 0; n < 4; ++n)
        #pragma unroll
        for (int jh = 0; jh < 2; ++jh){
          float p0 = exp2f(s[n][2*jh]     - m);
          float p1 = exp2f(s[n][2*jh + 1] - m);
          rs += p0 + p1;
          w[n][jh] = cvt_pk_bf16(p0, p1);
        }
      rs += __shfl_xor(rs, 16);
      rs += __shfl_xor(rs, 32);
      l += rs;
      const int srcA = l16 + ((g & 1) << 5);
      const int srcB = srcA + 16;
      const bool hi = (g >= 2);
      bf16x8 pa[2];
      #pragma unroll
      for (int ks2 = 0; ks2 < 2; ++ks2){
        unsigned a0 = __shfl((int)w[2*ks2][0],     srcA);
        unsigned b0 = __shfl((int)w[2*ks2 + 1][0], srcA);
        unsigned a1 = __shfl((int)w[2*ks2][1],     srcA);
        unsigned b1 = __shfl((int)w[2*ks2 + 1][1], srcA);
        unsigned a2 = __shfl((int)w[2*ks2][0],     srcB);
        unsigned b2 = __shfl((int)w[2*ks2 + 1][0], srcB);
        unsigned a3 = __shfl((int)w[2*ks2][1],     srcB);
        unsigned b3 = __shfl((int)w[2*ks2 + 1][1], srcB);
        union { unsigned u[4]; bf16x8 v; } pk;
        pk.u[0] = hi ? b0 : a0;
        pk.u[1] = hi ? b1 : a1;
        pk.u[2] = hi ? b2 : a2;
        pk.u[3] = hi ? b3 : a3;
        pa[ks2] = pk.v;
      }
      #pragma unroll
      for (int ks2 = 0; ks2 < 2; ++ks2){
        int colsw = ((ks2 << 5) + lk) ^ sw8;
        #pragma unroll
        for (int db = 0; db < 8; ++db){
          bf16x8 vb = *reinterpret_cast<const bf16x8*>(&smem[8192 + ((db << 4) + l16) * 64 + colsw]);
          o[db] = mfma16(pa[ks2], vb, o[db]);
        }
      }
      __syncthreads();                      // reads done before next STAGE overwrites
    }
    #pragma unroll
    for (int j = 0; j < 4; ++j){
      float lv = __shfl(l, r4 + j);
      float rinv = 1.f / lv;
      const int tq = qlo + r4 + j;
      u16* dst = aout + (bT + tq) * 2048 + (h << 7) + l16;
      #pragma unroll
      for (int db = 0; db < 8; ++db)
        dst[db << 4] = f2bf(o[db][j] * rinv);
    }
  }
}

extern "C" void kernel_launch(void* const* d_in, const int* in_sizes, int n_in,
                              void* d_out, int out_size, void* d_ws, size_t ws_size,
                              hipStream_t stream){
  const void* x       = d_in[0];
  const void* cosp    = d_in[1];
  const void* sinp    = d_in[2];
  const void* w_kv    = d_in[3];
  const void* w_kdec  = d_in[4];
  const void* w_vdec  = d_in[5];
  const void* w_qc    = d_in[6];
  const void* w_qdec  = d_in[7];
  const void* w_krope = d_in[8];
  const void* w_qrope = d_in[9];
  const void* w_o     = d_in[10];

  char* ws = (char*)d_ws;
  size_t off = 0;
  auto alloc = [&](size_t bytes){ void* p = ws + off; off += (bytes + 255) & ~(size_t)255; return p; };
  int* flag     = (int*)alloc(256);
  int* ticket   = (int*)alloc(1024);                         // 8 tickets, stride 16 ints
  u16* x_bf     = (u16*)alloc((size_t)NROWS * DIM_ * 2);
  u16* w_c1T    = (u16*)alloc((size_t)2304 * DIM_ * 2);      // [kvT(512); qcT(1536); kropeT(64); qropeT(64); pad(128)] x 2048
  u16* w_kvdT   = (u16*)alloc((size_t)3072 * DC_ * 2);       // [kdecPackedT(1024); vdecT(2048)] x 512
  u16* w_qdPT   = (u16*)alloc((size_t)1024 * DCQ_ * 2);      // packed qdecT (1024 x 1536)
  u16* w_oT     = (u16*)alloc((size_t)DIM_ * DIM_ * 2);
  u16* xc       = (u16*)alloc((size_t)NROWS * 2304 * 2);     // [c_kv(512) | c_q(1536) | ropes(128) | pad(128)]
  u16* qP       = (u16*)alloc((size_t)NROWS * 1024 * 2);     // packed q decode (pre-scaled)
  u16* kvP      = (u16*)alloc((size_t)NROWS * 3072 * 2);     // [kPacked(1024) | v(2048)]
  u16* krope    = (u16*)alloc((size_t)NROWS * 64 * 2);
  u16* qrope    = (u16*)alloc((size_t)NROWS * 64 * 2);       // pre-scaled
  u16* vT       = (u16*)alloc((size_t)32 * 128 * T_ * 2);    // [bh][d][t]
  u16* aout     = (u16*)alloc((size_t)NROWS * DIM_ * 2);
  (void)in_sizes; (void)n_in; (void)out_size; (void)ws_size;

  const float SC2 = 0.12753139626374414f;   // 1/sqrt(128) * log2(e)

  hipLaunchKernelGGL(k_detect, dim3(1), dim3(128), 0, stream, (const u16*)cosp, flag, ticket);

  // merged x-convert + weight transposes (8192 conv blocks + 2880 transpose blocks)
  TPack tp;
  tp.d[0] = { w_kv,    w_c1T,                        512,  2048, 64,  8,  0    };
  tp.d[1] = { w_qc,    w_c1T + (size_t)512 * 2048,   1536, 2048, 64,  24, 256  };
  tp.d[2] = { w_krope, w_c1T + (size_t)2048 * 2048,  64,   2048, 64,  1,  1024 };
  tp.d[3] = { w_qrope, w_c1T + (size_t)2112 * 2048,  64,   2048, 64,  1,  1056 };
  tp.d[4] = { w_kdec,  w_kvdT,                       2048, 512,  128, 16, 1088 };
  tp.d[5] = { w_vdec,  w_kvdT + (size_t)1024 * 512,  2048, 512,  64,  32, 1216 };
  tp.d[6] = { w_qdec,  w_qdPT,                       2048, 1536, 128, 16, 1472 };
  tp.d[7] = { w_o,     w_oT,                         2048, 2048, 64,  32, 1856 };
  hipLaunchKernelGGL(k_prep, dim3(CONVBLK + 2880), dim3(256), 0, stream, x, x_bf, tp, flag);

  // G13: xc = x @ [w_kv | w_qc | w_krope | w_qrope | pad]  (4096 x 2304, K=2048), XCD-chunked
  hipLaunchKernelGGL(k_gemm256, dim3(16, 9), dim3(512), 0, stream,
                     x_bf, DIM_, w_c1T, DIM_, xc, 2304, 1.0f,
                     x_bf, DIM_, w_c1T, DIM_, xc, 2304, 1.0f,
                     9, 1, (void*)nullptr, (const int*)nullptr);
  // G2 + G4 grouped (256 blocks, linear order: groups have unequal K -> keep round-robin)
  hipLaunchKernelGGL(k_gemm256, dim3(16, 16), dim3(512), 0, stream,
                     xc, 2304, w_kvdT, DC_, kvP, 3072, 1.0f,
                     xc + 512, 2304, w_qdPT, DCQ_, qP, 1024, SC2,
                     12, 0, (void*)nullptr, (const int*)nullptr);
  // merged RoPE + vT (2048 + 2048 blocks)
  hipLaunchKernelGGL(k_ropevt, dim3(4096), dim3(256), 0, stream,
                     xc, cosp, sinp, flag, krope, qrope, kvP, vT);
  // attention (1024 workers, XCD-partitioned tickets; (256,2) no-spill, 4-5 blocks/CU)
  hipLaunchKernelGGL(k_attn, dim3(1024), dim3(256), 0, stream,
                     qP, kvP, vT, krope, qrope, aout, ticket);
  // G5: out = aout @ w_o  (4096 x 2048, K=2048; writes d_out, dtype per flag), XCD-chunked
  hipLaunchKernelGGL(k_gemm256, dim3(16, 8), dim3(512), 0, stream,
                     aout, DIM_, w_oT, DIM_, (u16*)nullptr, DIM_, 1.0f,
                     aout, DIM_, w_oT, DIM_, (u16*)nullptr, DIM_, 1.0f,
                     8, 1, d_out, (const int*)flag);
}

// Round 13
// 300.363 us; speedup vs baseline: 1.1705x; 1.0508x over previous
//
#include <hip/hip_runtime.h>
#include <stdint.h>
#include <math.h>

#define B_    2
#define T_    2048
#define DIM_  2048
#define H_    16
#define DC_   512
#define DCQ_  1536
#define NROWS (B_*T_)   // 4096

typedef unsigned short u16;
typedef __attribute__((ext_vector_type(8))) __bf16 bf16x8;
typedef __attribute__((ext_vector_type(4))) float  f32x4;
typedef __attribute__((ext_vector_type(8))) unsigned short u16x8;
typedef __attribute__((ext_vector_type(4))) float  f4v;

__device__ __forceinline__ u16 f2bf(float f){
  unsigned u = __float_as_uint(f);
  u += 0x7FFFu + ((u >> 16) & 1u);   // RNE
  return (u16)(u >> 16);
}
__device__ __forceinline__ float bf2f(u16 h){ return __uint_as_float(((unsigned)h) << 16); }

__device__ __forceinline__ unsigned cvt_pk_bf16(float lo, float hi){
  unsigned r;
  asm("v_cvt_pk_bf16_f32 %0, %1, %2" : "=v"(r) : "v"(lo), "v"(hi));
  return r;
}

// async global->LDS, 16B per lane; LDS dest = wave-uniform base + lane*16.
__device__ __forceinline__ void gld_lds16(const void* g, void* l){
  auto gp = reinterpret_cast<__attribute__((address_space(1))) unsigned int*>(
      reinterpret_cast<uintptr_t>(g));
  auto lp = reinterpret_cast<__attribute__((address_space(3))) unsigned int*>(
      reinterpret_cast<uintptr_t>(l));
  __builtin_amdgcn_global_load_lds(gp, lp, 16, 0, 0);
}

__device__ __forceinline__ f32x4 mfma16(bf16x8 a, bf16x8 b, f32x4 c){
  return __builtin_amdgcn_mfma_f32_16x16x32_bf16(a, b, c, 0, 0, 0);
}

__device__ __forceinline__ void vmwait0(){ asm volatile("s_waitcnt vmcnt(0)" ::: "memory"); }
__device__ __forceinline__ void vmwait8(){ asm volatile("s_waitcnt vmcnt(8)" ::: "memory"); }
__device__ __forceinline__ void barr(){ asm volatile("s_barrier" ::: "memory"); }

// ---------------- dtype detect + ticket reset (8 XCD-partition tickets, stride 16)
__global__ void k_detect(const u16* cosr, int* flag, int* ticket){
  if (threadIdx.x == 0) *flag = (cosr[0] == (u16)0x3F80u) ? 1 : 0;
  if (threadIdx.x < 128) ticket[threadIdx.x] = 0;
}

// ---------------- merged x-convert + 8 weight transposes (one launch)
struct TDesc { const void* src; u16* dst; int srcStride, dstStride, cblk, nbx, blk0; };
struct TPack { TDesc d[8]; };
#define CONVBLK 8192

__global__ void k_prep(const void* __restrict__ xsrc, u16* __restrict__ x_bf,
                       TPack p, const int* flag){
  __shared__ u16 tile[64][72];
  const int bid = blockIdx.x;
  const int tid = threadIdx.x;
  const int f = *flag;
  if (bid < CONVBLK){
    int id = bid * 256 + tid;                 // n4 = 2097152 = 8192*256 exactly
    if (f){
      reinterpret_cast<uint2*>(x_bf)[id] = reinterpret_cast<const uint2*>(xsrc)[id];
    } else {
      f4v v = reinterpret_cast<const f4v*>(xsrc)[id];
      unsigned lo = (unsigned)f2bf(v.x) | ((unsigned)f2bf(v.y) << 16);
      unsigned hi = (unsigned)f2bf(v.z) | ((unsigned)f2bf(v.w) << 16);
      reinterpret_cast<uint2*>(x_bf)[id] = make_uint2(lo, hi);
    }
    return;
  }
  const int tb = bid - CONVBLK;
  int i = 0;
  #pragma unroll
  for (int k = 1; k < 8; ++k) if (tb >= p.d[k].blk0) i = k;
  const void* src = p.d[i].src;
  u16* dst = p.d[i].dst;
  const int srcStride = p.d[i].srcStride, dstStride = p.d[i].dstStride;
  const int rel = tb - p.d[i].blk0;
  const int bx = rel % p.d[i].nbx, by = rel / p.d[i].nbx;
  const int r0 = by << 6, c0 = bx * p.d[i].cblk;
  #pragma unroll
  for (int it = 0; it < 2; ++it){
    int task = (it << 8) + tid;
    int r = task >> 3, c8 = (task & 7) << 3;
    if (f){
      const u16* pp = (const u16*)src + (size_t)(r0 + r) * srcStride + c0 + c8;
      u16x8 v = *reinterpret_cast<const u16x8*>(pp);
      #pragma unroll
      for (int j = 0; j < 8; ++j) tile[r][c8 + j] = v[j];
    } else {
      const float* pp = (const float*)src + (size_t)(r0 + r) * srcStride + c0 + c8;
      f4v a = reinterpret_cast<const f4v*>(pp)[0];
      f4v b = reinterpret_cast<const f4v*>(pp)[1];
      tile[r][c8+0]=f2bf(a.x); tile[r][c8+1]=f2bf(a.y); tile[r][c8+2]=f2bf(a.z); tile[r][c8+3]=f2bf(a.w);
      tile[r][c8+4]=f2bf(b.x); tile[r][c8+5]=f2bf(b.y); tile[r][c8+6]=f2bf(b.z); tile[r][c8+7]=f2bf(b.w);
    }
  }
  __syncthreads();
  #pragma unroll
  for (int it = 0; it < 2; ++it){
    int task = (it << 8) + tid;
    int rr = task >> 3, cc8 = (task & 7) << 3;
    u16x8 v;
    #pragma unroll
    for (int j = 0; j < 8; ++j) v[j] = tile[cc8 + j][rr];
    *reinterpret_cast<u16x8*>(dst + (size_t)((bx << 6) + rr) * dstStride + r0 + cc8) = v;
  }
}

// ---------------- 256x256 8-phase GEMM, counted-vmcnt pipeline (2 groups by by-index).
// Optional bijective XCD-chunked swizzle (swz=1; nwg must be divisible by 8, gridDim.x==16).
// Row-XOR swizzle byte ^= ((row&7)<<4) via inverse-swizzled global sources.
#define MMQ(MH, NH, BFR) do{ \
  __builtin_amdgcn_s_setprio(1); \
  _Pragma("unroll") for (int ks = 0; ks < 2; ++ks) \
    _Pragma("unroll") for (int mi = 0; mi < 4; ++mi) \
      _Pragma("unroll") for (int ni = 0; ni < 2; ++ni) \
        acc[(MH)*4+mi][(NH)*2+ni] = mfma16(af[ks][mi], BFR[ks][ni], acc[(MH)*4+mi][(NH)*2+ni]); \
  __builtin_amdgcn_s_setprio(0); \
}while(0)

#define LDA(MH) do{ \
  _Pragma("unroll") for (int ks = 0; ks < 2; ++ks) \
    _Pragma("unroll") for (int mi = 0; mi < 4; ++mi){ \
      int row = (MH)*64 + mi*16 + l16; \
      int cb = ((ks << 6) + (g << 4)) ^ ((row & 7) << 4); \
      af[ks][mi] = *reinterpret_cast<const bf16x8*>(&lds[buf*32768 + wm*8192 + (((row << 7) + cb) >> 1)]); \
    } \
}while(0)

#define LDB(DST, NH) do{ \
  _Pragma("unroll") for (int ks = 0; ks < 2; ++ks) \
    _Pragma("unroll") for (int ni = 0; ni < 2; ++ni){ \
      int row = ((wn & 1) * 64) + (NH)*32 + ni*16 + l16; \
      int cb = ((ks << 6) + (g << 4)) ^ ((row & 7) << 4); \
      DST[ks][ni] = *reinterpret_cast<const bf16x8*>(&lds[buf*32768 + 16384 + (wn >> 1)*8192 + (((row << 7) + cb) >> 1)]); \
    } \
}while(0)

__global__ __launch_bounds__(512, 2) void k_gemm256(
    const u16* __restrict__ A0, int lda0, const u16* __restrict__ Bt0, int K0,
    u16* __restrict__ C0, int ldc0, float os0,
    const u16* __restrict__ A1, int lda1, const u16* __restrict__ Bt1, int K1,
    u16* __restrict__ C1, int ldc1, float os1,
    int ysplit, int swz, void* outp, const int* flag){
  __shared__ alignas(16) u16 lds[65536];   // 128 KB
  const int tid = threadIdx.x;
  const int wid = tid >> 6, lane = tid & 63;
  const int wm = wid >> 2, wn = wid & 3;
  const int l16 = lane & 15, g = lane >> 4;
  int lin = blockIdx.y * 16 + blockIdx.x;
  if (swz){
    const int q8 = (gridDim.x * gridDim.y) >> 3;
    lin = (lin & 7) * q8 + (lin >> 3);       // chunk per XCD (bijective: nwg%8==0)
  }
  int by = lin >> 4;
  const int m0 = (lin & 15) << 8;
  const u16 *A, *Bt; u16* C; int lda, K, ldc; float oscale;
  if (by < ysplit){ A = A0; lda = lda0; Bt = Bt0; K = K0; C = C0; ldc = ldc0; oscale = os0; }
  else { by -= ysplit; A = A1; lda = lda1; Bt = Bt1; K = K1; C = C1; ldc = ldc1; oscale = os1; }
  const int n0 = by << 8;
  const size_t Kz = (size_t)K;
  const int nkt = K >> 6;

  auto STAGE = [&](int kt, int bufn){
    const int kb = kt << 6;
    #pragma unroll
    for (int q = 0; q < 8; ++q){
      const int ht = q >> 1, ch = q & 1;
      const int Lb = ((ch * 8 + wid) << 10) + (lane << 4);   // byte within half-tile
      const int row = Lb >> 7;
      const int colb = (Lb & 127) ^ ((row & 7) << 4);        // inverse-swizzled source
      const u16* src;
      if (ht < 2) src = A  + (size_t)(m0 + ht * 128 + row) * lda + kb + (colb >> 1);
      else        src = Bt + (size_t)(n0 + (ht - 2) * 128 + row) * Kz + kb + (colb >> 1);
      gld_lds16(src, &lds[bufn * 32768 + ht * 8192 + ((ch * 8 + wid) << 9)]);
    }
  };

  f32x4 acc[8][4] = {};
  bf16x8 af[2][4], bf0[2][2], bf1[2][2];

  STAGE(0, 0);
  int buf = 0;

  for (int kt = 0; kt < nkt; ++kt){
    if (kt + 1 < nkt){ STAGE(kt + 1, buf ^ 1); vmwait8(); }   // wait only tile-kt's loads
    else vmwait0();
    barr();                                                    // buf resident for all waves
    // phase 0
    LDA(0);
    LDB(bf0, 0);
    barr();
    MMQ(0, 0, bf0);
    barr();
    // phase 1
    LDB(bf1, 1);
    barr();
    MMQ(0, 1, bf1);
    barr();
    // phase 2
    LDA(1);
    barr();
    MMQ(1, 0, bf0);
    barr();
    // phase 3
    MMQ(1, 1, bf1);
    barr();                                                    // reads done before next STAGE overwrites
    buf ^= 1;
  }

  const int r4 = g << 2;
  const int f = flag ? *flag : 1;
  #pragma unroll
  for (int mi8 = 0; mi8 < 8; ++mi8){
    int row = m0 + wm * 128 + mi8 * 16 + r4;
    #pragma unroll
    for (int ni4 = 0; ni4 < 4; ++ni4){
      int col = n0 + wn * 64 + ni4 * 16 + l16;
      #pragma unroll
      for (int j = 0; j < 4; ++j){
        float v = acc[mi8][ni4][j] * oscale;
        if (outp){
          if (f) ((u16*)outp)[(size_t)(row + j) * ldc + col] = f2bf(v);
          else   ((float*)outp)[(size_t)(row + j) * ldc + col] = v;
        } else {
          C[(size_t)(row + j) * ldc + col] = f2bf(v);
        }
      }
    }
  }
}

// ---------------- merged RoPE + vT build (one launch, 4096 blocks)
__global__ void k_ropevt(const u16* __restrict__ xc, const void* __restrict__ cosp,
                         const void* __restrict__ sinp, const int* flag,
                         u16* __restrict__ krope, u16* __restrict__ qrope,
                         const u16* __restrict__ kvP, u16* __restrict__ vT){
  __shared__ u16 tile[64][72];
  if (blockIdx.x < 2048){
    // RoPE from xc cols 2048..2175 (stride 2304); q-part pre-scaled by 1/sqrt(D)*log2e
    int id = blockIdx.x * 256 + threadIdx.x;   // exactly NROWS*128
    int row = id >> 7, c = id & 127;
    int t = row & (T_ - 1);
    int d = c & 63, i = d & 31;
    float cs, sn;
    if (*flag){ cs = bf2f(((const u16*)cosp)[t * 32 + i]); sn = bf2f(((const u16*)sinp)[t * 32 + i]); }
    else      { cs = ((const float*)cosp)[t * 32 + i];     sn = ((const float*)sinp)[t * 32 + i]; }
    int base = c & 64;
    float t1 = bf2f(xc[(size_t)row * 2304 + 2048 + base + i]);
    float t2 = bf2f(xc[(size_t)row * 2304 + 2048 + base + 32 + i]);
    float v = (d < 32) ? (t1 * cs - t2 * sn) : (t2 * cs + t1 * sn);
    if (c >= 64) v *= 0.12753139626374414f;
    ((c < 64) ? krope : qrope)[(size_t)row * 64 + d] = f2bf(v);
    return;
  }
  const int rel = blockIdx.x - 2048;
  const int t0 = (rel & 31) << 6, d0 = ((rel >> 5) & 1) << 6, bh = rel >> 6;
  const int b = bh >> 4, h = bh & 15;
  const int tid = threadIdx.x;
  #pragma unroll
  for (int i = 0; i < 2; ++i){
    int task = (i << 8) + tid;
    int r = task >> 3, c8 = (task & 7) << 3;
    const u16* p = kvP + (size_t)(b * T_ + t0 + r) * 3072 + 1024 + h * 128 + d0 + c8;
    u16x8 v = *reinterpret_cast<const u16x8*>(p);
    #pragma unroll
    for (int j = 0; j < 8; ++j) tile[r][c8 + j] = v[j];
  }
  __syncthreads();
  #pragma unroll
  for (int i = 0; i < 2; ++i){
    int task = (i << 8) + tid;
    int rr = task >> 3, cc8 = (task & 7) << 3;
    u16x8 v;
    #pragma unroll
    for (int j = 0; j < 8; ++j) v[j] = tile[cc8 + j][rr];
    *reinterpret_cast<u16x8*>(vT + ((size_t)bh * 128 + d0 + rr) * T_ + t0 + cc8) = v;
  }
}

// ---------------- causal flash attention (round-9 config: measured best 85.7us)
// 64 KB LDS double-buffer, 512 workers (2 blocks/CU), per-XCD tickets with 2:1
// item:worker stealing (heavy-first). + s_setprio around MFMA clusters (T5).
// Round-12 lesson: 1:1 items kills the tail (no stealing), serial stage +30%/tile.
__global__ __launch_bounds__(256, 2) void k_attn(const u16* __restrict__ qP,
                                                 const u16* __restrict__ kvP,
                                                 const u16* __restrict__ vT,
                                                 const u16* __restrict__ krope,
                                                 const u16* __restrict__ qrope,
                                                 u16* __restrict__ aout,
                                                 int* __restrict__ ticket){
  __shared__ alignas(16) u16 smem[32768];   // 64 KB: 2 buffers x (K [64][128] + V [128][64])
  const int tid = threadIdx.x, wid = tid >> 6, lane = tid & 63;
  const int l16 = lane & 15, g = lane >> 4;
  const int lk = g << 3, r4 = g << 2;
  const int sw8 = (l16 & 7) << 3;
  const int xcd = blockIdx.x & 7;

  while (true){
    if (tid == 0) *(int*)&smem[0] = atomicAdd(&ticket[xcd << 4], 1);
    __syncthreads();
    const int it = *(const int*)&smem[0];
    __syncthreads();
    if (it >= 128) break;
    const int qt = 31 - (it >> 2);          // heavy-first within partition
    const int bh = (xcd << 2) + (it & 3), b = bh >> 4, h = bh & 15;
    const int q0 = qt << 6;
    const size_t bT = (size_t)b * T_;
    const u16* kvPb = kvP + bT * 3072 + (h << 6);
    const u16* krb  = krope + bT * 64;
    const u16* vTb  = vT + (size_t)bh * 128 * T_;
    const int qlo = q0 + (wid << 4);
    const int nkv = qt + 1;

    auto STAGE = [&](int buf, int k0){
      const int base = buf << 14;
      #pragma unroll
      for (int r = 0; r < 8; ++r){
        int c = (r << 8) + tid;
        const u16* src;
        if (r < 4){
          int row = c >> 4, cc = c & 15;
          int ccx = (cc & 8) | ((cc & 7) ^ (row & 7));
          int col0 = ccx << 3;
          src = (col0 < 64) ? (kvPb + (size_t)(k0 + row) * 3072 + col0)
                            : (krb  + (size_t)(k0 + row) * 64 + (col0 - 64));
        } else {
          int cv = c - 1024;
          int row = cv >> 3, cc = cv & 7;
          int ccx = cc ^ (row & 7);
          src = vTb + (size_t)row * T_ + k0 + (ccx << 3);
        }
        gld_lds16(src, &smem[base + (((r << 8) + (wid << 6)) << 3)]);
      }
    };

    bf16x8 qf[4];
    {
      size_t grow = bT + qlo + l16;
      #pragma unroll
      for (int ks = 0; ks < 4; ++ks){
        int d = (ks << 5) + lk;
        const u16* src = (ks < 2) ? (qP + grow * 1024 + (h << 6) + d)
                                  : (qrope + grow * 64 + (d - 64));
        qf[ks] = *reinterpret_cast<const bf16x8*>(src);
      }
    }
    f32x4 o[8] = {};
    float m = -3e38f, l = 0.f;

    STAGE(0, 0);
    __syncthreads();
    int cur = 0;

    for (int kv = 0; kv < nkv; ++kv){
      const int k0 = kv << 6;
      if (kv + 1 < nkv) STAGE(cur ^ 1, (kv + 1) << 6);
      const int kb = cur << 14;
      f32x4 s[4] = {};
      __builtin_amdgcn_s_setprio(1);
      #pragma unroll
      for (int ks = 0; ks < 4; ++ks){
        int colsw = ((ks << 5) + lk) ^ sw8;
        #pragma unroll
        for (int n = 0; n < 4; ++n){
          bf16x8 kf = *reinterpret_cast<const bf16x8*>(&smem[kb + ((n << 4) + l16) * 128 + colsw]);
          s[n] = mfma16(kf, qf[ks], s[n]);
        }
      }
      __builtin_amdgcn_s_setprio(0);
      if (k0 == q0){
        const int tq = qlo + l16;
        #pragma unroll
        for (int n = 0; n < 4; ++n)
          #pragma unroll
          for (int j = 0; j < 4; ++j)
            s[n][j] = (k0 + (n << 4) + r4 + j <= tq) ? s[n][j] : -3e38f;
      }
      float mx;
      {
        float a0 = fmaxf(fmaxf(s[0][0], s[0][1]), fmaxf(s[0][2], s[0][3]));
        float a1 = fmaxf(fmaxf(s[1][0], s[1][1]), fmaxf(s[1][2], s[1][3]));
        float a2 = fmaxf(fmaxf(s[2][0], s[2][1]), fmaxf(s[2][2], s[2][3]));
        float a3 = fmaxf(fmaxf(s[3][0], s[3][1]), fmaxf(s[3][2], s[3][3]));
        mx = fmaxf(fmaxf(a0, a1), fmaxf(a2, a3));
        mx = fmaxf(mx, __shfl_xor(mx, 16));
        mx = fmaxf(mx, __shfl_xor(mx, 32));
      }
      if (__ballot(mx > m + 8.f)){
        float mnew = fmaxf(m, mx);
        float alpha = exp2f(m - mnew);
        m = mnew; l *= alpha;
        #pragma unroll
        for (int j = 0; j < 4; ++j){
          float av = __shfl(alpha, r4 + j);
          #pragma unroll
          for (int db = 0; db < 8; ++db) o[db][j] *= av;
        }
      }
      unsigned w[4][2];
      float rs = 0.f;
      #pragma unroll
      for (int n = 0; n < 4; ++n)
        #pragma unroll
        for (int jh = 0; jh < 2; ++jh){
          float p0 = exp2f(s[n][2*jh]     - m);
          float p1 = exp2f(s[n][2*jh + 1] - m);
          rs += p0 + p1;
          w[n][jh] = cvt_pk_bf16(p0, p1);
        }
      rs += __shfl_xor(rs, 16);
      rs += __shfl_xor(rs, 32);
      l += rs;
      const int srcA = l16 + ((g & 1) << 5);
      const int srcB = srcA + 16;
      const bool hi = (g >= 2);
      bf16x8 pa[2];
      #pragma unroll
      for (int ks2 = 0; ks2 < 2; ++ks2){
        unsigned a0 = __shfl((int)w[2*ks2][0],     srcA);
        unsigned b0 = __shfl((int)w[2*ks2 + 1][0], srcA);
        unsigned a1 = __shfl((int)w[2*ks2][1],     srcA);
        unsigned b1 = __shfl((int)w[2*ks2 + 1][1], srcA);
        unsigned a2 = __shfl((int)w[2*ks2][0],     srcB);
        unsigned b2 = __shfl((int)w[2*ks2 + 1][0], srcB);
        unsigned a3 = __shfl((int)w[2*ks2][1],     srcB);
        unsigned b3 = __shfl((int)w[2*ks2 + 1][1], srcB);
        union { unsigned u[4]; bf16x8 v; } pk;
        pk.u[0] = hi ? b0 : a0;
        pk.u[1] = hi ? b1 : a1;
        pk.u[2] = hi ? b2 : a2;
        pk.u[3] = hi ? b3 : a3;
        pa[ks2] = pk.v;
      }
      __builtin_amdgcn_s_setprio(1);
      #pragma unroll
      for (int ks2 = 0; ks2 < 2; ++ks2){
        int colsw = ((ks2 << 5) + lk) ^ sw8;
        #pragma unroll
        for (int db = 0; db < 8; ++db){
          bf16x8 vb = *reinterpret_cast<const bf16x8*>(&smem[kb + 8192 + ((db << 4) + l16) * 64 + colsw]);
          o[db] = mfma16(pa[ks2], vb, o[db]);
        }
      }
      __builtin_amdgcn_s_setprio(0);
      __syncthreads();                      // drains prefetch; reads done before buffer reuse
      cur ^= 1;
    }
    #pragma unroll
    for (int j = 0; j < 4; ++j){
      float lv = __shfl(l, r4 + j);
      float rinv = 1.f / lv;
      const int tq = qlo + r4 + j;
      u16* dst = aout + (bT + tq) * 2048 + (h << 7) + l16;
      #pragma unroll
      for (int db = 0; db < 8; ++db)
        dst[db << 4] = f2bf(o[db][j] * rinv);
    }
  }
}

extern "C" void kernel_launch(void* const* d_in, const int* in_sizes, int n_in,
                              void* d_out, int out_size, void* d_ws, size_t ws_size,
                              hipStream_t stream){
  const void* x       = d_in[0];
  const void* cosp    = d_in[1];
  const void* sinp    = d_in[2];
  const void* w_kv    = d_in[3];
  const void* w_kdec  = d_in[4];
  const void* w_vdec  = d_in[5];
  const void* w_qc    = d_in[6];
  const void* w_qdec  = d_in[7];
  const void* w_krope = d_in[8];
  const void* w_qrope = d_in[9];
  const void* w_o     = d_in[10];

  char* ws = (char*)d_ws;
  size_t off = 0;
  auto alloc = [&](size_t bytes){ void* p = ws + off; off += (bytes + 255) & ~(size_t)255; return p; };
  int* flag     = (int*)alloc(256);
  int* ticket   = (int*)alloc(1024);                         // 8 tickets, stride 16 ints
  u16* x_bf     = (u16*)alloc((size_t)NROWS * DIM_ * 2);
  u16* w_c1T    = (u16*)alloc((size_t)2304 * DIM_ * 2);      // [kvT(512); qcT(1536); kropeT(64); qropeT(64); pad(128)] x 2048
  u16* w_kvdT   = (u16*)alloc((size_t)3072 * DC_ * 2);       // [kdecPackedT(1024); vdecT(2048)] x 512
  u16* w_qdPT   = (u16*)alloc((size_t)1024 * DCQ_ * 2);      // packed qdecT (1024 x 1536)
  u16* w_oT     = (u16*)alloc((size_t)DIM_ * DIM_ * 2);
  u16* xc       = (u16*)alloc((size_t)NROWS * 2304 * 2);     // [c_kv(512) | c_q(1536) | ropes(128) | pad(128)]
  u16* qP       = (u16*)alloc((size_t)NROWS * 1024 * 2);     // packed q decode (pre-scaled)
  u16* kvP      = (u16*)alloc((size_t)NROWS * 3072 * 2);     // [kPacked(1024) | v(2048)]
  u16* krope    = (u16*)alloc((size_t)NROWS * 64 * 2);
  u16* qrope    = (u16*)alloc((size_t)NROWS * 64 * 2);       // pre-scaled
  u16* vT       = (u16*)alloc((size_t)32 * 128 * T_ * 2);    // [bh][d][t]
  u16* aout     = (u16*)alloc((size_t)NROWS * DIM_ * 2);
  (void)in_sizes; (void)n_in; (void)out_size; (void)ws_size;

  const float SC2 = 0.12753139626374414f;   // 1/sqrt(128) * log2(e)

  hipLaunchKernelGGL(k_detect, dim3(1), dim3(128), 0, stream, (const u16*)cosp, flag, ticket);

  // merged x-convert + weight transposes (8192 conv blocks + 2880 transpose blocks)
  TPack tp;
  tp.d[0] = { w_kv,    w_c1T,                        512,  2048, 64,  8,  0    };
  tp.d[1] = { w_qc,    w_c1T + (size_t)512 * 2048,   1536, 2048, 64,  24, 256  };
  tp.d[2] = { w_krope, w_c1T + (size_t)2048 * 2048,  64,   2048, 64,  1,  1024 };
  tp.d[3] = { w_qrope, w_c1T + (size_t)2112 * 2048,  64,   2048, 64,  1,  1056 };
  tp.d[4] = { w_kdec,  w_kvdT,                       2048, 512,  128, 16, 1088 };
  tp.d[5] = { w_vdec,  w_kvdT + (size_t)1024 * 512,  2048, 512,  64,  32, 1216 };
  tp.d[6] = { w_qdec,  w_qdPT,                       2048, 1536, 128, 16, 1472 };
  tp.d[7] = { w_o,     w_oT,                         2048, 2048, 64,  32, 1856 };
  hipLaunchKernelGGL(k_prep, dim3(CONVBLK + 2880), dim3(256), 0, stream, x, x_bf, tp, flag);

  // G13: xc = x @ [w_kv | w_qc | w_krope | w_qrope | pad]  (4096 x 2304, K=2048), XCD-chunked
  hipLaunchKernelGGL(k_gemm256, dim3(16, 9), dim3(512), 0, stream,
                     x_bf, DIM_, w_c1T, DIM_, xc, 2304, 1.0f,
                     x_bf, DIM_, w_c1T, DIM_, xc, 2304, 1.0f,
                     9, 1, (void*)nullptr, (const int*)nullptr);
  // G2 + G4 grouped (256 blocks, linear order: groups have unequal K -> keep round-robin)
  hipLaunchKernelGGL(k_gemm256, dim3(16, 16), dim3(512), 0, stream,
                     xc, 2304, w_kvdT, DC_, kvP, 3072, 1.0f,
                     xc + 512, 2304, w_qdPT, DCQ_, qP, 1024, SC2,
                     12, 0, (void*)nullptr, (const int*)nullptr);
  // merged RoPE + vT (2048 + 2048 blocks)
  hipLaunchKernelGGL(k_ropevt, dim3(4096), dim3(256), 0, stream,
                     xc, cosp, sinp, flag, krope, qrope, kvP, vT);
  // attention (512 workers = 2 blocks/CU, 2:1 stealing, XCD-partitioned tickets)
  hipLaunchKernelGGL(k_attn, dim3(512), dim3(256), 0, stream,
                     qP, kvP, vT, krope, qrope, aout, ticket);
  // G5: out = aout @ w_o  (4096 x 2048, K=2048; writes d_out, dtype per flag), XCD-chunked
  hipLaunchKernelGGL(k_gemm256, dim3(16, 8), dim3(512), 0, stream,
                     aout, DIM_, w_oT, DIM_, (u16*)nullptr, DIM_, 1.0f,
                     aout, DIM_, w_oT, DIM_, (u16*)nullptr, DIM_, 1.0f,
                     8, 1, d_out, (const int*)flag);
}

// Round 14
// 262.677 us; speedup vs baseline: 1.3384x; 1.1435x over previous
//
#include <hip/hip_runtime.h>
#include <stdint.h>
#include <math.h>

#define B_    2
#define T_    2048
#define DIM_  2048
#define H_    16
#define DC_   512
#define DCQ_  1536
#define NROWS (B_*T_)   // 4096

typedef unsigned short u16;
typedef __attribute__((ext_vector_type(8))) __bf16 bf16x8;
typedef __attribute__((ext_vector_type(4))) float  f32x4;
typedef __attribute__((ext_vector_type(8))) unsigned short u16x8;
typedef __attribute__((ext_vector_type(4))) float  f4v;

__device__ __forceinline__ u16 f2bf(float f){
  unsigned u = __float_as_uint(f);
  u += 0x7FFFu + ((u >> 16) & 1u);   // RNE
  return (u16)(u >> 16);
}
__device__ __forceinline__ float bf2f(u16 h){ return __uint_as_float(((unsigned)h) << 16); }

__device__ __forceinline__ unsigned cvt_pk_bf16(float lo, float hi){
  unsigned r;
  asm("v_cvt_pk_bf16_f32 %0, %1, %2" : "=v"(r) : "v"(lo), "v"(hi));
  return r;
}

// async global->LDS, 16B per lane; LDS dest = wave-uniform base + lane*16.
__device__ __forceinline__ void gld_lds16(const void* g, void* l){
  auto gp = reinterpret_cast<__attribute__((address_space(1))) unsigned int*>(
      reinterpret_cast<uintptr_t>(g));
  auto lp = reinterpret_cast<__attribute__((address_space(3))) unsigned int*>(
      reinterpret_cast<uintptr_t>(l));
  __builtin_amdgcn_global_load_lds(gp, lp, 16, 0, 0);
}

__device__ __forceinline__ f32x4 mfma16(bf16x8 a, bf16x8 b, f32x4 c){
  return __builtin_amdgcn_mfma_f32_16x16x32_bf16(a, b, c, 0, 0, 0);
}

__device__ __forceinline__ void vmwait0(){ asm volatile("s_waitcnt vmcnt(0)" ::: "memory"); }
__device__ __forceinline__ void vmwait6(){ asm volatile("s_waitcnt vmcnt(6)" ::: "memory"); }
__device__ __forceinline__ void vmwait8(){ asm volatile("s_waitcnt vmcnt(8)" ::: "memory"); }
__device__ __forceinline__ void barr(){ asm volatile("s_barrier" ::: "memory"); }

// ---------------- dtype detect + ticket reset (8 XCD-partition tickets, stride 16)
__global__ void k_detect(const u16* cosr, int* flag, int* ticket){
  if (threadIdx.x == 0) *flag = (cosr[0] == (u16)0x3F80u) ? 1 : 0;
  if (threadIdx.x < 128) ticket[threadIdx.x] = 0;
}

// ---------------- merged x-convert + 8 weight transposes (one launch)
struct TDesc { const void* src; u16* dst; int srcStride, dstStride, cblk, nbx, blk0; };
struct TPack { TDesc d[8]; };
#define CONVBLK 8192

__global__ void k_prep(const void* __restrict__ xsrc, u16* __restrict__ x_bf,
                       TPack p, const int* flag){
  __shared__ u16 tile[64][72];
  const int bid = blockIdx.x;
  const int tid = threadIdx.x;
  const int f = *flag;
  if (bid < CONVBLK){
    int id = bid * 256 + tid;                 // n4 = 2097152 = 8192*256 exactly
    if (f){
      reinterpret_cast<uint2*>(x_bf)[id] = reinterpret_cast<const uint2*>(xsrc)[id];
    } else {
      f4v v = reinterpret_cast<const f4v*>(xsrc)[id];
      unsigned lo = (unsigned)f2bf(v.x) | ((unsigned)f2bf(v.y) << 16);
      unsigned hi = (unsigned)f2bf(v.z) | ((unsigned)f2bf(v.w) << 16);
      reinterpret_cast<uint2*>(x_bf)[id] = make_uint2(lo, hi);
    }
    return;
  }
  const int tb = bid - CONVBLK;
  int i = 0;
  #pragma unroll
  for (int k = 1; k < 8; ++k) if (tb >= p.d[k].blk0) i = k;
  const void* src = p.d[i].src;
  u16* dst = p.d[i].dst;
  const int srcStride = p.d[i].srcStride, dstStride = p.d[i].dstStride;
  const int rel = tb - p.d[i].blk0;
  const int bx = rel % p.d[i].nbx, by = rel / p.d[i].nbx;
  const int r0 = by << 6, c0 = bx * p.d[i].cblk;
  #pragma unroll
  for (int it = 0; it < 2; ++it){
    int task = (it << 8) + tid;
    int r = task >> 3, c8 = (task & 7) << 3;
    if (f){
      const u16* pp = (const u16*)src + (size_t)(r0 + r) * srcStride + c0 + c8;
      u16x8 v = *reinterpret_cast<const u16x8*>(pp);
      #pragma unroll
      for (int j = 0; j < 8; ++j) tile[r][c8 + j] = v[j];
    } else {
      const float* pp = (const float*)src + (size_t)(r0 + r) * srcStride + c0 + c8;
      f4v a = reinterpret_cast<const f4v*>(pp)[0];
      f4v b = reinterpret_cast<const f4v*>(pp)[1];
      tile[r][c8+0]=f2bf(a.x); tile[r][c8+1]=f2bf(a.y); tile[r][c8+2]=f2bf(a.z); tile[r][c8+3]=f2bf(a.w);
      tile[r][c8+4]=f2bf(b.x); tile[r][c8+5]=f2bf(b.y); tile[r][c8+6]=f2bf(b.z); tile[r][c8+7]=f2bf(b.w);
    }
  }
  __syncthreads();
  #pragma unroll
  for (int it = 0; it < 2; ++it){
    int task = (it << 8) + tid;
    int rr = task >> 3, cc8 = (task & 7) << 3;
    u16x8 v;
    #pragma unroll
    for (int j = 0; j < 8; ++j) v[j] = tile[cc8 + j][rr];
    *reinterpret_cast<u16x8*>(dst + (size_t)((bx << 6) + rr) * dstStride + r0 + cc8) = v;
  }
}

// ---------------- 256x256 8-phase GEMM, counted-vmcnt pipeline (used for G13).
#define MMQ(MH, NH, BFR) do{ \
  __builtin_amdgcn_s_setprio(1); \
  _Pragma("unroll") for (int ks = 0; ks < 2; ++ks) \
    _Pragma("unroll") for (int mi = 0; mi < 4; ++mi) \
      _Pragma("unroll") for (int ni = 0; ni < 2; ++ni) \
        acc[(MH)*4+mi][(NH)*2+ni] = mfma16(af[ks][mi], BFR[ks][ni], acc[(MH)*4+mi][(NH)*2+ni]); \
  __builtin_amdgcn_s_setprio(0); \
}while(0)

#define LDA(MH) do{ \
  _Pragma("unroll") for (int ks = 0; ks < 2; ++ks) \
    _Pragma("unroll") for (int mi = 0; mi < 4; ++mi){ \
      int row = (MH)*64 + mi*16 + l16; \
      int cb = ((ks << 6) + (g << 4)) ^ ((row & 7) << 4); \
      af[ks][mi] = *reinterpret_cast<const bf16x8*>(&lds[buf*32768 + wm*8192 + (((row << 7) + cb) >> 1)]); \
    } \
}while(0)

#define LDB(DST, NH) do{ \
  _Pragma("unroll") for (int ks = 0; ks < 2; ++ks) \
    _Pragma("unroll") for (int ni = 0; ni < 2; ++ni){ \
      int row = ((wn & 1) * 64) + (NH)*32 + ni*16 + l16; \
      int cb = ((ks << 6) + (g << 4)) ^ ((row & 7) << 4); \
      DST[ks][ni] = *reinterpret_cast<const bf16x8*>(&lds[buf*32768 + 16384 + (wn >> 1)*8192 + (((row << 7) + cb) >> 1)]); \
    } \
}while(0)

__global__ __launch_bounds__(512, 2) void k_gemm256(
    const u16* __restrict__ A0, int lda0, const u16* __restrict__ Bt0, int K0,
    u16* __restrict__ C0, int ldc0, float os0,
    const u16* __restrict__ A1, int lda1, const u16* __restrict__ Bt1, int K1,
    u16* __restrict__ C1, int ldc1, float os1,
    int ysplit, int swz, void* outp, const int* flag){
  __shared__ alignas(16) u16 lds[65536];   // 128 KB
  const int tid = threadIdx.x;
  const int wid = tid >> 6, lane = tid & 63;
  const int wm = wid >> 2, wn = wid & 3;
  const int l16 = lane & 15, g = lane >> 4;
  int lin = blockIdx.y * 16 + blockIdx.x;
  if (swz){
    const int q8 = (gridDim.x * gridDim.y) >> 3;
    lin = (lin & 7) * q8 + (lin >> 3);       // chunk per XCD (bijective: nwg%8==0)
  }
  int by = lin >> 4;
  const int m0 = (lin & 15) << 8;
  const u16 *A, *Bt; u16* C; int lda, K, ldc; float oscale;
  if (by < ysplit){ A = A0; lda = lda0; Bt = Bt0; K = K0; C = C0; ldc = ldc0; oscale = os0; }
  else { by -= ysplit; A = A1; lda = lda1; Bt = Bt1; K = K1; C = C1; ldc = ldc1; oscale = os1; }
  const int n0 = by << 8;
  const size_t Kz = (size_t)K;
  const int nkt = K >> 6;

  auto STAGE = [&](int kt, int bufn){
    const int kb = kt << 6;
    #pragma unroll
    for (int q = 0; q < 8; ++q){
      const int ht = q >> 1, ch = q & 1;
      const int Lb = ((ch * 8 + wid) << 10) + (lane << 4);
      const int row = Lb >> 7;
      const int colb = (Lb & 127) ^ ((row & 7) << 4);
      const u16* src;
      if (ht < 2) src = A  + (size_t)(m0 + ht * 128 + row) * lda + kb + (colb >> 1);
      else        src = Bt + (size_t)(n0 + (ht - 2) * 128 + row) * Kz + kb + (colb >> 1);
      gld_lds16(src, &lds[bufn * 32768 + ht * 8192 + ((ch * 8 + wid) << 9)]);
    }
  };

  f32x4 acc[8][4] = {};
  bf16x8 af[2][4], bf0[2][2], bf1[2][2];

  STAGE(0, 0);
  int buf = 0;

  for (int kt = 0; kt < nkt; ++kt){
    if (kt + 1 < nkt){ STAGE(kt + 1, buf ^ 1); vmwait8(); }
    else vmwait0();
    barr();
    LDA(0);
    LDB(bf0, 0);
    barr();
    MMQ(0, 0, bf0);
    barr();
    LDB(bf1, 1);
    barr();
    MMQ(0, 1, bf1);
    barr();
    LDA(1);
    barr();
    MMQ(1, 0, bf0);
    barr();
    MMQ(1, 1, bf1);
    barr();
    buf ^= 1;
  }

  const int r4 = g << 2;
  const int f = flag ? *flag : 1;
  #pragma unroll
  for (int mi8 = 0; mi8 < 8; ++mi8){
    int row = m0 + wm * 128 + mi8 * 16 + r4;
    #pragma unroll
    for (int ni4 = 0; ni4 < 4; ++ni4){
      int col = n0 + wn * 64 + ni4 * 16 + l16;
      #pragma unroll
      for (int j = 0; j < 4; ++j){
        float v = acc[mi8][ni4][j] * oscale;
        if (outp){
          if (f) ((u16*)outp)[(size_t)(row + j) * ldc + col] = f2bf(v);
          else   ((float*)outp)[(size_t)(row + j) * ldc + col] = v;
        } else {
          C[(size_t)(row + j) * ldc + col] = f2bf(v);
        }
      }
    }
  }
}

// ---------------- 128x256 GEMM variant (fills the grid where 256^2 under-subscribes).
// 512 thr / 8 waves (2M x 4N), per-wave 64x64, acc[4][4]. LDS 96 KB: 2 buf x
// {A[128][64] + B0[128][64] + B1[128][64]}. Row-XOR swizzle, vmcnt(6) pipeline.
#define MMQ1(NH, BFR) do{ \
  __builtin_amdgcn_s_setprio(1); \
  _Pragma("unroll") for (int ks = 0; ks < 2; ++ks) \
    _Pragma("unroll") for (int mi = 0; mi < 4; ++mi) \
      _Pragma("unroll") for (int ni = 0; ni < 2; ++ni) \
        acc[mi][(NH)*2+ni] = mfma16(af[ks][mi], BFR[ks][ni], acc[mi][(NH)*2+ni]); \
  __builtin_amdgcn_s_setprio(0); \
}while(0)

#define LDA1() do{ \
  _Pragma("unroll") for (int ks = 0; ks < 2; ++ks) \
    _Pragma("unroll") for (int mi = 0; mi < 4; ++mi){ \
      int row = wm*64 + mi*16 + l16; \
      int cb = ((ks << 6) + (g << 4)) ^ ((row & 7) << 4); \
      af[ks][mi] = *reinterpret_cast<const bf16x8*>(&lds[buf*24576 + (((row << 7) + cb) >> 1)]); \
    } \
}while(0)

#define LDB1(DST, NH) do{ \
  _Pragma("unroll") for (int ks = 0; ks < 2; ++ks) \
    _Pragma("unroll") for (int ni = 0; ni < 2; ++ni){ \
      int row = ((wn & 1) * 64) + (NH)*32 + ni*16 + l16; \
      int cb = ((ks << 6) + (g << 4)) ^ ((row & 7) << 4); \
      DST[ks][ni] = *reinterpret_cast<const bf16x8*>(&lds[buf*24576 + (1 + (wn >> 1))*8192 + (((row << 7) + cb) >> 1)]); \
    } \
}while(0)

__global__ __launch_bounds__(512, 2) void k_gemm128(
    const u16* __restrict__ A0, int lda0, const u16* __restrict__ Bt0, int K0,
    u16* __restrict__ C0, int ldc0, float os0,
    const u16* __restrict__ A1, int lda1, const u16* __restrict__ Bt1, int K1,
    u16* __restrict__ C1, int ldc1, float os1,
    int ysplit, int swz, void* outp, const int* flag){
  __shared__ alignas(16) u16 lds[49152];   // 96 KB
  const int tid = threadIdx.x;
  const int wid = tid >> 6, lane = tid & 63;
  const int wm = wid >> 2, wn = wid & 3;
  const int l16 = lane & 15, g = lane >> 4;
  int lin = blockIdx.y * 32 + blockIdx.x;    // gridDim.x == 32
  if (swz){
    const int q8 = (gridDim.x * gridDim.y) >> 3;
    lin = (lin & 7) * q8 + (lin >> 3);
  }
  const int m0 = (lin & 31) << 7;
  int nt = lin >> 5;
  const u16 *A, *Bt; u16* C; int lda, K, ldc; float oscale;
  if (nt < ysplit){ A = A0; lda = lda0; Bt = Bt0; K = K0; C = C0; ldc = ldc0; oscale = os0; }
  else { nt -= ysplit; A = A1; lda = lda1; Bt = Bt1; K = K1; C = C1; ldc = ldc1; oscale = os1; }
  const int n0 = nt << 8;
  const size_t Kz = (size_t)K;
  const int nkt = K >> 6;

  auto STAGE = [&](int kt, int bufn){
    const int kb = kt << 6;
    #pragma unroll
    for (int q = 0; q < 6; ++q){
      const int ht = q >> 1, ch = q & 1;
      const int Lb = ((ch * 8 + wid) << 10) + (lane << 4);   // byte within half-tile
      const int row = Lb >> 7;
      const int colb = (Lb & 127) ^ ((row & 7) << 4);        // inverse-swizzled source
      const u16* src;
      if (ht == 0)      src = A  + (size_t)(m0 + row) * lda + kb + (colb >> 1);
      else if (ht == 1) src = Bt + (size_t)(n0 + row) * Kz + kb + (colb >> 1);
      else              src = Bt + (size_t)(n0 + 128 + row) * Kz + kb + (colb >> 1);
      gld_lds16(src, &lds[bufn * 24576 + ht * 8192 + ((ch * 8 + wid) << 9)]);
    }
  };

  f32x4 acc[4][4] = {};
  bf16x8 af[2][4], bf0[2][2], bf1[2][2];

  STAGE(0, 0);
  int buf = 0;

  for (int kt = 0; kt < nkt; ++kt){
    if (kt + 1 < nkt){ STAGE(kt + 1, buf ^ 1); vmwait6(); }   // wait only tile-kt's 6 loads
    else vmwait0();
    barr();
    LDA1();
    LDB1(bf0, 0);
    barr();
    MMQ1(0, bf0);
    barr();
    LDB1(bf1, 1);
    barr();
    MMQ1(1, bf1);
    barr();
    buf ^= 1;
  }

  const int r4 = g << 2;
  const int f = flag ? *flag : 1;
  #pragma unroll
  for (int mi4 = 0; mi4 < 4; ++mi4){
    int row = m0 + wm * 64 + mi4 * 16 + r4;
    #pragma unroll
    for (int ni4 = 0; ni4 < 4; ++ni4){
      int col = n0 + wn * 64 + ni4 * 16 + l16;
      #pragma unroll
      for (int j = 0; j < 4; ++j){
        float v = acc[mi4][ni4][j] * oscale;
        if (outp){
          if (f) ((u16*)outp)[(size_t)(row + j) * ldc + col] = f2bf(v);
          else   ((float*)outp)[(size_t)(row + j) * ldc + col] = v;
        } else {
          C[(size_t)(row + j) * ldc + col] = f2bf(v);
        }
      }
    }
  }
}

// ---------------- merged RoPE + vT build (one launch, 4096 blocks)
__global__ void k_ropevt(const u16* __restrict__ xc, const void* __restrict__ cosp,
                         const void* __restrict__ sinp, const int* flag,
                         u16* __restrict__ krope, u16* __restrict__ qrope,
                         const u16* __restrict__ kvP, u16* __restrict__ vT){
  __shared__ u16 tile[64][72];
  if (blockIdx.x < 2048){
    int id = blockIdx.x * 256 + threadIdx.x;   // exactly NROWS*128
    int row = id >> 7, c = id & 127;
    int t = row & (T_ - 1);
    int d = c & 63, i = d & 31;
    float cs, sn;
    if (*flag){ cs = bf2f(((const u16*)cosp)[t * 32 + i]); sn = bf2f(((const u16*)sinp)[t * 32 + i]); }
    else      { cs = ((const float*)cosp)[t * 32 + i];     sn = ((const float*)sinp)[t * 32 + i]; }
    int base = c & 64;
    float t1 = bf2f(xc[(size_t)row * 2304 + 2048 + base + i]);
    float t2 = bf2f(xc[(size_t)row * 2304 + 2048 + base + 32 + i]);
    float v = (d < 32) ? (t1 * cs - t2 * sn) : (t2 * cs + t1 * sn);
    if (c >= 64) v *= 0.12753139626374414f;
    ((c < 64) ? krope : qrope)[(size_t)row * 64 + d] = f2bf(v);
    return;
  }
  const int rel = blockIdx.x - 2048;
  const int t0 = (rel & 31) << 6, d0 = ((rel >> 5) & 1) << 6, bh = rel >> 6;
  const int b = bh >> 4, h = bh & 15;
  const int tid = threadIdx.x;
  #pragma unroll
  for (int i = 0; i < 2; ++i){
    int task = (i << 8) + tid;
    int r = task >> 3, c8 = (task & 7) << 3;
    const u16* p = kvP + (size_t)(b * T_ + t0 + r) * 3072 + 1024 + h * 128 + d0 + c8;
    u16x8 v = *reinterpret_cast<const u16x8*>(p);
    #pragma unroll
    for (int j = 0; j < 8; ++j) tile[r][c8 + j] = v[j];
  }
  __syncthreads();
  #pragma unroll
  for (int i = 0; i < 2; ++i){
    int task = (i << 8) + tid;
    int rr = task >> 3, cc8 = (task & 7) << 3;
    u16x8 v;
    #pragma unroll
    for (int j = 0; j < 8; ++j) v[j] = tile[cc8 + j][rr];
    *reinterpret_cast<u16x8*>(vT + ((size_t)bh * 128 + d0 + rr) * T_ + t0 + cc8) = v;
  }
}

// ---------------- causal flash attention (round-9 config + setprio)
__global__ __launch_bounds__(256, 2) void k_attn(const u16* __restrict__ qP,
                                                 const u16* __restrict__ kvP,
                                                 const u16* __restrict__ vT,
                                                 const u16* __restrict__ krope,
                                                 const u16* __restrict__ qrope,
                                                 u16* __restrict__ aout,
                                                 int* __restrict__ ticket){
  __shared__ alignas(16) u16 smem[32768];   // 64 KB: 2 buffers x (K [64][128] + V [128][64])
  const int tid = threadIdx.x, wid = tid >> 6, lane = tid & 63;
  const int l16 = lane & 15, g = lane >> 4;
  const int lk = g << 3, r4 = g << 2;
  const int sw8 = (l16 & 7) << 3;
  const int xcd = blockIdx.x & 7;

  while (true){
    if (tid == 0) *(int*)&smem[0] = atomicAdd(&ticket[xcd << 4], 1);
    __syncthreads();
    const int it = *(const int*)&smem[0];
    __syncthreads();
    if (it >= 128) break;
    const int qt = 31 - (it >> 2);          // heavy-first within partition
    const int bh = (xcd << 2) + (it & 3), b = bh >> 4, h = bh & 15;
    const int q0 = qt << 6;
    const size_t bT = (size_t)b * T_;
    const u16* kvPb = kvP + bT * 3072 + (h << 6);
    const u16* krb  = krope + bT * 64;
    const u16* vTb  = vT + (size_t)bh * 128 * T_;
    const int qlo = q0 + (wid << 4);
    const int nkv = qt + 1;

    auto STAGE = [&](int buf, int k0){
      const int base = buf << 14;
      #pragma unroll
      for (int r = 0; r < 8; ++r){
        int c = (r << 8) + tid;
        const u16* src;
        if (r < 4){
          int row = c >> 4, cc = c & 15;
          int ccx = (cc & 8) | ((cc & 7) ^ (row & 7));
          int col0 = ccx << 3;
          src = (col0 < 64) ? (kvPb + (size_t)(k0 + row) * 3072 + col0)
                            : (krb  + (size_t)(k0 + row) * 64 + (col0 - 64));
        } else {
          int cv = c - 1024;
          int row = cv >> 3, cc = cv & 7;
          int ccx = cc ^ (row & 7);
          src = vTb + (size_t)row * T_ + k0 + (ccx << 3);
        }
        gld_lds16(src, &smem[base + (((r << 8) + (wid << 6)) << 3)]);
      }
    };

    bf16x8 qf[4];
    {
      size_t grow = bT + qlo + l16;
      #pragma unroll
      for (int ks = 0; ks < 4; ++ks){
        int d = (ks << 5) + lk;
        const u16* src = (ks < 2) ? (qP + grow * 1024 + (h << 6) + d)
                                  : (qrope + grow * 64 + (d - 64));
        qf[ks] = *reinterpret_cast<const bf16x8*>(src);
      }
    }
    f32x4 o[8] = {};
    float m = -3e38f, l = 0.f;

    STAGE(0, 0);
    __syncthreads();
    int cur = 0;

    for (int kv = 0; kv < nkv; ++kv){
      const int k0 = kv << 6;
      if (kv + 1 < nkv) STAGE(cur ^ 1, (kv + 1) << 6);
      const int kb = cur << 14;
      f32x4 s[4] = {};
      __builtin_amdgcn_s_setprio(1);
      #pragma unroll
      for (int ks = 0; ks < 4; ++ks){
        int colsw = ((ks << 5) + lk) ^ sw8;
        #pragma unroll
        for (int n = 0; n < 4; ++n){
          bf16x8 kf = *reinterpret_cast<const bf16x8*>(&smem[kb + ((n << 4) + l16) * 128 + colsw]);
          s[n] = mfma16(kf, qf[ks], s[n]);
        }
      }
      __builtin_amdgcn_s_setprio(0);
      if (k0 == q0){
        const int tq = qlo + l16;
        #pragma unroll
        for (int n = 0; n < 4; ++n)
          #pragma unroll
          for (int j = 0; j < 4; ++j)
            s[n][j] = (k0 + (n << 4) + r4 + j <= tq) ? s[n][j] : -3e38f;
      }
      float mx;
      {
        float a0 = fmaxf(fmaxf(s[0][0], s[0][1]), fmaxf(s[0][2], s[0][3]));
        float a1 = fmaxf(fmaxf(s[1][0], s[1][1]), fmaxf(s[1][2], s[1][3]));
        float a2 = fmaxf(fmaxf(s[2][0], s[2][1]), fmaxf(s[2][2], s[2][3]));
        float a3 = fmaxf(fmaxf(s[3][0], s[3][1]), fmaxf(s[3][2], s[3][3]));
        mx = fmaxf(fmaxf(a0, a1), fmaxf(a2, a3));
        mx = fmaxf(mx, __shfl_xor(mx, 16));
        mx = fmaxf(mx, __shfl_xor(mx, 32));
      }
      if (__ballot(mx > m + 8.f)){
        float mnew = fmaxf(m, mx);
        float alpha = exp2f(m - mnew);
        m = mnew; l *= alpha;
        #pragma unroll
        for (int j = 0; j < 4; ++j){
          float av = __shfl(alpha, r4 + j);
          #pragma unroll
          for (int db = 0; db < 8; ++db) o[db][j] *= av;
        }
      }
      unsigned w[4][2];
      float rs = 0.f;
      #pragma unroll
      for (int n = 0; n < 4; ++n)
        #pragma unroll
        for (int jh = 0; jh < 2; ++jh){
          float p0 = exp2f(s[n][2*jh]     - m);
          float p1 = exp2f(s[n][2*jh + 1] - m);
          rs += p0 + p1;
          w[n][jh] = cvt_pk_bf16(p0, p1);
        }
      rs += __shfl_xor(rs, 16);
      rs += __shfl_xor(rs, 32);
      l += rs;
      const int srcA = l16 + ((g & 1) << 5);
      const int srcB = srcA + 16;
      const bool hi = (g >= 2);
      bf16x8 pa[2];
      #pragma unroll
      for (int ks2 = 0; ks2 < 2; ++ks2){
        unsigned a0 = __shfl((int)w[2*ks2][0],     srcA);
        unsigned b0 = __shfl((int)w[2*ks2 + 1][0], srcA);
        unsigned a1 = __shfl((int)w[2*ks2][1],     srcA);
        unsigned b1 = __shfl((int)w[2*ks2 + 1][1], srcA);
        unsigned a2 = __shfl((int)w[2*ks2][0],     srcB);
        unsigned b2 = __shfl((int)w[2*ks2 + 1][0], srcB);
        unsigned a3 = __shfl((int)w[2*ks2][1],     srcB);
        unsigned b3 = __shfl((int)w[2*ks2 + 1][1], srcB);
        union { unsigned u[4]; bf16x8 v; } pk;
        pk.u[0] = hi ? b0 : a0;
        pk.u[1] = hi ? b1 : a1;
        pk.u[2] = hi ? b2 : a2;
        pk.u[3] = hi ? b3 : a3;
        pa[ks2] = pk.v;
      }
      __builtin_amdgcn_s_setprio(1);
      #pragma unroll
      for (int ks2 = 0; ks2 < 2; ++ks2){
        int colsw = ((ks2 << 5) + lk) ^ sw8;
        #pragma unroll
        for (int db = 0; db < 8; ++db){
          bf16x8 vb = *reinterpret_cast<const bf16x8*>(&smem[kb + 8192 + ((db << 4) + l16) * 64 + colsw]);
          o[db] = mfma16(pa[ks2], vb, o[db]);
        }
      }
      __builtin_amdgcn_s_setprio(0);
      __syncthreads();
      cur ^= 1;
    }
    #pragma unroll
    for (int j = 0; j < 4; ++j){
      float lv = __shfl(l, r4 + j);
      float rinv = 1.f / lv;
      const int tq = qlo + r4 + j;
      u16* dst = aout + (bT + tq) * 2048 + (h << 7) + l16;
      #pragma unroll
      for (int db = 0; db < 8; ++db)
        dst[db << 4] = f2bf(o[db][j] * rinv);
    }
  }
}

extern "C" void kernel_launch(void* const* d_in, const int* in_sizes, int n_in,
                              void* d_out, int out_size, void* d_ws, size_t ws_size,
                              hipStream_t stream){
  const void* x       = d_in[0];
  const void* cosp    = d_in[1];
  const void* sinp    = d_in[2];
  const void* w_kv    = d_in[3];
  const void* w_kdec  = d_in[4];
  const void* w_vdec  = d_in[5];
  const void* w_qc    = d_in[6];
  const void* w_qdec  = d_in[7];
  const void* w_krope = d_in[8];
  const void* w_qrope = d_in[9];
  const void* w_o     = d_in[10];

  char* ws = (char*)d_ws;
  size_t off = 0;
  auto alloc = [&](size_t bytes){ void* p = ws + off; off += (bytes + 255) & ~(size_t)255; return p; };
  int* flag     = (int*)alloc(256);
  int* ticket   = (int*)alloc(1024);                         // 8 tickets, stride 16 ints
  u16* x_bf     = (u16*)alloc((size_t)NROWS * DIM_ * 2);
  u16* w_c1T    = (u16*)alloc((size_t)2304 * DIM_ * 2);      // [kvT(512); qcT(1536); kropeT(64); qropeT(64); pad(128)] x 2048
  u16* w_kvdT   = (u16*)alloc((size_t)3072 * DC_ * 2);       // [kdecPackedT(1024); vdecT(2048)] x 512
  u16* w_qdPT   = (u16*)alloc((size_t)1024 * DCQ_ * 2);      // packed qdecT (1024 x 1536)
  u16* w_oT     = (u16*)alloc((size_t)DIM_ * DIM_ * 2);
  u16* xc       = (u16*)alloc((size_t)NROWS * 2304 * 2);     // [c_kv(512) | c_q(1536) | ropes(128) | pad(128)]
  u16* qP       = (u16*)alloc((size_t)NROWS * 1024 * 2);     // packed q decode (pre-scaled)
  u16* kvP      = (u16*)alloc((size_t)NROWS * 3072 * 2);     // [kPacked(1024) | v(2048)]
  u16* krope    = (u16*)alloc((size_t)NROWS * 64 * 2);
  u16* qrope    = (u16*)alloc((size_t)NROWS * 64 * 2);       // pre-scaled
  u16* vT       = (u16*)alloc((size_t)32 * 128 * T_ * 2);    // [bh][d][t]
  u16* aout     = (u16*)alloc((size_t)NROWS * DIM_ * 2);
  (void)in_sizes; (void)n_in; (void)out_size; (void)ws_size;

  const float SC2 = 0.12753139626374414f;   // 1/sqrt(128) * log2(e)

  hipLaunchKernelGGL(k_detect, dim3(1), dim3(128), 0, stream, (const u16*)cosp, flag, ticket);

  // merged x-convert + weight transposes (8192 conv blocks + 2880 transpose blocks)
  TPack tp;
  tp.d[0] = { w_kv,    w_c1T,                        512,  2048, 64,  8,  0    };
  tp.d[1] = { w_qc,    w_c1T + (size_t)512 * 2048,   1536, 2048, 64,  24, 256  };
  tp.d[2] = { w_krope, w_c1T + (size_t)2048 * 2048,  64,   2048, 64,  1,  1024 };
  tp.d[3] = { w_qrope, w_c1T + (size_t)2112 * 2048,  64,   2048, 64,  1,  1056 };
  tp.d[4] = { w_kdec,  w_kvdT,                       2048, 512,  128, 16, 1088 };
  tp.d[5] = { w_vdec,  w_kvdT + (size_t)1024 * 512,  2048, 512,  64,  32, 1216 };
  tp.d[6] = { w_qdec,  w_qdPT,                       2048, 1536, 128, 16, 1472 };
  tp.d[7] = { w_o,     w_oT,                         2048, 2048, 64,  32, 1856 };
  hipLaunchKernelGGL(k_prep, dim3(CONVBLK + 2880), dim3(256), 0, stream, x, x_bf, tp, flag);

  // G13: xc = x @ [w_kv | w_qc | w_krope | w_qrope | pad]  (4096 x 2304, K=2048), 256^2, XCD-chunked
  hipLaunchKernelGGL(k_gemm256, dim3(16, 9), dim3(512), 0, stream,
                     x_bf, DIM_, w_c1T, DIM_, xc, 2304, 1.0f,
                     x_bf, DIM_, w_c1T, DIM_, xc, 2304, 1.0f,
                     9, 1, (void*)nullptr, (const int*)nullptr);
  // G4 + G2 grouped on 128x256 tiles (512 blocks; heavy K=1536 group dispatched first):
  //   nt<4:  qP = xc[:, 512:2048] @ w_qdecP  (4096 x 1024, K=1536), pre-scaled
  //   nt>=4: kvP = xc[:, :512] @ [w_kdecP | w_vdec]  (4096 x 3072, K=512)
  hipLaunchKernelGGL(k_gemm128, dim3(32, 16), dim3(512), 0, stream,
                     xc + 512, 2304, w_qdPT, DCQ_, qP, 1024, SC2,
                     xc, 2304, w_kvdT, DC_, kvP, 3072, 1.0f,
                     4, 0, (void*)nullptr, (const int*)nullptr);
  // merged RoPE + vT (2048 + 2048 blocks)
  hipLaunchKernelGGL(k_ropevt, dim3(4096), dim3(256), 0, stream,
                     xc, cosp, sinp, flag, krope, qrope, kvP, vT);
  // attention (512 workers = 2 blocks/CU, 2:1 stealing, XCD-partitioned tickets)
  hipLaunchKernelGGL(k_attn, dim3(512), dim3(256), 0, stream,
                     qP, kvP, vT, krope, qrope, aout, ticket);
  // G5: out = aout @ w_o  (4096 x 2048, K=2048) on 128x256 tiles -> 256 blocks (all CUs), XCD-chunked
  hipLaunchKernelGGL(k_gemm128, dim3(32, 8), dim3(512), 0, stream,
                     aout, DIM_, w_oT, DIM_, (u16*)nullptr, DIM_, 1.0f,
                     aout, DIM_, w_oT, DIM_, (u16*)nullptr, DIM_, 1.0f,
                     8, 1, d_out, (const int*)flag);
}

// Round 15
// 253.699 us; speedup vs baseline: 1.3858x; 1.0354x over previous
//
#include <hip/hip_runtime.h>
#include <stdint.h>
#include <math.h>

#define B_    2
#define T_    2048
#define DIM_  2048
#define H_    16
#define DC_   512
#define DCQ_  1536
#define NROWS (B_*T_)   // 4096

typedef unsigned short u16;
typedef __attribute__((ext_vector_type(8))) __bf16 bf16x8;
typedef __attribute__((ext_vector_type(4))) float  f32x4;
typedef __attribute__((ext_vector_type(8))) unsigned short u16x8;
typedef __attribute__((ext_vector_type(4))) float  f4v;

__device__ __forceinline__ u16 f2bf(float f){
  unsigned u = __float_as_uint(f);
  u += 0x7FFFu + ((u >> 16) & 1u);   // RNE
  return (u16)(u >> 16);
}
__device__ __forceinline__ float bf2f(u16 h){ return __uint_as_float(((unsigned)h) << 16); }

__device__ __forceinline__ unsigned cvt_pk_bf16(float lo, float hi){
  unsigned r;
  asm("v_cvt_pk_bf16_f32 %0, %1, %2" : "=v"(r) : "v"(lo), "v"(hi));
  return r;
}

// async global->LDS, 16B per lane; LDS dest = wave-uniform base + lane*16.
__device__ __forceinline__ void gld_lds16(const void* g, void* l){
  auto gp = reinterpret_cast<__attribute__((address_space(1))) unsigned int*>(
      reinterpret_cast<uintptr_t>(g));
  auto lp = reinterpret_cast<__attribute__((address_space(3))) unsigned int*>(
      reinterpret_cast<uintptr_t>(l));
  __builtin_amdgcn_global_load_lds(gp, lp, 16, 0, 0);
}

__device__ __forceinline__ f32x4 mfma16(bf16x8 a, bf16x8 b, f32x4 c){
  return __builtin_amdgcn_mfma_f32_16x16x32_bf16(a, b, c, 0, 0, 0);
}

__device__ __forceinline__ void vmwait0(){ asm volatile("s_waitcnt vmcnt(0)" ::: "memory"); }
__device__ __forceinline__ void vmwait8(){ asm volatile("s_waitcnt vmcnt(8)" ::: "memory"); }
__device__ __forceinline__ void barr(){ asm volatile("s_barrier" ::: "memory"); }

// ---------------- dtype detect + ticket reset (8 XCD-partition tickets, stride 16)
__global__ void k_detect(const u16* cosr, int* flag, int* ticket){
  if (threadIdx.x == 0) *flag = (cosr[0] == (u16)0x3F80u) ? 1 : 0;
  if (threadIdx.x < 128) ticket[threadIdx.x] = 0;
}

// ---------------- merged x-convert + 8 weight transposes (one launch)
struct TDesc { const void* src; u16* dst; int srcStride, dstStride, cblk, nbx, blk0; };
struct TPack { TDesc d[8]; };
#define CONVBLK 8192

__global__ void k_prep(const void* __restrict__ xsrc, u16* __restrict__ x_bf,
                       TPack p, const int* flag){
  __shared__ u16 tile[64][72];
  const int bid = blockIdx.x;
  const int tid = threadIdx.x;
  const int f = *flag;
  if (bid < CONVBLK){
    int id = bid * 256 + tid;                 // n4 = 2097152 = 8192*256 exactly
    if (f){
      reinterpret_cast<uint2*>(x_bf)[id] = reinterpret_cast<const uint2*>(xsrc)[id];
    } else {
      f4v v = reinterpret_cast<const f4v*>(xsrc)[id];
      unsigned lo = (unsigned)f2bf(v.x) | ((unsigned)f2bf(v.y) << 16);
      unsigned hi = (unsigned)f2bf(v.z) | ((unsigned)f2bf(v.w) << 16);
      reinterpret_cast<uint2*>(x_bf)[id] = make_uint2(lo, hi);
    }
    return;
  }
  const int tb = bid - CONVBLK;
  int i = 0;
  #pragma unroll
  for (int k = 1; k < 8; ++k) if (tb >= p.d[k].blk0) i = k;
  const void* src = p.d[i].src;
  u16* dst = p.d[i].dst;
  const int srcStride = p.d[i].srcStride, dstStride = p.d[i].dstStride;
  const int rel = tb - p.d[i].blk0;
  const int bx = rel % p.d[i].nbx, by = rel / p.d[i].nbx;
  const int r0 = by << 6, c0 = bx * p.d[i].cblk;
  #pragma unroll
  for (int it = 0; it < 2; ++it){
    int task = (it << 8) + tid;
    int r = task >> 3, c8 = (task & 7) << 3;
    if (f){
      const u16* pp = (const u16*)src + (size_t)(r0 + r) * srcStride + c0 + c8;
      u16x8 v = *reinterpret_cast<const u16x8*>(pp);
      #pragma unroll
      for (int j = 0; j < 8; ++j) tile[r][c8 + j] = v[j];
    } else {
      const float* pp = (const float*)src + (size_t)(r0 + r) * srcStride + c0 + c8;
      f4v a = reinterpret_cast<const f4v*>(pp)[0];
      f4v b = reinterpret_cast<const f4v*>(pp)[1];
      tile[r][c8+0]=f2bf(a.x); tile[r][c8+1]=f2bf(a.y); tile[r][c8+2]=f2bf(a.z); tile[r][c8+3]=f2bf(a.w);
      tile[r][c8+4]=f2bf(b.x); tile[r][c8+5]=f2bf(b.y); tile[r][c8+6]=f2bf(b.z); tile[r][c8+7]=f2bf(b.w);
    }
  }
  __syncthreads();
  #pragma unroll
  for (int it = 0; it < 2; ++it){
    int task = (it << 8) + tid;
    int rr = task >> 3, cc8 = (task & 7) << 3;
    u16x8 v;
    #pragma unroll
    for (int j = 0; j < 8; ++j) v[j] = tile[cc8 + j][rr];
    *reinterpret_cast<u16x8*>(dst + (size_t)((bx << 6) + rr) * dstStride + r0 + cc8) = v;
  }
}

// ---------------- unified 128x128 GEMM: 256 thr / 4 waves (2x2), 64x64 per wave,
// LDS 64 KB (2 buf x {A[128][64] + B[128][64]}) -> 2 blocks/CU.
// Row-XOR swizzle (byte ^= (row&7)<<4) via inverse-swizzled global_load_lds sources;
// counted vmcnt(8) pipeline (never 0 mid-loop); setprio around the MFMA cluster.
// Two groups selectable by N-tile index (heavy-K group dispatched first when swz=0).
__global__ __launch_bounds__(256, 2) void k_gemm(
    const u16* __restrict__ A0, int lda0, const u16* __restrict__ Bt0, int K0,
    u16* __restrict__ C0, int ldc0, float os0,
    const u16* __restrict__ A1, int lda1, const u16* __restrict__ Bt1, int K1,
    u16* __restrict__ C1, int ldc1, float os1,
    int ysplit, int swz, void* outp, const int* flag){
  __shared__ alignas(16) u16 lds[32768];   // 64 KB
  const int tid = threadIdx.x;
  const int wid = tid >> 6, lane = tid & 63;
  const int wr = wid >> 1, wc = wid & 1;
  const int l16 = lane & 15, g = lane >> 4;
  int lin = blockIdx.y * 32 + blockIdx.x;    // gridDim.x == 32 (M-tiles)
  if (swz){
    const int q8 = (gridDim.x * gridDim.y) >> 3;
    lin = (lin & 7) * q8 + (lin >> 3);       // bijective XCD chunking (nwg%8==0)
  }
  const int m0 = (lin & 31) << 7;
  int nt = lin >> 5;
  const u16 *A, *Bt; u16* C; int lda, K, ldc; float oscale;
  if (nt < ysplit){ A = A0; lda = lda0; Bt = Bt0; K = K0; C = C0; ldc = ldc0; oscale = os0; }
  else { nt -= ysplit; A = A1; lda = lda1; Bt = Bt1; K = K1; C = C1; ldc = ldc1; oscale = os1; }
  const int n0 = nt << 7;
  const size_t Kz = (size_t)K;
  const int nkt = K >> 6;

  auto STAGE = [&](int kt, int bufn){
    const int kb = kt << 6;
    #pragma unroll
    for (int q = 0; q < 8; ++q){
      const int ht = q >> 2;                 // 0 = A half, 1 = B half
      const int cq = ((q & 3) << 8) + tid;   // chunk 0..1023 within half
      const int Lb = cq << 4;                // byte in [128][128B] half-tile
      const int row = Lb >> 7;
      const int colb = (Lb & 127) ^ ((row & 7) << 4);   // inverse-swizzled source
      const u16* src = ht ? (Bt + (size_t)(n0 + row) * Kz + kb + (colb >> 1))
                          : (A  + (size_t)(m0 + row) * lda + kb + (colb >> 1));
      gld_lds16(src, &lds[bufn * 16384 + ht * 8192 + (cq << 3)]);
    }
  };

  f32x4 acc[4][4] = {};

  STAGE(0, 0);
  int buf = 0;

  for (int kt = 0; kt < nkt; ++kt){
    if (kt + 1 < nkt){ STAGE(kt + 1, buf ^ 1); vmwait8(); }   // waits tile-kt's 8 loads
    else vmwait0();
    barr();                                                    // staged tile visible to all
    bf16x8 af[2][4], bfr[2][4];
    #pragma unroll
    for (int ks = 0; ks < 2; ++ks){
      #pragma unroll
      for (int mi = 0; mi < 4; ++mi){
        int row = (wr << 6) + (mi << 4) + l16;
        int cb = ((ks << 6) + (g << 4)) ^ ((row & 7) << 4);
        af[ks][mi] = *reinterpret_cast<const bf16x8*>(&lds[buf * 16384 + (((row << 7) + cb) >> 1)]);
      }
      #pragma unroll
      for (int ni = 0; ni < 4; ++ni){
        int row = (wc << 6) + (ni << 4) + l16;
        int cb = ((ks << 6) + (g << 4)) ^ ((row & 7) << 4);
        bfr[ks][ni] = *reinterpret_cast<const bf16x8*>(&lds[buf * 16384 + 8192 + (((row << 7) + cb) >> 1)]);
      }
    }
    __builtin_amdgcn_s_setprio(1);
    #pragma unroll
    for (int ks = 0; ks < 2; ++ks)
      #pragma unroll
      for (int mi = 0; mi < 4; ++mi)
        #pragma unroll
        for (int ni = 0; ni < 4; ++ni)
          acc[mi][ni] = mfma16(af[ks][mi], bfr[ks][ni], acc[mi][ni]);
    __builtin_amdgcn_s_setprio(0);
    barr();                                  // reads done before next STAGE overwrites
    buf ^= 1;
  }

  const int r4 = g << 2;
  const int f = flag ? *flag : 1;
  #pragma unroll
  for (int mi = 0; mi < 4; ++mi){
    int row = m0 + (wr << 6) + (mi << 4) + r4;
    #pragma unroll
    for (int ni = 0; ni < 4; ++ni){
      int col = n0 + (wc << 6) + (ni << 4) + l16;
      #pragma unroll
      for (int j = 0; j < 4; ++j){
        float v = acc[mi][ni][j] * oscale;
        if (outp){
          if (f) ((u16*)outp)[(size_t)(row + j) * ldc + col] = f2bf(v);
          else   ((float*)outp)[(size_t)(row + j) * ldc + col] = v;
        } else {
          C[(size_t)(row + j) * ldc + col] = f2bf(v);
        }
      }
    }
  }
}

// ---------------- merged RoPE + vT build (one launch, 4096 blocks)
__global__ void k_ropevt(const u16* __restrict__ xc, const void* __restrict__ cosp,
                         const void* __restrict__ sinp, const int* flag,
                         u16* __restrict__ krope, u16* __restrict__ qrope,
                         const u16* __restrict__ kvP, u16* __restrict__ vT){
  __shared__ u16 tile[64][72];
  if (blockIdx.x < 2048){
    int id = blockIdx.x * 256 + threadIdx.x;   // exactly NROWS*128
    int row = id >> 7, c = id & 127;
    int t = row & (T_ - 1);
    int d = c & 63, i = d & 31;
    float cs, sn;
    if (*flag){ cs = bf2f(((const u16*)cosp)[t * 32 + i]); sn = bf2f(((const u16*)sinp)[t * 32 + i]); }
    else      { cs = ((const float*)cosp)[t * 32 + i];     sn = ((const float*)sinp)[t * 32 + i]; }
    int base = c & 64;
    float t1 = bf2f(xc[(size_t)row * 2304 + 2048 + base + i]);
    float t2 = bf2f(xc[(size_t)row * 2304 + 2048 + base + 32 + i]);
    float v = (d < 32) ? (t1 * cs - t2 * sn) : (t2 * cs + t1 * sn);
    if (c >= 64) v *= 0.12753139626374414f;
    ((c < 64) ? krope : qrope)[(size_t)row * 64 + d] = f2bf(v);
    return;
  }
  const int rel = blockIdx.x - 2048;
  const int t0 = (rel & 31) << 6, d0 = ((rel >> 5) & 1) << 6, bh = rel >> 6;
  const int b = bh >> 4, h = bh & 15;
  const int tid = threadIdx.x;
  #pragma unroll
  for (int i = 0; i < 2; ++i){
    int task = (i << 8) + tid;
    int r = task >> 3, c8 = (task & 7) << 3;
    const u16* p = kvP + (size_t)(b * T_ + t0 + r) * 3072 + 1024 + h * 128 + d0 + c8;
    u16x8 v = *reinterpret_cast<const u16x8*>(p);
    #pragma unroll
    for (int j = 0; j < 8; ++j) tile[r][c8 + j] = v[j];
  }
  __syncthreads();
  #pragma unroll
  for (int i = 0; i < 2; ++i){
    int task = (i << 8) + tid;
    int rr = task >> 3, cc8 = (task & 7) << 3;
    u16x8 v;
    #pragma unroll
    for (int j = 0; j < 8; ++j) v[j] = tile[cc8 + j][rr];
    *reinterpret_cast<u16x8*>(vT + ((size_t)bh * 128 + d0 + rr) * T_ + t0 + cc8) = v;
  }
}

// ---------------- causal flash attention (round-9 config + setprio; measured 89us)
__global__ __launch_bounds__(256, 2) void k_attn(const u16* __restrict__ qP,
                                                 const u16* __restrict__ kvP,
                                                 const u16* __restrict__ vT,
                                                 const u16* __restrict__ krope,
                                                 const u16* __restrict__ qrope,
                                                 u16* __restrict__ aout,
                                                 int* __restrict__ ticket){
  __shared__ alignas(16) u16 smem[32768];   // 64 KB: 2 buffers x (K [64][128] + V [128][64])
  const int tid = threadIdx.x, wid = tid >> 6, lane = tid & 63;
  const int l16 = lane & 15, g = lane >> 4;
  const int lk = g << 3, r4 = g << 2;
  const int sw8 = (l16 & 7) << 3;
  const int xcd = blockIdx.x & 7;

  while (true){
    if (tid == 0) *(int*)&smem[0] = atomicAdd(&ticket[xcd << 4], 1);
    __syncthreads();
    const int it = *(const int*)&smem[0];
    __syncthreads();
    if (it >= 128) break;
    const int qt = 31 - (it >> 2);          // heavy-first within partition
    const int bh = (xcd << 2) + (it & 3), b = bh >> 4, h = bh & 15;
    const int q0 = qt << 6;
    const size_t bT = (size_t)b * T_;
    const u16* kvPb = kvP + bT * 3072 + (h << 6);
    const u16* krb  = krope + bT * 64;
    const u16* vTb  = vT + (size_t)bh * 128 * T_;
    const int qlo = q0 + (wid << 4);
    const int nkv = qt + 1;

    auto STAGE = [&](int buf, int k0){
      const int base = buf << 14;
      #pragma unroll
      for (int r = 0; r < 8; ++r){
        int c = (r << 8) + tid;
        const u16* src;
        if (r < 4){
          int row = c >> 4, cc = c & 15;
          int ccx = (cc & 8) | ((cc & 7) ^ (row & 7));
          int col0 = ccx << 3;
          src = (col0 < 64) ? (kvPb + (size_t)(k0 + row) * 3072 + col0)
                            : (krb  + (size_t)(k0 + row) * 64 + (col0 - 64));
        } else {
          int cv = c - 1024;
          int row = cv >> 3, cc = cv & 7;
          int ccx = cc ^ (row & 7);
          src = vTb + (size_t)row * T_ + k0 + (ccx << 3);
        }
        gld_lds16(src, &smem[base + (((r << 8) + (wid << 6)) << 3)]);
      }
    };

    bf16x8 qf[4];
    {
      size_t grow = bT + qlo + l16;
      #pragma unroll
      for (int ks = 0; ks < 4; ++ks){
        int d = (ks << 5) + lk;
        const u16* src = (ks < 2) ? (qP + grow * 1024 + (h << 6) + d)
                                  : (qrope + grow * 64 + (d - 64));
        qf[ks] = *reinterpret_cast<const bf16x8*>(src);
      }
    }
    f32x4 o[8] = {};
    float m = -3e38f, l = 0.f;

    STAGE(0, 0);
    __syncthreads();
    int cur = 0;

    for (int kv = 0; kv < nkv; ++kv){
      const int k0 = kv << 6;
      if (kv + 1 < nkv) STAGE(cur ^ 1, (kv + 1) << 6);
      const int kb = cur << 14;
      f32x4 s[4] = {};
      __builtin_amdgcn_s_setprio(1);
      #pragma unroll
      for (int ks = 0; ks < 4; ++ks){
        int colsw = ((ks << 5) + lk) ^ sw8;
        #pragma unroll
        for (int n = 0; n < 4; ++n){
          bf16x8 kf = *reinterpret_cast<const bf16x8*>(&smem[kb + ((n << 4) + l16) * 128 + colsw]);
          s[n] = mfma16(kf, qf[ks], s[n]);
        }
      }
      __builtin_amdgcn_s_setprio(0);
      if (k0 == q0){
        const int tq = qlo + l16;
        #pragma unroll
        for (int n = 0; n < 4; ++n)
          #pragma unroll
          for (int j = 0; j < 4; ++j)
            s[n][j] = (k0 + (n << 4) + r4 + j <= tq) ? s[n][j] : -3e38f;
      }
      float mx;
      {
        float a0 = fmaxf(fmaxf(s[0][0], s[0][1]), fmaxf(s[0][2], s[0][3]));
        float a1 = fmaxf(fmaxf(s[1][0], s[1][1]), fmaxf(s[1][2], s[1][3]));
        float a2 = fmaxf(fmaxf(s[2][0], s[2][1]), fmaxf(s[2][2], s[2][3]));
        float a3 = fmaxf(fmaxf(s[3][0], s[3][1]), fmaxf(s[3][2], s[3][3]));
        mx = fmaxf(fmaxf(a0, a1), fmaxf(a2, a3));
        mx = fmaxf(mx, __shfl_xor(mx, 16));
        mx = fmaxf(mx, __shfl_xor(mx, 32));
      }
      if (__ballot(mx > m + 8.f)){
        float mnew = fmaxf(m, mx);
        float alpha = exp2f(m - mnew);
        m = mnew; l *= alpha;
        #pragma unroll
        for (int j = 0; j < 4; ++j){
          float av = __shfl(alpha, r4 + j);
          #pragma unroll
          for (int db = 0; db < 8; ++db) o[db][j] *= av;
        }
      }
      unsigned w[4][2];
      float rs = 0.f;
      #pragma unroll
      for (int n = 0; n < 4; ++n)
        #pragma unroll
        for (int jh = 0; jh < 2; ++jh){
          float p0 = exp2f(s[n][2*jh]     - m);
          float p1 = exp2f(s[n][2*jh + 1] - m);
          rs += p0 + p1;
          w[n][jh] = cvt_pk_bf16(p0, p1);
        }
      rs += __shfl_xor(rs, 16);
      rs += __shfl_xor(rs, 32);
      l += rs;
      const int srcA = l16 + ((g & 1) << 5);
      const int srcB = srcA + 16;
      const bool hi = (g >= 2);
      bf16x8 pa[2];
      #pragma unroll
      for (int ks2 = 0; ks2 < 2; ++ks2){
        unsigned a0 = __shfl((int)w[2*ks2][0],     srcA);
        unsigned b0 = __shfl((int)w[2*ks2 + 1][0], srcA);
        unsigned a1 = __shfl((int)w[2*ks2][1],     srcA);
        unsigned b1 = __shfl((int)w[2*ks2 + 1][1], srcA);
        unsigned a2 = __shfl((int)w[2*ks2][0],     srcB);
        unsigned b2 = __shfl((int)w[2*ks2 + 1][0], srcB);
        unsigned a3 = __shfl((int)w[2*ks2][1],     srcB);
        unsigned b3 = __shfl((int)w[2*ks2 + 1][1], srcB);
        union { unsigned u[4]; bf16x8 v; } pk;
        pk.u[0] = hi ? b0 : a0;
        pk.u[1] = hi ? b1 : a1;
        pk.u[2] = hi ? b2 : a2;
        pk.u[3] = hi ? b3 : a3;
        pa[ks2] = pk.v;
      }
      __builtin_amdgcn_s_setprio(1);
      #pragma unroll
      for (int ks2 = 0; ks2 < 2; ++ks2){
        int colsw = ((ks2 << 5) + lk) ^ sw8;
        #pragma unroll
        for (int db = 0; db < 8; ++db){
          bf16x8 vb = *reinterpret_cast<const bf16x8*>(&smem[kb + 8192 + ((db << 4) + l16) * 64 + colsw]);
          o[db] = mfma16(pa[ks2], vb, o[db]);
        }
      }
      __builtin_amdgcn_s_setprio(0);
      __syncthreads();
      cur ^= 1;
    }
    #pragma unroll
    for (int j = 0; j < 4; ++j){
      float lv = __shfl(l, r4 + j);
      float rinv = 1.f / lv;
      const int tq = qlo + r4 + j;
      u16* dst = aout + (bT + tq) * 2048 + (h << 7) + l16;
      #pragma unroll
      for (int db = 0; db < 8; ++db)
        dst[db << 4] = f2bf(o[db][j] * rinv);
    }
  }
}

extern "C" void kernel_launch(void* const* d_in, const int* in_sizes, int n_in,
                              void* d_out, int out_size, void* d_ws, size_t ws_size,
                              hipStream_t stream){
  const void* x       = d_in[0];
  const void* cosp    = d_in[1];
  const void* sinp    = d_in[2];
  const void* w_kv    = d_in[3];
  const void* w_kdec  = d_in[4];
  const void* w_vdec  = d_in[5];
  const void* w_qc    = d_in[6];
  const void* w_qdec  = d_in[7];
  const void* w_krope = d_in[8];
  const void* w_qrope = d_in[9];
  const void* w_o     = d_in[10];

  char* ws = (char*)d_ws;
  size_t off = 0;
  auto alloc = [&](size_t bytes){ void* p = ws + off; off += (bytes + 255) & ~(size_t)255; return p; };
  int* flag     = (int*)alloc(256);
  int* ticket   = (int*)alloc(1024);                         // 8 tickets, stride 16 ints
  u16* x_bf     = (u16*)alloc((size_t)NROWS * DIM_ * 2);
  u16* w_c1T    = (u16*)alloc((size_t)2304 * DIM_ * 2);      // [kvT(512); qcT(1536); kropeT(64); qropeT(64); pad(128)] x 2048
  u16* w_kvdT   = (u16*)alloc((size_t)3072 * DC_ * 2);       // [kdecPackedT(1024); vdecT(2048)] x 512
  u16* w_qdPT   = (u16*)alloc((size_t)1024 * DCQ_ * 2);      // packed qdecT (1024 x 1536)
  u16* w_oT     = (u16*)alloc((size_t)DIM_ * DIM_ * 2);
  u16* xc       = (u16*)alloc((size_t)NROWS * 2304 * 2);     // [c_kv(512) | c_q(1536) | ropes(128) | pad(128)]
  u16* qP       = (u16*)alloc((size_t)NROWS * 1024 * 2);     // packed q decode (pre-scaled)
  u16* kvP      = (u16*)alloc((size_t)NROWS * 3072 * 2);     // [kPacked(1024) | v(2048)]
  u16* krope    = (u16*)alloc((size_t)NROWS * 64 * 2);
  u16* qrope    = (u16*)alloc((size_t)NROWS * 64 * 2);       // pre-scaled
  u16* vT       = (u16*)alloc((size_t)32 * 128 * T_ * 2);    // [bh][d][t]
  u16* aout     = (u16*)alloc((size_t)NROWS * DIM_ * 2);
  (void)in_sizes; (void)n_in; (void)out_size; (void)ws_size;

  const float SC2 = 0.12753139626374414f;   // 1/sqrt(128) * log2(e)

  hipLaunchKernelGGL(k_detect, dim3(1), dim3(128), 0, stream, (const u16*)cosp, flag, ticket);

  // merged x-convert + weight transposes (8192 conv blocks + 2880 transpose blocks)
  TPack tp;
  tp.d[0] = { w_kv,    w_c1T,                        512,  2048, 64,  8,  0    };
  tp.d[1] = { w_qc,    w_c1T + (size_t)512 * 2048,   1536, 2048, 64,  24, 256  };
  tp.d[2] = { w_krope, w_c1T + (size_t)2048 * 2048,  64,   2048, 64,  1,  1024 };
  tp.d[3] = { w_qrope, w_c1T + (size_t)2112 * 2048,  64,   2048, 64,  1,  1056 };
  tp.d[4] = { w_kdec,  w_kvdT,                       2048, 512,  128, 16, 1088 };
  tp.d[5] = { w_vdec,  w_kvdT + (size_t)1024 * 512,  2048, 512,  64,  32, 1216 };
  tp.d[6] = { w_qdec,  w_qdPT,                       2048, 1536, 128, 16, 1472 };
  tp.d[7] = { w_o,     w_oT,                         2048, 2048, 64,  32, 1856 };
  hipLaunchKernelGGL(k_prep, dim3(CONVBLK + 2880), dim3(256), 0, stream, x, x_bf, tp, flag);

  // G13: xc = x @ [w_kv | w_qc | w_krope | w_qrope | pad]  (4096 x 2304, K=2048)
  // 128^2 tiles: (32, 18) = 576 blocks (2/CU -> 1.125 rounds), XCD-chunked
  hipLaunchKernelGGL(k_gemm, dim3(32, 18), dim3(256), 0, stream,
                     x_bf, DIM_, w_c1T, DIM_, xc, 2304, 1.0f,
                     x_bf, DIM_, w_c1T, DIM_, xc, 2304, 1.0f,
                     18, 1, (void*)nullptr, (const int*)nullptr);
  // G4 + G2 grouped on 128^2 tiles (1024 blocks; heavy K=1536 group dispatched first):
  //   nt<8:  qP = xc[:, 512:2048] @ w_qdecP  (4096 x 1024, K=1536), pre-scaled
  //   nt>=8: kvP = xc[:, :512] @ [w_kdecP | w_vdec]  (4096 x 3072, K=512)
  hipLaunchKernelGGL(k_gemm, dim3(32, 32), dim3(256), 0, stream,
                     xc + 512, 2304, w_qdPT, DCQ_, qP, 1024, SC2,
                     xc, 2304, w_kvdT, DC_, kvP, 3072, 1.0f,
                     8, 0, (void*)nullptr, (const int*)nullptr);
  // merged RoPE + vT (2048 + 2048 blocks)
  hipLaunchKernelGGL(k_ropevt, dim3(4096), dim3(256), 0, stream,
                     xc, cosp, sinp, flag, krope, qrope, kvP, vT);
  // attention (512 workers = 2 blocks/CU, 2:1 stealing, XCD-partitioned tickets)
  hipLaunchKernelGGL(k_attn, dim3(512), dim3(256), 0, stream,
                     qP, kvP, vT, krope, qrope, aout, ticket);
  // G5: out = aout @ w_o  (4096 x 2048, K=2048) -> (32,16) = 512 blocks = exactly 2/CU, XCD-chunked
  hipLaunchKernelGGL(k_gemm, dim3(32, 16), dim3(256), 0, stream,
                     aout, DIM_, w_oT, DIM_, (u16*)nullptr, DIM_, 1.0f,
                     aout, DIM_, w_oT, DIM_, (u16*)nullptr, DIM_, 1.0f,
                     16, 1, d_out, (const int*)flag);
}

// Round 16
// 249.790 us; speedup vs baseline: 1.4075x; 1.0157x over previous
//
#include <hip/hip_runtime.h>
#include <stdint.h>
#include <math.h>

#define B_    2
#define T_    2048
#define DIM_  2048
#define H_    16
#define DC_   512
#define DCQ_  1536
#define NROWS (B_*T_)   // 4096

typedef unsigned short u16;
typedef __attribute__((ext_vector_type(8))) __bf16 bf16x8;
typedef __attribute__((ext_vector_type(4))) float  f32x4;
typedef __attribute__((ext_vector_type(8))) unsigned short u16x8;
typedef __attribute__((ext_vector_type(4))) float  f4v;

__device__ __forceinline__ u16 f2bf(float f){
  unsigned u = __float_as_uint(f);
  u += 0x7FFFu + ((u >> 16) & 1u);   // RNE
  return (u16)(u >> 16);
}
__device__ __forceinline__ float bf2f(u16 h){ return __uint_as_float(((unsigned)h) << 16); }

__device__ __forceinline__ unsigned cvt_pk_bf16(float lo, float hi){
  unsigned r;
  asm("v_cvt_pk_bf16_f32 %0, %1, %2" : "=v"(r) : "v"(lo), "v"(hi));
  return r;
}

// async global->LDS, 16B per lane; LDS dest = wave-uniform base + lane*16.
__device__ __forceinline__ void gld_lds16(const void* g, void* l){
  auto gp = reinterpret_cast<__attribute__((address_space(1))) unsigned int*>(
      reinterpret_cast<uintptr_t>(g));
  auto lp = reinterpret_cast<__attribute__((address_space(3))) unsigned int*>(
      reinterpret_cast<uintptr_t>(l));
  __builtin_amdgcn_global_load_lds(gp, lp, 16, 0, 0);
}

__device__ __forceinline__ f32x4 mfma16(bf16x8 a, bf16x8 b, f32x4 c){
  return __builtin_amdgcn_mfma_f32_16x16x32_bf16(a, b, c, 0, 0, 0);
}

__device__ __forceinline__ void vmwait0(){ asm volatile("s_waitcnt vmcnt(0)" ::: "memory"); }
__device__ __forceinline__ void vmwait8(){ asm volatile("s_waitcnt vmcnt(8)" ::: "memory"); }
__device__ __forceinline__ void barr(){ asm volatile("s_barrier" ::: "memory"); }

// ---------------- dtype detect + ticket reset (8 XCD-partition tickets, stride 16)
__global__ void k_detect(const u16* cosr, int* flag, int* ticket){
  if (threadIdx.x == 0) *flag = (cosr[0] == (u16)0x3F80u) ? 1 : 0;
  if (threadIdx.x < 128) ticket[threadIdx.x] = 0;
}

// ---------------- merged x-convert + 8 weight transposes (one launch)
struct TDesc { const void* src; u16* dst; int srcStride, dstStride, cblk, nbx, blk0; };
struct TPack { TDesc d[8]; };
#define CONVBLK 8192

__global__ void k_prep(const void* __restrict__ xsrc, u16* __restrict__ x_bf,
                       TPack p, const int* flag){
  __shared__ u16 tile[64][72];
  const int bid = blockIdx.x;
  const int tid = threadIdx.x;
  const int f = *flag;
  if (bid < CONVBLK){
    if (f) return;                            // bf16 input: G13 reads x directly, skip copy
    int id = bid * 256 + tid;                 // n4 = 2097152 = 8192*256 exactly
    f4v v = reinterpret_cast<const f4v*>(xsrc)[id];
    unsigned lo = (unsigned)f2bf(v.x) | ((unsigned)f2bf(v.y) << 16);
    unsigned hi = (unsigned)f2bf(v.z) | ((unsigned)f2bf(v.w) << 16);
    reinterpret_cast<uint2*>(x_bf)[id] = make_uint2(lo, hi);
    return;
  }
  const int tb = bid - CONVBLK;
  int i = 0;
  #pragma unroll
  for (int k = 1; k < 8; ++k) if (tb >= p.d[k].blk0) i = k;
  const void* src = p.d[i].src;
  u16* dst = p.d[i].dst;
  const int srcStride = p.d[i].srcStride, dstStride = p.d[i].dstStride;
  const int rel = tb - p.d[i].blk0;
  const int bx = rel % p.d[i].nbx, by = rel / p.d[i].nbx;
  const int r0 = by << 6, c0 = bx * p.d[i].cblk;
  #pragma unroll
  for (int it = 0; it < 2; ++it){
    int task = (it << 8) + tid;
    int r = task >> 3, c8 = (task & 7) << 3;
    if (f){
      const u16* pp = (const u16*)src + (size_t)(r0 + r) * srcStride + c0 + c8;
      u16x8 v = *reinterpret_cast<const u16x8*>(pp);
      #pragma unroll
      for (int j = 0; j < 8; ++j) tile[r][c8 + j] = v[j];
    } else {
      const float* pp = (const float*)src + (size_t)(r0 + r) * srcStride + c0 + c8;
      f4v a = reinterpret_cast<const f4v*>(pp)[0];
      f4v b = reinterpret_cast<const f4v*>(pp)[1];
      tile[r][c8+0]=f2bf(a.x); tile[r][c8+1]=f2bf(a.y); tile[r][c8+2]=f2bf(a.z); tile[r][c8+3]=f2bf(a.w);
      tile[r][c8+4]=f2bf(b.x); tile[r][c8+5]=f2bf(b.y); tile[r][c8+6]=f2bf(b.z); tile[r][c8+7]=f2bf(b.w);
    }
  }
  __syncthreads();
  #pragma unroll
  for (int it = 0; it < 2; ++it){
    int task = (it << 8) + tid;
    int rr = task >> 3, cc8 = (task & 7) << 3;
    u16x8 v;
    #pragma unroll
    for (int j = 0; j < 8; ++j) v[j] = tile[cc8 + j][rr];
    *reinterpret_cast<u16x8*>(dst + (size_t)((bx << 6) + rr) * dstStride + r0 + cc8) = v;
  }
}

// ---------------- unified 128x128 GEMM: 256 thr / 4 waves (2x2), 64x64 per wave,
// LDS 64 KB -> 2 blocks/CU. Row-XOR swizzle via inverse-swizzled global_load_lds sources;
// counted vmcnt(8) pipeline; setprio around MFMA cluster. Two groups by N-tile index.
// Optional alt-A pointers used when *flag (bf16 passthrough of unconverted input).
__global__ __launch_bounds__(256, 2) void k_gemm(
    const u16* __restrict__ A0, int lda0, const u16* __restrict__ Bt0, int K0,
    u16* __restrict__ C0, int ldc0, float os0,
    const u16* __restrict__ A1, int lda1, const u16* __restrict__ Bt1, int K1,
    u16* __restrict__ C1, int ldc1, float os1,
    int ysplit, int swz, void* outp, const int* flag,
    const u16* __restrict__ alt0, const u16* __restrict__ alt1){
  __shared__ alignas(16) u16 lds[32768];   // 64 KB
  const int tid = threadIdx.x;
  const int wid = tid >> 6, lane = tid & 63;
  const int wr = wid >> 1, wc = wid & 1;
  const int l16 = lane & 15, g = lane >> 4;
  int lin = blockIdx.y * 32 + blockIdx.x;    // gridDim.x == 32 (M-tiles)
  if (swz){
    const int q8 = (gridDim.x * gridDim.y) >> 3;
    lin = (lin & 7) * q8 + (lin >> 3);       // bijective XCD chunking (nwg%8==0)
  }
  const int m0 = (lin & 31) << 7;
  int nt = lin >> 5;
  const u16 *A, *Bt, *alt; u16* C; int lda, K, ldc; float oscale;
  if (nt < ysplit){ A = A0; lda = lda0; Bt = Bt0; K = K0; C = C0; ldc = ldc0; oscale = os0; alt = alt0; }
  else { nt -= ysplit; A = A1; lda = lda1; Bt = Bt1; K = K1; C = C1; ldc = ldc1; oscale = os1; alt = alt1; }
  const int f = flag ? *flag : 1;
  if (alt && f) A = alt;                     // bf16 input: read source directly
  const int n0 = nt << 7;
  const size_t Kz = (size_t)K;
  const int nkt = K >> 6;

  auto STAGE = [&](int kt, int bufn){
    const int kb = kt << 6;
    #pragma unroll
    for (int q = 0; q < 8; ++q){
      const int ht = q >> 2;                 // 0 = A half, 1 = B half
      const int cq = ((q & 3) << 8) + tid;   // chunk 0..1023 within half
      const int Lb = cq << 4;                // byte in [128][128B] half-tile
      const int row = Lb >> 7;
      const int colb = (Lb & 127) ^ ((row & 7) << 4);   // inverse-swizzled source
      const u16* src = ht ? (Bt + (size_t)(n0 + row) * Kz + kb + (colb >> 1))
                          : (A  + (size_t)(m0 + row) * lda + kb + (colb >> 1));
      gld_lds16(src, &lds[bufn * 16384 + ht * 8192 + (cq << 3)]);
    }
  };

  f32x4 acc[4][4] = {};

  STAGE(0, 0);
  int buf = 0;

  for (int kt = 0; kt < nkt; ++kt){
    if (kt + 1 < nkt){ STAGE(kt + 1, buf ^ 1); vmwait8(); }   // waits tile-kt's 8 loads
    else vmwait0();
    barr();                                                    // staged tile visible to all
    bf16x8 af[2][4], bfr[2][4];
    #pragma unroll
    for (int ks = 0; ks < 2; ++ks){
      #pragma unroll
      for (int mi = 0; mi < 4; ++mi){
        int row = (wr << 6) + (mi << 4) + l16;
        int cb = ((ks << 6) + (g << 4)) ^ ((row & 7) << 4);
        af[ks][mi] = *reinterpret_cast<const bf16x8*>(&lds[buf * 16384 + (((row << 7) + cb) >> 1)]);
      }
      #pragma unroll
      for (int ni = 0; ni < 4; ++ni){
        int row = (wc << 6) + (ni << 4) + l16;
        int cb = ((ks << 6) + (g << 4)) ^ ((row & 7) << 4);
        bfr[ks][ni] = *reinterpret_cast<const bf16x8*>(&lds[buf * 16384 + 8192 + (((row << 7) + cb) >> 1)]);
      }
    }
    __builtin_amdgcn_s_setprio(1);
    #pragma unroll
    for (int ks = 0; ks < 2; ++ks)
      #pragma unroll
      for (int mi = 0; mi < 4; ++mi)
        #pragma unroll
        for (int ni = 0; ni < 4; ++ni)
          acc[mi][ni] = mfma16(af[ks][mi], bfr[ks][ni], acc[mi][ni]);
    __builtin_amdgcn_s_setprio(0);
    barr();                                  // reads done before next STAGE overwrites
    buf ^= 1;
  }

  const int r4 = g << 2;
  #pragma unroll
  for (int mi = 0; mi < 4; ++mi){
    int row = m0 + (wr << 6) + (mi << 4) + r4;
    #pragma unroll
    for (int ni = 0; ni < 4; ++ni){
      int col = n0 + (wc << 6) + (ni << 4) + l16;
      #pragma unroll
      for (int j = 0; j < 4; ++j){
        float v = acc[mi][ni][j] * oscale;
        if (outp){
          if (f) ((u16*)outp)[(size_t)(row + j) * ldc + col] = f2bf(v);
          else   ((float*)outp)[(size_t)(row + j) * ldc + col] = v;
        } else {
          C[(size_t)(row + j) * ldc + col] = f2bf(v);
        }
      }
    }
  }
}

// ---------------- merged RoPE + vT build (one launch, 4096 blocks)
__global__ void k_ropevt(const u16* __restrict__ xc, const void* __restrict__ cosp,
                         const void* __restrict__ sinp, const int* flag,
                         u16* __restrict__ krope, u16* __restrict__ qrope,
                         const u16* __restrict__ kvP, u16* __restrict__ vT){
  __shared__ u16 tile[64][72];
  if (blockIdx.x < 2048){
    int id = blockIdx.x * 256 + threadIdx.x;   // exactly NROWS*128
    int row = id >> 7, c = id & 127;
    int t = row & (T_ - 1);
    int d = c & 63, i = d & 31;
    float cs, sn;
    if (*flag){ cs = bf2f(((const u16*)cosp)[t * 32 + i]); sn = bf2f(((const u16*)sinp)[t * 32 + i]); }
    else      { cs = ((const float*)cosp)[t * 32 + i];     sn = ((const float*)sinp)[t * 32 + i]; }
    int base = c & 64;
    float t1 = bf2f(xc[(size_t)row * 2304 + 2048 + base + i]);
    float t2 = bf2f(xc[(size_t)row * 2304 + 2048 + base + 32 + i]);
    float v = (d < 32) ? (t1 * cs - t2 * sn) : (t2 * cs + t1 * sn);
    if (c >= 64) v *= 0.12753139626374414f;
    ((c < 64) ? krope : qrope)[(size_t)row * 64 + d] = f2bf(v);
    return;
  }
  const int rel = blockIdx.x - 2048;
  const int t0 = (rel & 31) << 6, d0 = ((rel >> 5) & 1) << 6, bh = rel >> 6;
  const int b = bh >> 4, h = bh & 15;
  const int tid = threadIdx.x;
  #pragma unroll
  for (int i = 0; i < 2; ++i){
    int task = (i << 8) + tid;
    int r = task >> 3, c8 = (task & 7) << 3;
    const u16* p = kvP + (size_t)(b * T_ + t0 + r) * 3072 + 1024 + h * 128 + d0 + c8;
    u16x8 v = *reinterpret_cast<const u16x8*>(p);
    #pragma unroll
    for (int j = 0; j < 8; ++j) tile[r][c8 + j] = v[j];
  }
  __syncthreads();
  #pragma unroll
  for (int i = 0; i < 2; ++i){
    int task = (i << 8) + tid;
    int rr = task >> 3, cc8 = (task & 7) << 3;
    u16x8 v;
    #pragma unroll
    for (int j = 0; j < 8; ++j) v[j] = tile[cc8 + j][rr];
    *reinterpret_cast<u16x8*>(vT + ((size_t)bh * 128 + d0 + rr) * T_ + t0 + cc8) = v;
  }
}

// ---------------- causal flash attention: 128-row items, 8 waves x 16 rows (512 thr).
// Same 64KB LDS double-buffer per tile now feeds 2x the MFMA work -> staging bytes and
// barriers per unit work halve. 256 workers (1 block/CU, 8 waves = same waves/CU as the
// 512x4-wave config), per-XCD tickets: 64 items over 32 workers = 2:1 heavy-first stealing.
// Waves whose rows end before the last tile skip compute (barriers outside the guard).
__global__ __launch_bounds__(512, 2) void k_attn(const u16* __restrict__ qP,
                                                 const u16* __restrict__ kvP,
                                                 const u16* __restrict__ vT,
                                                 const u16* __restrict__ krope,
                                                 const u16* __restrict__ qrope,
                                                 u16* __restrict__ aout,
                                                 int* __restrict__ ticket){
  __shared__ alignas(16) u16 smem[32768];   // 64 KB: 2 buffers x (K [64][128] + V [128][64])
  const int tid = threadIdx.x, wid = tid >> 6, lane = tid & 63;
  const int l16 = lane & 15, g = lane >> 4;
  const int lk = g << 3, r4 = g << 2;
  const int sw8 = (l16 & 7) << 3;
  const int xcd = blockIdx.x & 7;

  while (true){
    if (tid == 0) *(int*)&smem[0] = atomicAdd(&ticket[xcd << 4], 1);
    __syncthreads();
    const int it = *(const int*)&smem[0];
    __syncthreads();
    if (it >= 64) break;
    const int qt = 15 - (it >> 2);          // heavy-first within partition (128-row tiles)
    const int bh = (xcd << 2) + (it & 3), b = bh >> 4, h = bh & 15;
    const int q0 = qt << 7;
    const size_t bT = (size_t)b * T_;
    const u16* kvPb = kvP + bT * 3072 + (h << 6);
    const u16* krb  = krope + bT * 64;
    const u16* vTb  = vT + (size_t)bh * 128 * T_;
    const int qlo = q0 + (wid << 4);
    const int qhi = qlo + 15;
    const int nkv = (qt << 1) + 2;

    auto STAGE = [&](int buf, int k0){
      const int base = buf << 14;
      #pragma unroll
      for (int r = 0; r < 4; ++r){
        int c = (r << 9) + tid;              // 0..2047 chunks of 16B
        const u16* src;
        if (r < 2){
          int row = c >> 4, cc = c & 15;
          int ccx = (cc & 8) | ((cc & 7) ^ (row & 7));
          int col0 = ccx << 3;
          src = (col0 < 64) ? (kvPb + (size_t)(k0 + row) * 3072 + col0)
                            : (krb  + (size_t)(k0 + row) * 64 + (col0 - 64));
        } else {
          int cv = c - 1024;
          int row = cv >> 3, cc = cv & 7;
          int ccx = cc ^ (row & 7);
          src = vTb + (size_t)row * T_ + k0 + (ccx << 3);
        }
        gld_lds16(src, &smem[base + (c << 3)]);
      }
    };

    bf16x8 qf[4];
    {
      size_t grow = bT + qlo + l16;
      #pragma unroll
      for (int ks = 0; ks < 4; ++ks){
        int d = (ks << 5) + lk;
        const u16* src = (ks < 2) ? (qP + grow * 1024 + (h << 6) + d)
                                  : (qrope + grow * 64 + (d - 64));
        qf[ks] = *reinterpret_cast<const bf16x8*>(src);
      }
    }
    f32x4 o[8] = {};
    float m = -3e38f, l = 0.f;

    STAGE(0, 0);
    __syncthreads();
    int cur = 0;

    for (int kv = 0; kv < nkv; ++kv){
      const int k0 = kv << 6;
      if (kv + 1 < nkv) STAGE(cur ^ 1, (kv + 1) << 6);
      if (k0 <= qhi){
        const int kb = cur << 14;
        f32x4 s[4] = {};
        __builtin_amdgcn_s_setprio(1);
        #pragma unroll
        for (int ks = 0; ks < 4; ++ks){
          int colsw = ((ks << 5) + lk) ^ sw8;
          #pragma unroll
          for (int n = 0; n < 4; ++n){
            bf16x8 kf = *reinterpret_cast<const bf16x8*>(&smem[kb + ((n << 4) + l16) * 128 + colsw]);
            s[n] = mfma16(kf, qf[ks], s[n]);
          }
        }
        __builtin_amdgcn_s_setprio(0);
        if (k0 + 63 > qlo){                  // only the wave's diagonal tile needs masking
          const int tq = qlo + l16;
          #pragma unroll
          for (int n = 0; n < 4; ++n)
            #pragma unroll
            for (int j = 0; j < 4; ++j)
              s[n][j] = (k0 + (n << 4) + r4 + j <= tq) ? s[n][j] : -3e38f;
        }
        float mx;
        {
          float a0 = fmaxf(fmaxf(s[0][0], s[0][1]), fmaxf(s[0][2], s[0][3]));
          float a1 = fmaxf(fmaxf(s[1][0], s[1][1]), fmaxf(s[1][2], s[1][3]));
          float a2 = fmaxf(fmaxf(s[2][0], s[2][1]), fmaxf(s[2][2], s[2][3]));
          float a3 = fmaxf(fmaxf(s[3][0], s[3][1]), fmaxf(s[3][2], s[3][3]));
          mx = fmaxf(fmaxf(a0, a1), fmaxf(a2, a3));
          mx = fmaxf(mx, __shfl_xor(mx, 16));
          mx = fmaxf(mx, __shfl_xor(mx, 32));
        }
        if (__ballot(mx > m + 8.f)){
          float mnew = fmaxf(m, mx);
          float alpha = exp2f(m - mnew);
          m = mnew; l *= alpha;
          #pragma unroll
          for (int j = 0; j < 4; ++j){
            float av = __shfl(alpha, r4 + j);
            #pragma unroll
            for (int db = 0; db < 8; ++db) o[db][j] *= av;
          }
        }
        unsigned w[4][2];
        float rs = 0.f;
        #pragma unroll
        for (int n = 0; n < 4; ++n)
          #pragma unroll
          for (int jh = 0; jh < 2; ++jh){
            float p0 = exp2f(s[n][2*jh]     - m);
            float p1 = exp2f(s[n][2*jh + 1] - m);
            rs += p0 + p1;
            w[n][jh] = cvt_pk_bf16(p0, p1);
          }
        rs += __shfl_xor(rs, 16);
        rs += __shfl_xor(rs, 32);
        l += rs;
        const int srcA = l16 + ((g & 1) << 5);
        const int srcB = srcA + 16;
        const bool hi = (g >= 2);
        bf16x8 pa[2];
        #pragma unroll
        for (int ks2 = 0; ks2 < 2; ++ks2){
          unsigned a0 = __shfl((int)w[2*ks2][0],     srcA);
          unsigned b0 = __shfl((int)w[2*ks2 + 1][0], srcA);
          unsigned a1 = __shfl((int)w[2*ks2][1],     srcA);
          unsigned b1 = __shfl((int)w[2*ks2 + 1][1], srcA);
          unsigned a2 = __shfl((int)w[2*ks2][0],     srcB);
          unsigned b2 = __shfl((int)w[2*ks2 + 1][0], srcB);
          unsigned a3 = __shfl((int)w[2*ks2][1],     srcB);
          unsigned b3 = __shfl((int)w[2*ks2 + 1][1], srcB);
          union { unsigned u[4]; bf16x8 v; } pk;
          pk.u[0] = hi ? b0 : a0;
          pk.u[1] = hi ? b1 : a1;
          pk.u[2] = hi ? b2 : a2;
          pk.u[3] = hi ? b3 : a3;
          pa[ks2] = pk.v;
        }
        __builtin_amdgcn_s_setprio(1);
        #pragma unroll
        for (int ks2 = 0; ks2 < 2; ++ks2){
          int colsw = ((ks2 << 5) + lk) ^ sw8;
          #pragma unroll
          for (int db = 0; db < 8; ++db){
            bf16x8 vb = *reinterpret_cast<const bf16x8*>(&smem[(cur << 14) + 8192 + ((db << 4) + l16) * 64 + colsw]);
            o[db] = mfma16(pa[ks2], vb, o[db]);
          }
        }
        __builtin_amdgcn_s_setprio(0);
      }
      __syncthreads();                      // drains prefetch; reads done before buffer reuse
      cur ^= 1;
    }
    #pragma unroll
    for (int j = 0; j < 4; ++j){
      float lv = __shfl(l, r4 + j);
      float rinv = 1.f / lv;
      const int tq = qlo + r4 + j;
      u16* dst = aout + (bT + tq) * 2048 + (h << 7) + l16;
      #pragma unroll
      for (int db = 0; db < 8; ++db)
        dst[db << 4] = f2bf(o[db][j] * rinv);
    }
  }
}

extern "C" void kernel_launch(void* const* d_in, const int* in_sizes, int n_in,
                              void* d_out, int out_size, void* d_ws, size_t ws_size,
                              hipStream_t stream){
  const void* x       = d_in[0];
  const void* cosp    = d_in[1];
  const void* sinp    = d_in[2];
  const void* w_kv    = d_in[3];
  const void* w_kdec  = d_in[4];
  const void* w_vdec  = d_in[5];
  const void* w_qc    = d_in[6];
  const void* w_qdec  = d_in[7];
  const void* w_krope = d_in[8];
  const void* w_qrope = d_in[9];
  const void* w_o     = d_in[10];

  char* ws = (char*)d_ws;
  size_t off = 0;
  auto alloc = [&](size_t bytes){ void* p = ws + off; off += (bytes + 255) & ~(size_t)255; return p; };
  int* flag     = (int*)alloc(256);
  int* ticket   = (int*)alloc(1024);                         // 8 tickets, stride 16 ints
  u16* x_bf     = (u16*)alloc((size_t)NROWS * DIM_ * 2);
  u16* w_c1T    = (u16*)alloc((size_t)2304 * DIM_ * 2);      // [kvT(512); qcT(1536); kropeT(64); qropeT(64); pad(128)] x 2048
  u16* w_kvdT   = (u16*)alloc((size_t)3072 * DC_ * 2);       // [kdecPackedT(1024); vdecT(2048)] x 512
  u16* w_qdPT   = (u16*)alloc((size_t)1024 * DCQ_ * 2);      // packed qdecT (1024 x 1536)
  u16* w_oT     = (u16*)alloc((size_t)DIM_ * DIM_ * 2);
  u16* xc       = (u16*)alloc((size_t)NROWS * 2304 * 2);     // [c_kv(512) | c_q(1536) | ropes(128) | pad(128)]
  u16* qP       = (u16*)alloc((size_t)NROWS * 1024 * 2);     // packed q decode (pre-scaled)
  u16* kvP      = (u16*)alloc((size_t)NROWS * 3072 * 2);     // [kPacked(1024) | v(2048)]
  u16* krope    = (u16*)alloc((size_t)NROWS * 64 * 2);
  u16* qrope    = (u16*)alloc((size_t)NROWS * 64 * 2);       // pre-scaled
  u16* vT       = (u16*)alloc((size_t)32 * 128 * T_ * 2);    // [bh][d][t]
  u16* aout     = (u16*)alloc((size_t)NROWS * DIM_ * 2);
  (void)in_sizes; (void)n_in; (void)out_size; (void)ws_size;

  const float SC2 = 0.12753139626374414f;   // 1/sqrt(128) * log2(e)

  hipLaunchKernelGGL(k_detect, dim3(1), dim3(128), 0, stream, (const u16*)cosp, flag, ticket);

  // merged x-convert + weight transposes (8192 conv blocks + 2880 transpose blocks)
  TPack tp;
  tp.d[0] = { w_kv,    w_c1T,                        512,  2048, 64,  8,  0    };
  tp.d[1] = { w_qc,    w_c1T + (size_t)512 * 2048,   1536, 2048, 64,  24, 256  };
  tp.d[2] = { w_krope, w_c1T + (size_t)2048 * 2048,  64,   2048, 64,  1,  1024 };
  tp.d[3] = { w_qrope, w_c1T + (size_t)2112 * 2048,  64,   2048, 64,  1,  1056 };
  tp.d[4] = { w_kdec,  w_kvdT,                       2048, 512,  128, 16, 1088 };
  tp.d[5] = { w_vdec,  w_kvdT + (size_t)1024 * 512,  2048, 512,  64,  32, 1216 };
  tp.d[6] = { w_qdec,  w_qdPT,                       2048, 1536, 128, 16, 1472 };
  tp.d[7] = { w_o,     w_oT,                         2048, 2048, 64,  32, 1856 };
  hipLaunchKernelGGL(k_prep, dim3(CONVBLK + 2880), dim3(256), 0, stream, x, x_bf, tp, flag);

  // G13: xc = x @ [w_kv | w_qc | w_krope | w_qrope | pad]  (4096 x 2304, K=2048)
  // 128^2 tiles: (32, 18) = 576 blocks, XCD-chunked; A read straight from x when bf16
  hipLaunchKernelGGL(k_gemm, dim3(32, 18), dim3(256), 0, stream,
                     x_bf, DIM_, w_c1T, DIM_, xc, 2304, 1.0f,
                     x_bf, DIM_, w_c1T, DIM_, xc, 2304, 1.0f,
                     18, 1, (void*)nullptr, (const int*)flag,
                     (const u16*)x, (const u16*)x);
  // G4 + G2 grouped on 128^2 tiles (1024 blocks; heavy K=1536 group dispatched first):
  hipLaunchKernelGGL(k_gemm, dim3(32, 32), dim3(256), 0, stream,
                     xc + 512, 2304, w_qdPT, DCQ_, qP, 1024, SC2,
                     xc, 2304, w_kvdT, DC_, kvP, 3072, 1.0f,
                     8, 0, (void*)nullptr, (const int*)nullptr,
                     (const u16*)nullptr, (const u16*)nullptr);
  // merged RoPE + vT (2048 + 2048 blocks)
  hipLaunchKernelGGL(k_ropevt, dim3(4096), dim3(256), 0, stream,
                     xc, cosp, sinp, flag, krope, qrope, kvP, vT);
  // attention (256 workers x 8 waves, 128-row items, 2:1 stealing, XCD-partitioned tickets)
  hipLaunchKernelGGL(k_attn, dim3(256), dim3(512), 0, stream,
                     qP, kvP, vT, krope, qrope, aout, ticket);
  // G5: out = aout @ w_o  (4096 x 2048, K=2048) -> (32,16) = 512 blocks = 2/CU, XCD-chunked
  hipLaunchKernelGGL(k_gemm, dim3(32, 16), dim3(256), 0, stream,
                     aout, DIM_, w_oT, DIM_, (u16*)nullptr, DIM_, 1.0f,
                     aout, DIM_, w_oT, DIM_, (u16*)nullptr, DIM_, 1.0f,
                     16, 1, d_out, (const int*)flag,
                     (const u16*)nullptr, (const u16*)nullptr);
}

// Round 17
// 247.076 us; speedup vs baseline: 1.4229x; 1.0110x over previous
//
#include <hip/hip_runtime.h>
#include <stdint.h>
#include <math.h>

#define B_    2
#define T_    2048
#define DIM_  2048
#define H_    16
#define DC_   512
#define DCQ_  1536
#define NROWS (B_*T_)   // 4096

typedef unsigned short u16;
typedef __attribute__((ext_vector_type(8))) __bf16 bf16x8;
typedef __attribute__((ext_vector_type(4))) float  f32x4;
typedef __attribute__((ext_vector_type(8))) unsigned short u16x8;
typedef __attribute__((ext_vector_type(4))) float  f4v;

__device__ __forceinline__ u16 f2bf(float f){
  unsigned u = __float_as_uint(f);
  u += 0x7FFFu + ((u >> 16) & 1u);   // RNE
  return (u16)(u >> 16);
}
__device__ __forceinline__ float bf2f(u16 h){ return __uint_as_float(((unsigned)h) << 16); }

__device__ __forceinline__ unsigned cvt_pk_bf16(float lo, float hi){
  unsigned r;
  asm("v_cvt_pk_bf16_f32 %0, %1, %2" : "=v"(r) : "v"(lo), "v"(hi));
  return r;
}

// async global->LDS, 16B per lane; LDS dest = wave-uniform base + lane*16.
__device__ __forceinline__ void gld_lds16(const void* g, void* l){
  auto gp = reinterpret_cast<__attribute__((address_space(1))) unsigned int*>(
      reinterpret_cast<uintptr_t>(g));
  auto lp = reinterpret_cast<__attribute__((address_space(3))) unsigned int*>(
      reinterpret_cast<uintptr_t>(l));
  __builtin_amdgcn_global_load_lds(gp, lp, 16, 0, 0);
}

__device__ __forceinline__ f32x4 mfma16(bf16x8 a, bf16x8 b, f32x4 c){
  return __builtin_amdgcn_mfma_f32_16x16x32_bf16(a, b, c, 0, 0, 0);
}

__device__ __forceinline__ void vmwait0(){ asm volatile("s_waitcnt vmcnt(0)" ::: "memory"); }
__device__ __forceinline__ void vmwait8(){ asm volatile("s_waitcnt vmcnt(8)" ::: "memory"); }
__device__ __forceinline__ void barr(){ asm volatile("s_barrier" ::: "memory"); }

// ---------------- dtype detect + ticket reset (8 XCD-partition tickets, stride 16)
__global__ void k_detect(const u16* cosr, int* flag, int* ticket){
  if (threadIdx.x == 0) *flag = (cosr[0] == (u16)0x3F80u) ? 1 : 0;
  if (threadIdx.x < 128) ticket[threadIdx.x] = 0;
}

// ---------------- merged x-convert + 8 weight transposes (one launch)
struct TDesc { const void* src; u16* dst; int srcStride, dstStride, cblk, nbx, blk0; };
struct TPack { TDesc d[8]; };
#define CONVBLK 8192

__global__ void k_prep(const void* __restrict__ xsrc, u16* __restrict__ x_bf,
                       TPack p, const int* flag){
  __shared__ u16 tile[64][72];
  const int bid = blockIdx.x;
  const int tid = threadIdx.x;
  const int f = *flag;
  if (bid < CONVBLK){
    if (f) return;                            // bf16 input: G13 reads x directly, skip copy
    int id = bid * 256 + tid;                 // n4 = 2097152 = 8192*256 exactly
    f4v v = reinterpret_cast<const f4v*>(xsrc)[id];
    unsigned lo = (unsigned)f2bf(v.x) | ((unsigned)f2bf(v.y) << 16);
    unsigned hi = (unsigned)f2bf(v.z) | ((unsigned)f2bf(v.w) << 16);
    reinterpret_cast<uint2*>(x_bf)[id] = make_uint2(lo, hi);
    return;
  }
  const int tb = bid - CONVBLK;
  int i = 0;
  #pragma unroll
  for (int k = 1; k < 8; ++k) if (tb >= p.d[k].blk0) i = k;
  const void* src = p.d[i].src;
  u16* dst = p.d[i].dst;
  const int srcStride = p.d[i].srcStride, dstStride = p.d[i].dstStride;
  const int rel = tb - p.d[i].blk0;
  const int bx = rel % p.d[i].nbx, by = rel / p.d[i].nbx;
  const int r0 = by << 6, c0 = bx * p.d[i].cblk;
  #pragma unroll
  for (int it = 0; it < 2; ++it){
    int task = (it << 8) + tid;
    int r = task >> 3, c8 = (task & 7) << 3;
    if (f){
      const u16* pp = (const u16*)src + (size_t)(r0 + r) * srcStride + c0 + c8;
      u16x8 v = *reinterpret_cast<const u16x8*>(pp);
      #pragma unroll
      for (int j = 0; j < 8; ++j) tile[r][c8 + j] = v[j];
    } else {
      const float* pp = (const float*)src + (size_t)(r0 + r) * srcStride + c0 + c8;
      f4v a = reinterpret_cast<const f4v*>(pp)[0];
      f4v b = reinterpret_cast<const f4v*>(pp)[1];
      tile[r][c8+0]=f2bf(a.x); tile[r][c8+1]=f2bf(a.y); tile[r][c8+2]=f2bf(a.z); tile[r][c8+3]=f2bf(a.w);
      tile[r][c8+4]=f2bf(b.x); tile[r][c8+5]=f2bf(b.y); tile[r][c8+6]=f2bf(b.z); tile[r][c8+7]=f2bf(b.w);
    }
  }
  __syncthreads();
  #pragma unroll
  for (int it = 0; it < 2; ++it){
    int task = (it << 8) + tid;
    int rr = task >> 3, cc8 = (task & 7) << 3;
    u16x8 v;
    #pragma unroll
    for (int j = 0; j < 8; ++j) v[j] = tile[cc8 + j][rr];
    *reinterpret_cast<u16x8*>(dst + (size_t)((bx << 6) + rr) * dstStride + r0 + cc8) = v;
  }
}

// ---------------- unified 128x128 GEMM: 256 thr / 4 waves (2x2), 64x64 per wave,
// LDS 64 KB -> 2 blocks/CU. Row-XOR swizzle via inverse-swizzled global_load_lds sources;
// counted vmcnt(8) pipeline; setprio around MFMA cluster. Two groups by N-tile index.
// alt-A: bf16 passthrough of unconverted input when *flag.
// vt: when set for a group, output cols >= 1024 are V -> written TRANSPOSED to vT[bh][d][t]
// (4 consecutive t per acc vector = one 8B store); cols < 1024 go to C (packed K).
__global__ __launch_bounds__(256, 2) void k_gemm(
    const u16* __restrict__ A0, int lda0, const u16* __restrict__ Bt0, int K0,
    u16* __restrict__ C0, int ldc0, float os0,
    const u16* __restrict__ A1, int lda1, const u16* __restrict__ Bt1, int K1,
    u16* __restrict__ C1, int ldc1, float os1,
    int ysplit, int swz, void* outp, const int* flag,
    const u16* __restrict__ alt0, const u16* __restrict__ alt1,
    u16* __restrict__ vt0, u16* __restrict__ vt1){
  __shared__ alignas(16) u16 lds[32768];   // 64 KB
  const int tid = threadIdx.x;
  const int wid = tid >> 6, lane = tid & 63;
  const int wr = wid >> 1, wc = wid & 1;
  const int l16 = lane & 15, g = lane >> 4;
  int lin = blockIdx.y * 32 + blockIdx.x;    // gridDim.x == 32 (M-tiles)
  if (swz){
    const int q8 = (gridDim.x * gridDim.y) >> 3;
    lin = (lin & 7) * q8 + (lin >> 3);       // bijective XCD chunking (nwg%8==0)
  }
  const int m0 = (lin & 31) << 7;
  int nt = lin >> 5;
  const u16 *A, *Bt, *alt; u16 *C, *vtp; int lda, K, ldc; float oscale;
  if (nt < ysplit){ A = A0; lda = lda0; Bt = Bt0; K = K0; C = C0; ldc = ldc0; oscale = os0; alt = alt0; vtp = vt0; }
  else { nt -= ysplit; A = A1; lda = lda1; Bt = Bt1; K = K1; C = C1; ldc = ldc1; oscale = os1; alt = alt1; vtp = vt1; }
  const int f = flag ? *flag : 1;
  if (alt && f) A = alt;                     // bf16 input: read source directly
  const int n0 = nt << 7;
  const size_t Kz = (size_t)K;
  const int nkt = K >> 6;

  auto STAGE = [&](int kt, int bufn){
    const int kb = kt << 6;
    #pragma unroll
    for (int q = 0; q < 8; ++q){
      const int ht = q >> 2;                 // 0 = A half, 1 = B half
      const int cq = ((q & 3) << 8) + tid;   // chunk 0..1023 within half
      const int Lb = cq << 4;                // byte in [128][128B] half-tile
      const int row = Lb >> 7;
      const int colb = (Lb & 127) ^ ((row & 7) << 4);   // inverse-swizzled source
      const u16* src = ht ? (Bt + (size_t)(n0 + row) * Kz + kb + (colb >> 1))
                          : (A  + (size_t)(m0 + row) * lda + kb + (colb >> 1));
      gld_lds16(src, &lds[bufn * 16384 + ht * 8192 + (cq << 3)]);
    }
  };

  f32x4 acc[4][4] = {};

  STAGE(0, 0);
  int buf = 0;

  for (int kt = 0; kt < nkt; ++kt){
    if (kt + 1 < nkt){ STAGE(kt + 1, buf ^ 1); vmwait8(); }   // waits tile-kt's 8 loads
    else vmwait0();
    barr();                                                    // staged tile visible to all
    bf16x8 af[2][4], bfr[2][4];
    #pragma unroll
    for (int ks = 0; ks < 2; ++ks){
      #pragma unroll
      for (int mi = 0; mi < 4; ++mi){
        int row = (wr << 6) + (mi << 4) + l16;
        int cb = ((ks << 6) + (g << 4)) ^ ((row & 7) << 4);
        af[ks][mi] = *reinterpret_cast<const bf16x8*>(&lds[buf * 16384 + (((row << 7) + cb) >> 1)]);
      }
      #pragma unroll
      for (int ni = 0; ni < 4; ++ni){
        int row = (wc << 6) + (ni << 4) + l16;
        int cb = ((ks << 6) + (g << 4)) ^ ((row & 7) << 4);
        bfr[ks][ni] = *reinterpret_cast<const bf16x8*>(&lds[buf * 16384 + 8192 + (((row << 7) + cb) >> 1)]);
      }
    }
    __builtin_amdgcn_s_setprio(1);
    #pragma unroll
    for (int ks = 0; ks < 2; ++ks)
      #pragma unroll
      for (int mi = 0; mi < 4; ++mi)
        #pragma unroll
        for (int ni = 0; ni < 4; ++ni)
          acc[mi][ni] = mfma16(af[ks][mi], bfr[ks][ni], acc[mi][ni]);
    __builtin_amdgcn_s_setprio(0);
    barr();                                  // reads done before next STAGE overwrites
    buf ^= 1;
  }

  const int r4 = g << 2;
  #pragma unroll
  for (int mi = 0; mi < 4; ++mi){
    int row = m0 + (wr << 6) + (mi << 4) + r4;
    #pragma unroll
    for (int ni = 0; ni < 4; ++ni){
      int col = n0 + (wc << 6) + (ni << 4) + l16;
      if (vtp && col >= 1024){
        // V quadrant: write transposed to vT[bh][d][t]; rows j are consecutive t.
        int hd = col - 1024;
        u16* dst = vtp + (((size_t)(((row >> 11) << 4) + (hd >> 7)) << 7) + (hd & 127)) * (size_t)T_ + (row & (T_ - 1));
        union { u16 u[4]; uint2 v; } pk;
        #pragma unroll
        for (int j = 0; j < 4; ++j) pk.u[j] = f2bf(acc[mi][ni][j] * oscale);
        *reinterpret_cast<uint2*>(dst) = pk.v;
        continue;
      }
      #pragma unroll
      for (int j = 0; j < 4; ++j){
        float v = acc[mi][ni][j] * oscale;
        if (outp){
          if (f) ((u16*)outp)[(size_t)(row + j) * ldc + col] = f2bf(v);
          else   ((float*)outp)[(size_t)(row + j) * ldc + col] = v;
        } else {
          C[(size_t)(row + j) * ldc + col] = f2bf(v);
        }
      }
    }
  }
}

// ---------------- RoPE only (2048 blocks; vT now produced by the GEMM epilogue)
__global__ void k_rope(const u16* __restrict__ xc, const void* __restrict__ cosp,
                       const void* __restrict__ sinp, const int* flag,
                       u16* __restrict__ krope, u16* __restrict__ qrope){
  int id = blockIdx.x * 256 + threadIdx.x;   // exactly NROWS*128
  int row = id >> 7, c = id & 127;
  int t = row & (T_ - 1);
  int d = c & 63, i = d & 31;
  float cs, sn;
  if (*flag){ cs = bf2f(((const u16*)cosp)[t * 32 + i]); sn = bf2f(((const u16*)sinp)[t * 32 + i]); }
  else      { cs = ((const float*)cosp)[t * 32 + i];     sn = ((const float*)sinp)[t * 32 + i]; }
  int base = c & 64;
  float t1 = bf2f(xc[(size_t)row * 2304 + 2048 + base + i]);
  float t2 = bf2f(xc[(size_t)row * 2304 + 2048 + base + 32 + i]);
  float v = (d < 32) ? (t1 * cs - t2 * sn) : (t2 * cs + t1 * sn);
  if (c >= 64) v *= 0.12753139626374414f;   // 1/sqrt(128)*log2(e) folded into q
  ((c < 64) ? krope : qrope)[(size_t)row * 64 + d] = f2bf(v);
}

// ---------------- causal flash attention: 128-row items, 8 waves x 16 rows (512 thr).
// kvP is now K-only (stride 1024). 64KB LDS double-buffer; 256 workers, per-XCD tickets,
// 2:1 heavy-first stealing; setprio around MFMA clusters.
__global__ __launch_bounds__(512, 2) void k_attn(const u16* __restrict__ qP,
                                                 const u16* __restrict__ kvP,
                                                 const u16* __restrict__ vT,
                                                 const u16* __restrict__ krope,
                                                 const u16* __restrict__ qrope,
                                                 u16* __restrict__ aout,
                                                 int* __restrict__ ticket){
  __shared__ alignas(16) u16 smem[32768];   // 64 KB: 2 buffers x (K [64][128] + V [128][64])
  const int tid = threadIdx.x, wid = tid >> 6, lane = tid & 63;
  const int l16 = lane & 15, g = lane >> 4;
  const int lk = g << 3, r4 = g << 2;
  const int sw8 = (l16 & 7) << 3;
  const int xcd = blockIdx.x & 7;

  while (true){
    if (tid == 0) *(int*)&smem[0] = atomicAdd(&ticket[xcd << 4], 1);
    __syncthreads();
    const int it = *(const int*)&smem[0];
    __syncthreads();
    if (it >= 64) break;
    const int qt = 15 - (it >> 2);          // heavy-first within partition (128-row tiles)
    const int bh = (xcd << 2) + (it & 3), b = bh >> 4, h = bh & 15;
    const int q0 = qt << 7;
    const size_t bT = (size_t)b * T_;
    const u16* kvPb = kvP + bT * 1024 + (h << 6);
    const u16* krb  = krope + bT * 64;
    const u16* vTb  = vT + (size_t)bh * 128 * T_;
    const int qlo = q0 + (wid << 4);
    const int qhi = qlo + 15;
    const int nkv = (qt << 1) + 2;

    auto STAGE = [&](int buf, int k0){
      const int base = buf << 14;
      #pragma unroll
      for (int r = 0; r < 4; ++r){
        int c = (r << 9) + tid;              // 0..2047 chunks of 16B
        const u16* src;
        if (r < 2){
          int row = c >> 4, cc = c & 15;
          int ccx = (cc & 8) | ((cc & 7) ^ (row & 7));
          int col0 = ccx << 3;
          src = (col0 < 64) ? (kvPb + (size_t)(k0 + row) * 1024 + col0)
                            : (krb  + (size_t)(k0 + row) * 64 + (col0 - 64));
        } else {
          int cv = c - 1024;
          int row = cv >> 3, cc = cv & 7;
          int ccx = cc ^ (row & 7);
          src = vTb + (size_t)row * T_ + k0 + (ccx << 3);
        }
        gld_lds16(src, &smem[base + (c << 3)]);
      }
    };

    bf16x8 qf[4];
    {
      size_t grow = bT + qlo + l16;
      #pragma unroll
      for (int ks = 0; ks < 4; ++ks){
        int d = (ks << 5) + lk;
        const u16* src = (ks < 2) ? (qP + grow * 1024 + (h << 6) + d)
                                  : (qrope + grow * 64 + (d - 64));
        qf[ks] = *reinterpret_cast<const bf16x8*>(src);
      }
    }
    f32x4 o[8] = {};
    float m = -3e38f, l = 0.f;

    STAGE(0, 0);
    __syncthreads();
    int cur = 0;

    for (int kv = 0; kv < nkv; ++kv){
      const int k0 = kv << 6;
      if (kv + 1 < nkv) STAGE(cur ^ 1, (kv + 1) << 6);
      if (k0 <= qhi){
        const int kb = cur << 14;
        f32x4 s[4] = {};
        __builtin_amdgcn_s_setprio(1);
        #pragma unroll
        for (int ks = 0; ks < 4; ++ks){
          int colsw = ((ks << 5) + lk) ^ sw8;
          #pragma unroll
          for (int n = 0; n < 4; ++n){
            bf16x8 kf = *reinterpret_cast<const bf16x8*>(&smem[kb + ((n << 4) + l16) * 128 + colsw]);
            s[n] = mfma16(kf, qf[ks], s[n]);
          }
        }
        __builtin_amdgcn_s_setprio(0);
        if (k0 + 63 > qlo){                  // only the wave's diagonal tile needs masking
          const int tq = qlo + l16;
          #pragma unroll
          for (int n = 0; n < 4; ++n)
            #pragma unroll
            for (int j = 0; j < 4; ++j)
              s[n][j] = (k0 + (n << 4) + r4 + j <= tq) ? s[n][j] : -3e38f;
        }
        float mx;
        {
          float a0 = fmaxf(fmaxf(s[0][0], s[0][1]), fmaxf(s[0][2], s[0][3]));
          float a1 = fmaxf(fmaxf(s[1][0], s[1][1]), fmaxf(s[1][2], s[1][3]));
          float a2 = fmaxf(fmaxf(s[2][0], s[2][1]), fmaxf(s[2][2], s[2][3]));
          float a3 = fmaxf(fmaxf(s[3][0], s[3][1]), fmaxf(s[3][2], s[3][3]));
          mx = fmaxf(fmaxf(a0, a1), fmaxf(a2, a3));
          mx = fmaxf(mx, __shfl_xor(mx, 16));
          mx = fmaxf(mx, __shfl_xor(mx, 32));
        }
        if (__ballot(mx > m + 8.f)){
          float mnew = fmaxf(m, mx);
          float alpha = exp2f(m - mnew);
          m = mnew; l *= alpha;
          #pragma unroll
          for (int j = 0; j < 4; ++j){
            float av = __shfl(alpha, r4 + j);
            #pragma unroll
            for (int db = 0; db < 8; ++db) o[db][j] *= av;
          }
        }
        unsigned w[4][2];
        float rs = 0.f;
        #pragma unroll
        for (int n = 0; n < 4; ++n)
          #pragma unroll
          for (int jh = 0; jh < 2; ++jh){
            float p0 = exp2f(s[n][2*jh]     - m);
            float p1 = exp2f(s[n][2*jh + 1] - m);
            rs += p0 + p1;
            w[n][jh] = cvt_pk_bf16(p0, p1);
          }
        rs += __shfl_xor(rs, 16);
        rs += __shfl_xor(rs, 32);
        l += rs;
        const int srcA = l16 + ((g & 1) << 5);
        const int srcB = srcA + 16;
        const bool hi = (g >= 2);
        bf16x8 pa[2];
        #pragma unroll
        for (int ks2 = 0; ks2 < 2; ++ks2){
          unsigned a0 = __shfl((int)w[2*ks2][0],     srcA);
          unsigned b0 = __shfl((int)w[2*ks2 + 1][0], srcA);
          unsigned a1 = __shfl((int)w[2*ks2][1],     srcA);
          unsigned b1 = __shfl((int)w[2*ks2 + 1][1], srcA);
          unsigned a2 = __shfl((int)w[2*ks2][0],     srcB);
          unsigned b2 = __shfl((int)w[2*ks2 + 1][0], srcB);
          unsigned a3 = __shfl((int)w[2*ks2][1],     srcB);
          unsigned b3 = __shfl((int)w[2*ks2 + 1][1], srcB);
          union { unsigned u[4]; bf16x8 v; } pk;
          pk.u[0] = hi ? b0 : a0;
          pk.u[1] = hi ? b1 : a1;
          pk.u[2] = hi ? b2 : a2;
          pk.u[3] = hi ? b3 : a3;
          pa[ks2] = pk.v;
        }
        __builtin_amdgcn_s_setprio(1);
        #pragma unroll
        for (int ks2 = 0; ks2 < 2; ++ks2){
          int colsw = ((ks2 << 5) + lk) ^ sw8;
          #pragma unroll
          for (int db = 0; db < 8; ++db){
            bf16x8 vb = *reinterpret_cast<const bf16x8*>(&smem[(cur << 14) + 8192 + ((db << 4) + l16) * 64 + colsw]);
            o[db] = mfma16(pa[ks2], vb, o[db]);
          }
        }
        __builtin_amdgcn_s_setprio(0);
      }
      __syncthreads();                      // drains prefetch; reads done before buffer reuse
      cur ^= 1;
    }
    #pragma unroll
    for (int j = 0; j < 4; ++j){
      float lv = __shfl(l, r4 + j);
      float rinv = 1.f / lv;
      const int tq = qlo + r4 + j;
      u16* dst = aout + (bT + tq) * 2048 + (h << 7) + l16;
      #pragma unroll
      for (int db = 0; db < 8; ++db)
        dst[db << 4] = f2bf(o[db][j] * rinv);
    }
  }
}

extern "C" void kernel_launch(void* const* d_in, const int* in_sizes, int n_in,
                              void* d_out, int out_size, void* d_ws, size_t ws_size,
                              hipStream_t stream){
  const void* x       = d_in[0];
  const void* cosp    = d_in[1];
  const void* sinp    = d_in[2];
  const void* w_kv    = d_in[3];
  const void* w_kdec  = d_in[4];
  const void* w_vdec  = d_in[5];
  const void* w_qc    = d_in[6];
  const void* w_qdec  = d_in[7];
  const void* w_krope = d_in[8];
  const void* w_qrope = d_in[9];
  const void* w_o     = d_in[10];

  char* ws = (char*)d_ws;
  size_t off = 0;
  auto alloc = [&](size_t bytes){ void* p = ws + off; off += (bytes + 255) & ~(size_t)255; return p; };
  int* flag     = (int*)alloc(256);
  int* ticket   = (int*)alloc(1024);                         // 8 tickets, stride 16 ints
  u16* x_bf     = (u16*)alloc((size_t)NROWS * DIM_ * 2);
  u16* w_c1T    = (u16*)alloc((size_t)2304 * DIM_ * 2);      // [kvT(512); qcT(1536); kropeT(64); qropeT(64); pad(128)] x 2048
  u16* w_kvdT   = (u16*)alloc((size_t)3072 * DC_ * 2);       // [kdecPackedT(1024); vdecT(2048)] x 512
  u16* w_qdPT   = (u16*)alloc((size_t)1024 * DCQ_ * 2);      // packed qdecT (1024 x 1536)
  u16* w_oT     = (u16*)alloc((size_t)DIM_ * DIM_ * 2);
  u16* xc       = (u16*)alloc((size_t)NROWS * 2304 * 2);     // [c_kv(512) | c_q(1536) | ropes(128) | pad(128)]
  u16* qP       = (u16*)alloc((size_t)NROWS * 1024 * 2);     // packed q decode (pre-scaled)
  u16* kvP      = (u16*)alloc((size_t)NROWS * 1024 * 2);     // packed K only (stride 1024)
  u16* krope    = (u16*)alloc((size_t)NROWS * 64 * 2);
  u16* qrope    = (u16*)alloc((size_t)NROWS * 64 * 2);       // pre-scaled
  u16* vT       = (u16*)alloc((size_t)32 * 128 * T_ * 2);    // [bh][d][t], written by G2 epilogue
  u16* aout     = (u16*)alloc((size_t)NROWS * DIM_ * 2);
  (void)in_sizes; (void)n_in; (void)out_size; (void)ws_size;

  const float SC2 = 0.12753139626374414f;   // 1/sqrt(128) * log2(e)

  hipLaunchKernelGGL(k_detect, dim3(1), dim3(128), 0, stream, (const u16*)cosp, flag, ticket);

  // merged x-convert + weight transposes (8192 conv blocks + 2880 transpose blocks)
  TPack tp;
  tp.d[0] = { w_kv,    w_c1T,                        512,  2048, 64,  8,  0    };
  tp.d[1] = { w_qc,    w_c1T + (size_t)512 * 2048,   1536, 2048, 64,  24, 256  };
  tp.d[2] = { w_krope, w_c1T + (size_t)2048 * 2048,  64,   2048, 64,  1,  1024 };
  tp.d[3] = { w_qrope, w_c1T + (size_t)2112 * 2048,  64,   2048, 64,  1,  1056 };
  tp.d[4] = { w_kdec,  w_kvdT,                       2048, 512,  128, 16, 1088 };
  tp.d[5] = { w_vdec,  w_kvdT + (size_t)1024 * 512,  2048, 512,  64,  32, 1216 };
  tp.d[6] = { w_qdec,  w_qdPT,                       2048, 1536, 128, 16, 1472 };
  tp.d[7] = { w_o,     w_oT,                         2048, 2048, 64,  32, 1856 };
  hipLaunchKernelGGL(k_prep, dim3(CONVBLK + 2880), dim3(256), 0, stream, x, x_bf, tp, flag);

  // G13: xc = x @ [w_kv | w_qc | w_krope | w_qrope | pad]  (4096 x 2304, K=2048)
  // 128^2 tiles: (32, 18) = 576 blocks, XCD-chunked; A read straight from x when bf16
  hipLaunchKernelGGL(k_gemm, dim3(32, 18), dim3(256), 0, stream,
                     x_bf, DIM_, w_c1T, DIM_, xc, 2304, 1.0f,
                     x_bf, DIM_, w_c1T, DIM_, xc, 2304, 1.0f,
                     18, 1, (void*)nullptr, (const int*)flag,
                     (const u16*)x, (const u16*)x,
                     (u16*)nullptr, (u16*)nullptr);
  // G4 + G2 grouped on 128^2 tiles (1024 blocks; heavy K=1536 group first):
  //   nt<8:  qP = xc[:, 512:2048] @ w_qdecP  (4096 x 1024, K=1536), pre-scaled
  //   nt>=8: K -> kvP (stride 1024, cols<1024); V -> vT DIRECT TRANSPOSED (cols>=1024)
  hipLaunchKernelGGL(k_gemm, dim3(32, 32), dim3(256), 0, stream,
                     xc + 512, 2304, w_qdPT, DCQ_, qP, 1024, SC2,
                     xc, 2304, w_kvdT, DC_, kvP, 1024, 1.0f,
                     8, 0, (void*)nullptr, (const int*)nullptr,
                     (const u16*)nullptr, (const u16*)nullptr,
                     (u16*)nullptr, vT);
  // RoPE (2048 blocks; vT handled by the GEMM epilogue)
  hipLaunchKernelGGL(k_rope, dim3(2048), dim3(256), 0, stream,
                     xc, cosp, sinp, flag, krope, qrope);
  // attention (256 workers x 8 waves, 128-row items, 2:1 stealing, XCD-partitioned tickets)
  hipLaunchKernelGGL(k_attn, dim3(256), dim3(512), 0, stream,
                     qP, kvP, vT, krope, qrope, aout, ticket);
  // G5: out = aout @ w_o  (4096 x 2048, K=2048) -> (32,16) = 512 blocks = 2/CU, XCD-chunked
  hipLaunchKernelGGL(k_gemm, dim3(32, 16), dim3(256), 0, stream,
                     aout, DIM_, w_oT, DIM_, (u16*)nullptr, DIM_, 1.0f,
                     aout, DIM_, w_oT, DIM_, (u16*)nullptr, DIM_, 1.0f,
                     16, 1, d_out, (const int*)flag,
                     (const u16*)nullptr, (const u16*)nullptr,
                     (u16*)nullptr, (u16*)nullptr);
}